// Round 8
// baseline (660.450 us; speedup 1.0000x reference)
//
#include <hip/hip_runtime.h>

#define EPS_BN 1e-5f

typedef __attribute__((ext_vector_type(8))) short short8;
typedef __attribute__((ext_vector_type(4))) float f32x4;

__device__ __forceinline__ float fast_rcp(float x) { return __builtin_amdgcn_rcpf(x); }
__device__ __forceinline__ float sigmoid_f(float x) { return fast_rcp(1.0f + __expf(-x)); }
// robust tanh: no inf/inf NaN at large |x|
__device__ __forceinline__ float tanh_f(float x) { return 1.0f - 2.0f * fast_rcp(__expf(2.0f * x) + 1.0f); }

// round-to-nearest-even fp32 -> bf16 bits
__device__ __forceinline__ unsigned short f2bf(float f) {
    unsigned u = __float_as_uint(f);
    u += 0x7FFFu + ((u >> 16) & 1u);
    return (unsigned short)(u >> 16);
}
__device__ __forceinline__ unsigned pk_bf(float a, float b) {
    return (unsigned)f2bf(a) | ((unsigned)f2bf(b) << 16);
}
// value of the bf16 rounding (hi part); residual = f - bf_hi(f)
__device__ __forceinline__ float bf_hi(float f) {
    return __uint_as_float((unsigned)f2bf(f) << 16);
}

// async global -> LDS, 16 bytes per lane (dest is wave-uniform base + lane*16)
__device__ __forceinline__ void gload16(const unsigned short* g, unsigned short* l) {
    __builtin_amdgcn_global_load_lds(
        (const __attribute__((address_space(1))) unsigned int*)g,
        (__attribute__((address_space(3))) unsigned int*)l,
        16, 0, 0);
}

union AFrag { short e[8]; short8 v; };
union BFrag { uint4 u; short8 v; };

// ---------------------------------------------------------------------------
// Split-precision MFMA LSTM encoder v7 — MERGED dispatch, 32 seqs/block.
// LAUNCH BOUNDS: (256,2) is LOAD-BEARING (R4: (256,4) clamps VGPR -> spill).
// v6: merged-activation epilogue (5 rcp -> 3 rcp per element).
// v7: build_x0 fused into the neighbour epilogue. R7 verified (579.7us e2e).
// ---------------------------------------------------------------------------
__global__ __launch_bounds__(256, 2) void lstm_mfma(
    const float* __restrict__ xA,      // agent_traj [SA, T, 2]
    const float* __restrict__ aW_ih, const float* __restrict__ aW_hh,
    const float* __restrict__ ab_ih, const float* __restrict__ ab_hh,
    float* __restrict__ agent_h, float* __restrict__ agent_c,
    const float* __restrict__ xN,      // neighbours [SN, T, 2]
    const float* __restrict__ nW_ih, const float* __restrict__ nW_hh,
    const float* __restrict__ nb_ih, const float* __restrict__ nb_hh,
    const int* __restrict__ seg, const float* __restrict__ rW,
    const float* __restrict__ rb,
    unsigned short* __restrict__ x0hi, unsigned short* __restrict__ x0lo,
    int nAgentBlk, int T)
{
    __shared__ unsigned h_ex[2][2][32 * 52];   // [buf][hi/lo][32 seqs x 52]

    const bool isA = (blockIdx.x < (unsigned)nAgentBlk);
    const long blk = isA ? blockIdx.x : blockIdx.x - nAgentBlk;
    const float* __restrict__ x     = isA ? xA   : xN;
    const float* __restrict__ W_ih  = isA ? aW_ih : nW_ih;
    const float* __restrict__ W_hh  = isA ? aW_hh : nW_hh;
    const float* __restrict__ b_ih  = isA ? ab_ih : nb_ih;
    const float* __restrict__ b_hh  = isA ? ab_hh : nb_hh;

    const int tid  = threadIdx.x;
    const int w    = tid >> 6;        // cell-group == wave
    const int lane = tid & 63;
    const int s    = lane & 15;       // sequence within the 16 (per B-group)
    const int q    = lane >> 4;       // quad

    short8 ahi[4][3], alo[4][3];
#pragma unroll
    for (int gt = 0; gt < 4; ++gt) {
        const int n = gt * 64 + w * 16 + s;
#pragma unroll
        for (int kc = 0; kc < 2; ++kc) {
            const float* src = &W_hh[n * 64 + kc * 32 + q * 8];
            float4 v0 = *(const float4*)src;
            float4 v1 = *(const float4*)(src + 4);
            float v[8] = {v0.x, v0.y, v0.z, v0.w, v1.x, v1.y, v1.z, v1.w};
            AFrag a, b;
#pragma unroll
            for (int j = 0; j < 8; ++j) {
                a.e[j] = (short)f2bf(v[j]);
                b.e[j] = (short)f2bf(v[j] - bf_hi(v[j]));
            }
            ahi[gt][kc] = a.v;
            alo[gt][kc] = b.v;
        }
        AFrag a2, b2;
#pragma unroll
        for (int j = 0; j < 8; ++j) { a2.e[j] = 0; b2.e[j] = 0; }
        if (q == 0) {   // K rows 64(wi0), 65(wi1), 66(bias)
            const float wi0 = W_ih[n * 2 + 0];
            const float wi1 = W_ih[n * 2 + 1];
            const float bs  = b_ih[n] + b_hh[n];
            a2.e[0] = (short)f2bf(wi0); b2.e[0] = (short)f2bf(wi0 - bf_hi(wi0));
            a2.e[1] = (short)f2bf(wi1); b2.e[1] = (short)f2bf(wi1 - bf_hi(wi1));
            a2.e[2] = (short)f2bf(bs);  b2.e[2] = (short)f2bf(bs  - bf_hi(bs));
        }
        ahi[gt][2] = a2.v;
        alo[gt][2] = b2.v;
    }

    for (int i = tid; i < 2 * 2 * 32 * 52; i += 256) (&h_ex[0][0][0])[i] = 0u;
    __syncthreads();
    if (tid < 32) {   // seq = tid
        h_ex[0][0][tid * 52 + 33] = pk_bf(1.0f, 0.0f);
        h_ex[1][0][tid * 52 + 33] = pk_bf(1.0f, 0.0f);
        float2 xv = *(const float2*)&x[(blk * 32 + tid) * (long)(T * 2)];
        h_ex[0][0][tid * 52 + 32] = pk_bf(xv.x, xv.y);
        h_ex[0][1][tid * 52 + 32] = pk_bf(xv.x - bf_hi(xv.x), xv.y - bf_hi(xv.y));
    }
    __syncthreads();

    float creg[2][4] = {{0.f, 0.f, 0.f, 0.f}, {0.f, 0.f, 0.f, 0.f}};

    for (int t = 0; t < T; ++t) {
        const int rb_ = t & 1, wb = rb_ ^ 1;
        BFrag bhi[2][3], blo[2][3];
#pragma unroll
        for (int g = 0; g < 2; ++g)
#pragma unroll
        for (int kc = 0; kc < 3; ++kc) {
            const int off = (g * 16 + s) * 52 + kc * 16 + (q >> 1) * 8 + (q & 1) * 4;
            bhi[g][kc].u = *(const uint4*)&h_ex[rb_][0][off];
            blo[g][kc].u = *(const uint4*)&h_ex[rb_][1][off];
        }

        f32x4 acc[4][2];
#pragma unroll
        for (int gt = 0; gt < 4; ++gt) { acc[gt][0] = (f32x4)0.f; acc[gt][1] = (f32x4)0.f; }

#pragma unroll
        for (int kc = 0; kc < 3; ++kc) {
#pragma unroll
            for (int g = 0; g < 2; ++g) {
                const short8 bh = bhi[g][kc].v;
                const short8 bl = blo[g][kc].v;
#pragma unroll
                for (int gt = 0; gt < 4; ++gt) {
                    f32x4 a = acc[gt][g];
                    a = __builtin_amdgcn_mfma_f32_16x16x32_bf16(ahi[gt][kc], bh, a, 0, 0, 0);
                    a = __builtin_amdgcn_mfma_f32_16x16x32_bf16(ahi[gt][kc], bl, a, 0, 0, 0);
                    a = __builtin_amdgcn_mfma_f32_16x16x32_bf16(alo[gt][kc], bh, a, 0, 0, 0);
                    acc[gt][g] = a;
                }
            }
        }

#pragma unroll
        for (int g = 0; g < 2; ++g) {
            float hval[4];
#pragma unroll
            for (int r = 0; r < 4; ++r) {
                // merged activations: sigma(zi)*tanh(zg) and sigma(zo)*tanh(c)
                // via single-rcp rational forms (5 rcp -> 3 rcp per element).
                const float ei = __expf(-acc[0][g][r]);          // e^-zi
                const float eg = __expf(2.0f * acc[2][g][r]);    // e^2zg
                const float it = (eg - 1.0f) * fast_rcp((1.0f + ei) * (eg + 1.0f));
                const float sf = fast_rcp(1.0f + __expf(-acc[1][g][r]));
                const float c  = fmaf(sf, creg[g][r], it);
                creg[g][r] = c;
                const float eo = __expf(-acc[3][g][r]);          // e^-zo
                const float ec = __expf(2.0f * c);               // e^2c
                hval[r] = (ec - 1.0f) * fast_rcp((1.0f + eo) * (ec + 1.0f));
            }
            {
                const int w0 = (g * 16 + s) * 52 + w * 8 + q * 2;
                h_ex[wb][0][w0]     = pk_bf(hval[0], hval[1]);
                h_ex[wb][0][w0 + 1] = pk_bf(hval[2], hval[3]);
                h_ex[wb][1][w0]     = pk_bf(hval[0] - bf_hi(hval[0]), hval[1] - bf_hi(hval[1]));
                h_ex[wb][1][w0 + 1] = pk_bf(hval[2] - bf_hi(hval[2]), hval[3] - bf_hi(hval[3]));
            }
            if (t == T - 1) {
                const long seq = blk * 32 + g * 16 + s;
                const int j0 = w * 16 + q * 4;
                if (isA) {
                    *(float4*)&agent_h[seq * 64 + j0] =
                        make_float4(hval[0], hval[1], hval[2], hval[3]);
                    *(float4*)&agent_c[seq * 64 + j0] =
                        make_float4(creg[g][0], creg[g][1], creg[g][2], creg[g][3]);
                } else {
                    // x0 cols 0..63 = neigh_h (identical rounding to old path)
                    *(uint2*)&x0hi[seq * 128 + j0] = make_uint2(
                        pk_bf(hval[0], hval[1]), pk_bf(hval[2], hval[3]));
                    *(uint2*)&x0lo[seq * 128 + j0] = make_uint2(
                        pk_bf(hval[0] - bf_hi(hval[0]), hval[1] - bf_hi(hval[1])),
                        pk_bf(hval[2] - bf_hi(hval[2]), hval[3] - bf_hi(hval[3])));
                }
            }
        }
        if (tid < 32 && t + 1 < T) {
            float2 xv = *(const float2*)&x[(blk * 32 + tid) * (long)(T * 2) + (t + 1) * 2];
            h_ex[wb][0][tid * 52 + 32] = pk_bf(xv.x, xv.y);
            h_ex[wb][1][tid * 52 + 32] = pk_bf(xv.x - bf_hi(xv.x), xv.y - bf_hi(xv.y));
        }
        __syncthreads();
    }

    // x0 cols 64..127: rel_emb = rel @ rW.T + rb  (thread -> 1 seq x 8 cols)
    if (!isA) {
        const int sloc = tid >> 3;
        const long n = blk * 32 + sloc;
        const float2 np = *(const float2*)&x[n * (long)(T * 2) + (T - 1) * 2];
        const int sid = seg[n];
        const float2 ap = *(const float2*)&xA[(long)sid * (T * 2) + (T - 1) * 2];
        const float ra = np.x - ap.x, rbv = np.y - ap.y;
        const int o0 = (tid & 7) * 8;
#pragma unroll
        for (int j = 0; j < 8; ++j) {
            const int o = o0 + j;
            const float v = fmaf(rW[o * 2 + 0], ra, fmaf(rW[o * 2 + 1], rbv, rb[o]));
            x0hi[n * 128 + 64 + o] = f2bf(v);
            x0lo[n * 128 + 64 + o] = f2bf(v - bf_hi(v));
        }
    }
}

// ---------------------------------------------------------------------------
// Weight prep bodies (shared by prep_all / prep_w2).
// ---------------------------------------------------------------------------
__device__ __forceinline__ void wfrag_body(
    const float* __restrict__ W, int K, int blk, int l,
    unsigned short* __restrict__ Whi, unsigned short* __restrict__ Wlo)
{
    const int nKc = K >> 5;
    const int ti = blk / nKc, kc = blk - ti * nKc;
    const int n = ti * 16 + (l & 15);
    const int k0 = kc * 32 + (l >> 4) * 8;
    const long ob = ((long)blk * 64 + l) * 8;
#pragma unroll
    for (int j = 0; j < 8; ++j) {
        float v = W[(long)n * K + k0 + j];
        Whi[ob + j] = f2bf(v);
        Wlo[ob + j] = f2bf(v - bf_hi(v));
    }
}

// ---------------------------------------------------------------------------
// prep_all: all BN-independent weight preps in ONE dispatch (was 5).
// ---------------------------------------------------------------------------
__global__ __launch_bounds__(64) void prep_all(
    const float* __restrict__ m1W, const float* __restrict__ m1b,
    const float* __restrict__ i1W, const float* __restrict__ i1b,
    const float* __restrict__ dW_ih, const float* __restrict__ dW_hh,
    const float* __restrict__ db_ih, const float* __restrict__ db_hh,
    unsigned short* __restrict__ W1hi, unsigned short* __restrict__ W1lo,
    float* __restrict__ b1f,
    unsigned short* __restrict__ Wi1hi, unsigned short* __restrict__ Wi1lo,
    float* __restrict__ bi1f,
    float* __restrict__ Wc, float* __restrict__ bc)
{
    const int b = blockIdx.x, l = threadIdx.x;
    if (b < 128) {
        wfrag_body(m1W, 128, b, l, W1hi, W1lo);
    } else if (b < 2304) {
        wfrag_body(i1W, 1088, b - 128, l, Wi1hi, Wi1lo);
    } else if (b < 2312) {
        const int i = (b - 2304) * 64 + l;    // 512
        b1f[i] = m1b[i];
    } else if (b < 2328) {
        const int i = (b - 2312) * 64 + l;    // 1024
        bi1f[i] = i1b[i];
    } else {
        const int idx = (b - 2328) * 64 + l;  // 16640
        if (idx < 16384) Wc[idx] = dW_ih[idx] + dW_hh[idx];
        else if (idx < 16640) bc[idx - 16384] = db_ih[idx - 16384] + db_hh[idx - 16384];
    }
}

// ---------------------------------------------------------------------------
// prep_w2: W2 frag-split with BN1 scale folded INLINE from acc1 + bias fold.
// ---------------------------------------------------------------------------
__global__ __launch_bounds__(64) void prep_w2(
    const float* __restrict__ W,      // m2W [1024,512]
    const float* __restrict__ b2,     // m2b
    const float* __restrict__ acc1,   // [2*512]
    const float* __restrict__ g1, const float* __restrict__ be1,
    float invN,
    unsigned short* __restrict__ Whi, unsigned short* __restrict__ Wlo,
    float* __restrict__ bout)
{
    const int K = 512, nKc = 16;
    const int blk = blockIdx.x, l = threadIdx.x;
    if (blk < 1024) {
        const int ti = blk / nKc, kc = blk - ti * nKc;
        const int n = ti * 16 + (l & 15);
        const int k0 = kc * 32 + (l >> 4) * 8;
        const long ob = ((long)blk * 64 + l) * 8;
#pragma unroll
        for (int j = 0; j < 8; ++j) {
            const int k = k0 + j;
            const float mean = acc1[k] * invN;
            const float var  = acc1[512 + k] * invN - mean * mean;
            const float sc   = g1[k] * rsqrtf(var + EPS_BN);
            const float v = W[(long)n * K + k] * sc;
            Whi[ob + j] = f2bf(v);
            Wlo[ob + j] = f2bf(v - bf_hi(v));
        }
    } else {
        const int n = blk - 1024;
        float s = 0.f;
        for (int k = l; k < K; k += 64) {
            const float mean = acc1[k] * invN;
            const float var  = acc1[512 + k] * invN - mean * mean;
            const float sc   = g1[k] * rsqrtf(var + EPS_BN);
            const float sh   = be1[k] - mean * sc;
            s += sh * W[(long)n * K + k];
        }
#pragma unroll
        for (int m = 32; m >= 1; m >>= 1) s += __shfl_xor(s, m, 64);
        if (l == 0) bout[n] = b2[n] + s;
    }
}

// ---------------------------------------------------------------------------
// Split-activation MFMA GEMM v7 (this round): 2-DEEP PREFETCH with counted
// vmcnt (T3/T4). R7 counters: swizzle fixed conflicts (262K) but dur stayed
// 160us — the T2 regime-gate: with __syncthreads the critical path is the
// stage->vmcnt(0)->barrier drain (~600cy HBM latency vs 240cy compute slack).
// New schedule: 3-buffer LDS rotation; per iteration issue
//   [stageA(k+2): 4 gload_lds] SB [loadB(k+1): 8 loads] SB [compute(k)]
//   s_waitcnt vmcnt(12); raw s_barrier; SB
// where SB = sched_barrier(0) pins issue order. CORRECTNESS (counted-vmcnt
// proof, m135 in-order retirement): at the wait, the 12 newest vmem ops are
// exactly stage(k+2)+B(k+1), so vmcnt(12) retires stage(k+1) and B(k) and
// everything older. Every wave passes the barrier only after ITS stage(k+1)
// landed -> all of buffer (k+1)%3 visible to all waves next iteration.
// Buffer overwrite safety: stage(k+2) targets the buffer consumed at k-1,
// already released by the k-1 barrier. Prologue outstanding = S(0)4+S(1)4+
// B(0)8 = 16 -> vmcnt(12) waits S(0). Tail: vmcnt(12) trivially satisfied.
// stage(k+1) now has ~2 compute phases + 2 barriers (~700cy) to land.
// launch_bounds (256,2) LOAD-BEARING. nKc must be EVEN. gridDim.y % 8 == 0.
// Epilogue: LDS segment-max pool (span<=90 with 48KB As), interior-sid plain
// stores + boundary atomicMax; fallback to direct atomics.
// ---------------------------------------------------------------------------
__global__ __launch_bounds__(256, 2) void gemm_split(
    const unsigned short* __restrict__ Ahi,
    const unsigned short* __restrict__ Alo,
    const unsigned short* __restrict__ Whi,
    const unsigned short* __restrict__ Wlo,
    const float* __restrict__ bias,
    float* __restrict__ Yf,
    unsigned short* __restrict__ Yhi,
    unsigned short* __restrict__ Ylo,
    float* __restrict__ accum,
    const int* __restrict__ segp,
    float* __restrict__ poolmax,
    int M, int K, int O)
{
    __shared__ unsigned short As[3][2][128 * 32];   // 3-deep rotation, linear
    __shared__ int segl[128];
    const int t = threadIdx.x;
    const int lane = t & 63;
    const int w = t >> 6;
    const int wm = w & 1, wn = w >> 1;

    // XCD swizzle: flat -> (row panel, col panel)
    const int nx = gridDim.x;
    const int flat = blockIdx.y * nx + blockIdx.x;
    const int grp = flat / (8 * nx);
    const int loc = flat - grp * (8 * nx);
    const int m0 = (grp * 8 + (loc & 7)) * 128;
    const int n0 = (loc >> 3) * 128;
    const int nKc = K >> 5;   // even

    f32x4 acc[4][4];
#pragma unroll
    for (int mt = 0; mt < 4; ++mt)
#pragma unroll
    for (int nt = 0; nt < 4; ++nt) acc[mt][nt] = (f32x4)0.f;

    // A staging: wave w owns local rows [w*32, w*32+32) in 2 chunks of 16.
    const int rloc0 = w * 32 + (lane >> 2);
    const int rloc1 = rloc0 + 16;
    const int sd = lane & 3;
    const unsigned short* gsrc[2][2];
    gsrc[0][0] = Ahi + (long)(m0 + rloc0) * K + (sd ^ ((rloc0 >> 1) & 3)) * 8;
    gsrc[0][1] = Ahi + (long)(m0 + rloc1) * K + (sd ^ ((rloc1 >> 1) & 3)) * 8;
    gsrc[1][0] = Alo + (long)(m0 + rloc0) * K + (sd ^ ((rloc0 >> 1) & 3)) * 8;
    gsrc[1][1] = Alo + (long)(m0 + rloc1) * K + (sd ^ ((rloc1 >> 1) & 3)) * 8;

    unsigned short* asBase = &As[0][0][0];
    const unsigned PLANE = 128 * 32;   // shorts per plane
    const unsigned BUFS  = 2 * PLANE;  // shorts per buffer

    auto stageA = [&](unsigned bufOff, int kc) {
#pragma unroll
        for (int pp = 0; pp < 2; ++pp)
#pragma unroll
        for (int cc = 0; cc < 2; ++cc)
            gload16(gsrc[pp][cc] + kc * 32,
                    asBase + bufOff + pp * PLANE + (w * 32 + cc * 16) * 32);
    };

    // read-side swizzled slot (shorts offset); mt- and wm-independent.
    const int s2 = ((lane >> 4) ^ ((lane >> 1) & 3)) * 8;
    const int arow = wm * 64 + (lane & 15);
    const long bt0 = (long)((n0 >> 4) + wn * 4);

    auto loadB = [&](BFrag* bh, BFrag* bl, int kc) {
#pragma unroll
        for (int nt = 0; nt < 4; ++nt) {
            const long fb = ((bt0 + nt) * nKc + kc) * 512 + lane * 8;
            bh[nt].u = *(const uint4*)(Whi + fb);
            bl[nt].u = *(const uint4*)(Wlo + fb);
        }
    };
    auto compute = [&](unsigned bufOff, BFrag* bh, BFrag* bl) {
        BFrag afh[4], afl[4];
#pragma unroll
        for (int mt = 0; mt < 4; ++mt) {
            afh[mt].u = *(const uint4*)(asBase + bufOff + (arow + mt * 16) * 32 + s2);
            afl[mt].u = *(const uint4*)(asBase + bufOff + PLANE + (arow + mt * 16) * 32 + s2);
        }
#pragma unroll
        for (int nt = 0; nt < 4; ++nt)
#pragma unroll
        for (int mt = 0; mt < 4; ++mt) {
            f32x4 a = acc[mt][nt];
            a = __builtin_amdgcn_mfma_f32_16x16x32_bf16(afh[mt].v, bh[nt].v, a, 0, 0, 0);
            a = __builtin_amdgcn_mfma_f32_16x16x32_bf16(afh[mt].v, bl[nt].v, a, 0, 0, 0);
            a = __builtin_amdgcn_mfma_f32_16x16x32_bf16(afl[mt].v, bh[nt].v, a, 0, 0, 0);
            acc[mt][nt] = a;
        }
    };

    BFrag bhA[4], blA[4], bhB[4], blB[4];
    // prologue: 2-deep prefetch
    stageA(0, 0);
    stageA(BUFS, 1);
    __builtin_amdgcn_sched_barrier(0);
    loadB(bhA, blA, 0);
    __builtin_amdgcn_sched_barrier(0);
    asm volatile("s_waitcnt vmcnt(12)" ::: "memory");
    __builtin_amdgcn_s_barrier();
    __builtin_amdgcn_sched_barrier(0);

    unsigned oc = 0, on = BUFS, op = 2 * BUFS;
#pragma unroll 2
    for (int kc = 0; kc < nKc; ++kc) {
        if (kc + 2 < nKc) stageA(op, kc + 2);
        __builtin_amdgcn_sched_barrier(0);
        if (kc + 1 < nKc) {
            if (kc & 1) loadB(bhA, blA, kc + 1);
            else        loadB(bhB, blB, kc + 1);
        }
        __builtin_amdgcn_sched_barrier(0);
        if (kc & 1) compute(oc, bhB, blB);
        else        compute(oc, bhA, blA);
        asm volatile("s_waitcnt vmcnt(12)" ::: "memory");
        __builtin_amdgcn_s_barrier();
        __builtin_amdgcn_sched_barrier(0);
        const unsigned tmp = oc; oc = on; on = op; op = tmp;
    }

    int sid0 = 0, span = 0;
    bool useLds = false;
    float* pool = nullptr;
    if (segp) {
        __syncthreads();                 // As is dead after this point
        if (t < 128) segl[t] = segp[m0 + t];
        __syncthreads();
        sid0 = segl[0];
        span = segl[127] - sid0 + 1;     // sorted ids -> contiguous range
        pool = (float*)&As[0][0][0];     // reuse As as [span][132] fp32 pool
        useLds = (span <= 90);           // 90*132*4 = 47.5 KB <= 48 KB
        if (useLds) {
            for (int i = t; i < span * 132; i += 256) pool[i] = 0.f;
            __syncthreads();
        }
    }

    const int cn = lane & 15, cq = lane >> 4;
#pragma unroll
    for (int nt = 0; nt < 4; ++nt) {
        const int cl = wn * 64 + nt * 16 + cn;   // column local to n-panel
        const int n = n0 + cl;
        const float bs = bias[n];
        float s = 0.f, ssq = 0.f;
#pragma unroll
        for (int mt = 0; mt < 4; ++mt) {
            const int mb = wm * 64 + mt * 16 + cq * 4;
            float vmax = 0.f; int sid = -1;
#pragma unroll
            for (int r = 0; r < 4; ++r) {
                const float v = fmaxf(acc[mt][nt][r] + bs, 0.f);
                s += v; ssq += v * v;
                if (segp) {
                    const int sr = segl[mb + r];
                    if (r == 0) { vmax = v; sid = sr; }
                    else if (sr == sid) { vmax = fmaxf(vmax, v); }
                    else {
                        if (vmax > 0.f) {
                            if (useLds)
                                atomicMax((int*)&pool[(sid - sid0) * 132 + cl], __float_as_int(vmax));
                            else
                                atomicMax((int*)&poolmax[(long)sid * O + n], __float_as_int(vmax));
                        }
                        sid = sr; vmax = v;
                    }
                } else if (Yf) {
                    Yf[(long)(m0 + mb + r) * O + n] = v;
                } else {
                    const long idx = (long)(m0 + mb + r) * O + n;
                    Yhi[idx] = f2bf(v);
                    Ylo[idx] = f2bf(v - bf_hi(v));
                }
            }
            if (segp && vmax > 0.f) {
                if (useLds)
                    atomicMax((int*)&pool[(sid - sid0) * 132 + cl], __float_as_int(vmax));
                else
                    atomicMax((int*)&poolmax[(long)sid * O + n], __float_as_int(vmax));
            }
        }
        if (accum) {
            s   += __shfl_xor(s, 16, 64);   ssq += __shfl_xor(ssq, 16, 64);
            s   += __shfl_xor(s, 32, 64);   ssq += __shfl_xor(ssq, 32, 64);
            if (cq == 0) {
                atomicAdd(&accum[n], s);
                atomicAdd(&accum[O + n], ssq);
            }
        }
    }

    if (segp && useLds) {
        __syncthreads();
        // interior sids: unique writer -> plain store; boundary sids ->
        // global atomicMax. Absent sids are globally empty (sorted ids).
        for (int e = t; e < span * 128; e += 256) {
            const int sl = e >> 7, c = e & 127;
            const float v = pool[sl * 132 + c];
            const long gi = (long)(sid0 + sl) * O + (n0 + c);
            if (sl == 0 || sl == span - 1) {
                if (v > 0.f) atomicMax((int*)&poolmax[gi], __float_as_int(v));
            } else {
                poolmax[gi] = v;
            }
        }
    }
}

__global__ __launch_bounds__(256) void bn_finalize(
    const float* __restrict__ accum, const float* __restrict__ g,
    const float* __restrict__ be, int O, float invM,
    float* __restrict__ scale, float* __restrict__ shift)
{
    const int o = blockIdx.x * 256 + threadIdx.x;
    if (o < O) {
        const float mean = accum[o] * invM;
        const float var  = accum[O + o] * invM - mean * mean;
        const float sc   = g[o] * rsqrtf(var + EPS_BN);
        scale[o] = sc;
        shift[o] = be[o] - mean * sc;
    }
}

// ---------------------------------------------------------------------------
// d0 = concat( BN2(poolmax) or 0 (empty segment), agent_h ) -> hi/lo.
// BN2 computed INLINE from acc2.
// ---------------------------------------------------------------------------
__global__ __launch_bounds__(256) void build_d0(
    const float* __restrict__ poolraw, const float* __restrict__ agent_h,
    const int* __restrict__ seg, int N,
    const float* __restrict__ acc2, const float* __restrict__ g2,
    const float* __restrict__ be2, float invN,
    unsigned short* __restrict__ d0hi, unsigned short* __restrict__ d0lo)
{
    const int b = blockIdx.x;
    int l = 0, h = N;
    while (l < h) { const int mid = (l + h) >> 1; if (seg[mid] < b) l = mid + 1; else h = mid; }
    const bool nonempty = (l < N) && (seg[l] == b);
    for (int c = threadIdx.x; c < 1088; c += 256) {
        float v;
        if (c < 1024) {
            const float mean = acc2[c] * invN;
            const float var  = acc2[1024 + c] * invN - mean * mean;
            const float sc   = g2[c] * rsqrtf(var + EPS_BN);
            const float sh   = be2[c] - mean * sc;
            v = nonempty ? fmaf(sc, poolraw[(long)b * 1024 + c], sh) : 0.f;
        } else {
            v = agent_h[(long)b * 64 + (c - 1024)];
        }
        d0hi[(long)b * 1088 + c] = f2bf(v);
        d0lo[(long)b * 1088 + c] = f2bf(v - bf_hi(v));
    }
}

// ---------------------------------------------------------------------------
// i2 K-split partial GEMM (fp32, O=64): grid (M/128, KS).
// ---------------------------------------------------------------------------
__global__ __launch_bounds__(256) void gemm_i2_part(
    const float* __restrict__ A,   // [M, K] fp32
    const float* __restrict__ W,   // [64, K]
    const float* __restrict__ ascale, const float* __restrict__ ashift,
    float* __restrict__ part, int M, int K, int kchunk)
{
    __shared__ float As[16][132];
    __shared__ float Bs[16][68];
    const int t = threadIdx.x;
    const int m0 = blockIdx.x * 128;
    const int ks = blockIdx.y;
    const int kbeg = ks * kchunk;
    const int kend = kbeg + kchunk;
    const int tm = (t & 15) * 8;
    const int tn = (t >> 4) * 4;
    const int ar = t >> 1;          // 0..127
    const int ac = (t & 1) * 8;     // 0 or 8
    const int br = t >> 2;          // 0..63
    const int bc = (t & 3) * 4;     // 0,4,8,12

    float acc[8][4];
#pragma unroll
    for (int i = 0; i < 8; ++i)
#pragma unroll
    for (int j = 0; j < 4; ++j) acc[i][j] = 0.f;

    for (int k0 = kbeg; k0 < kend; k0 += 16) {
        float4 a0 = *(const float4*)&A[(long)(m0+ar)*K + k0 + ac];
        float4 a1 = *(const float4*)&A[(long)(m0+ar)*K + k0 + ac + 4];
        float4 s0 = *(const float4*)&ascale[k0 + ac];
        float4 s1 = *(const float4*)&ascale[k0 + ac + 4];
        float4 h0 = *(const float4*)&ashift[k0 + ac];
        float4 h1 = *(const float4*)&ashift[k0 + ac + 4];
        a0.x = fmaf(a0.x, s0.x, h0.x); a0.y = fmaf(a0.y, s0.y, h0.y);
        a0.z = fmaf(a0.z, s0.z, h0.z); a0.w = fmaf(a0.w, s0.w, h0.w);
        a1.x = fmaf(a1.x, s1.x, h1.x); a1.y = fmaf(a1.y, s1.y, h1.y);
        a1.z = fmaf(a1.z, s1.z, h1.z); a1.w = fmaf(a1.w, s1.w, h1.w);
        float4 b0 = *(const float4*)&W[(long)br*K + k0 + bc];
        __syncthreads();
        As[ac+0][ar] = a0.x; As[ac+1][ar] = a0.y; As[ac+2][ar] = a0.z; As[ac+3][ar] = a0.w;
        As[ac+4][ar] = a1.x; As[ac+5][ar] = a1.y; As[ac+6][ar] = a1.z; As[ac+7][ar] = a1.w;
        Bs[bc+0][br] = b0.x; Bs[bc+1][br] = b0.y; Bs[bc+2][br] = b0.z; Bs[bc+3][br] = b0.w;
        __syncthreads();
#pragma unroll
        for (int kk = 0; kk < 16; ++kk) {
            float av[8], bv[4];
            *(float4*)&av[0] = *(const float4*)&As[kk][tm];
            *(float4*)&av[4] = *(const float4*)&As[kk][tm + 4];
            *(float4*)&bv[0] = *(const float4*)&Bs[kk][tn];
#pragma unroll
            for (int i = 0; i < 8; ++i)
#pragma unroll
            for (int j = 0; j < 4; ++j)
                acc[i][j] = fmaf(av[i], bv[j], acc[i][j]);
        }
    }

    float* po = part + (long)ks * M * 64;
#pragma unroll
    for (int i = 0; i < 8; ++i)
        *(float4*)&po[(long)(m0 + tm + i) * 64 + tn] = *(float4*)&acc[i][0];
}

// ---------------------------------------------------------------------------
// t2 = relu(sum_ks part + bias) + fused column stats -> acc4.
// ---------------------------------------------------------------------------
__global__ __launch_bounds__(256) void i2_finish_stats(
    const float* __restrict__ part, const float* __restrict__ bias,
    int M, int KS, float* __restrict__ t2, float* __restrict__ accum)
{
    __shared__ float l1[256], l2[256];
    const int t = threadIdx.x;
    const long base = (long)blockIdx.x * 2048;
    float s = 0.f, ss = 0.f;
#pragma unroll
    for (int k = 0; k < 8; ++k) {
        const long idx = base + k * 256 + t;
        float v = 0.f;
        for (int ks = 0; ks < KS; ++ks) v += part[(long)ks * M * 64 + idx];
        v = fmaxf(v + bias[idx & 63], 0.f);
        t2[idx] = v;
        s += v; ss += v * v;
    }
    l1[t] = s; l2[t] = ss;
    __syncthreads();
    if (t < 64) {
        s  = l1[t] + l1[t + 64] + l1[t + 128] + l1[t + 192];
        ss = l2[t] + l2[t + 64] + l2[t + 128] + l2[t + 192];
        atomicAdd(&accum[t], s);
        atomicAdd(&accum[64 + t], ss);
    }
}

// ---------------------------------------------------------------------------
// Autoregressive decoder: 30 LSTMCell steps (input == h), fused prediction.
// BN4 computed INLINE from acc4.
// ---------------------------------------------------------------------------
__global__ __launch_bounds__(256) void decoder_kernel(
    const float* __restrict__ t2, const float* __restrict__ acc4,
    const float* __restrict__ ig2, const float* __restrict__ ib2, float invB,
    const float* __restrict__ agent_c,
    const float* __restrict__ Wc, const float* __restrict__ bc,
    const float* __restrict__ pW, const float* __restrict__ pb,
    float* __restrict__ pred /*[B,30,2]*/)
{
    __shared__ float h_lds[2][64];
    __shared__ float zg_lds[2][64];
    __shared__ float zo_lds[2][64];
    const int t = threadIdx.x;
    const int lane = t & 63;
    const int wave = t >> 6;
    const int s = wave >> 1;
    const int role = wave & 1;
    const long seq = (long)blockIdx.x * 2 + s;

    const int r0 = role * 128 + lane;
    const int r1 = r0 + 64;
    float w0[64], w1[64];
#pragma unroll
    for (int k = 0; k < 64; k += 4) {
        float4 va = *(const float4*)&Wc[r0 * 64 + k];
        w0[k] = va.x; w0[k+1] = va.y; w0[k+2] = va.z; w0[k+3] = va.w;
        float4 vb = *(const float4*)&Wc[r1 * 64 + k];
        w1[k] = vb.x; w1[k+1] = vb.y; w1[k+2] = vb.z; w1[k+3] = vb.w;
    }
    const float bias0 = bc[r0];
    const float bias1 = bc[r1];
    const float pw0 = pW[lane], pw1 = pW[64 + lane];
    const float pb0 = pb[0], pb1 = pb[1];

    float c = agent_c[seq*64 + lane];
    if (role == 0) {
        const float mean = acc4[lane] * invB;
        const float var  = acc4[64 + lane] * invB - mean * mean;
        const float sc   = ig2[lane] * rsqrtf(var + EPS_BN);
        const float sh   = ib2[lane] - mean * sc;
        h_lds[s][lane] = fmaf(sc, t2[seq*64 + lane], sh);
    }
    __syncthreads();
    float hv = h_lds[s][lane];

    for (int step = 0; step < 30; ++step) {
        float z0 = bias0, z1 = bias1;
#pragma unroll
        for (int k = 0; k < 64; ++k) {
            float hk = __int_as_float(__builtin_amdgcn_readlane(__float_as_int(hv), k));
            z0 = fmaf(hk, w0[k], z0);
            z1 = fmaf(hk, w1[k], z1);
        }
        if (role == 1) { zg_lds[s][lane] = z0; zo_lds[s][lane] = z1; }
        __syncthreads();
        if (role == 0) {
            const float ig = sigmoid_f(z0);
            const float fg = sigmoid_f(z1);
            const float gg = tanh_f(zg_lds[s][lane]);
            const float og = sigmoid_f(zo_lds[s][lane]);
            c = fmaf(fg, c, ig * gg);
            h_lds[s][lane] = og * tanh_f(c);
        }
        __syncthreads();
        hv = h_lds[s][lane];
        if (role == 0) {
            float p0 = hv * pw0;
            float p1 = hv * pw1;
#pragma unroll
            for (int m = 32; m >= 1; m >>= 1) {
                p0 += __shfl_xor(p0, m, 64);
                p1 += __shfl_xor(p1, m, 64);
            }
            if (lane == 0) {
                pred[seq*60 + step*2 + 0] = p0 + pb0;
                pred[seq*60 + step*2 + 1] = p1 + pb1;
            }
        }
    }
}

// ---------------------------------------------------------------------------
extern "C" void kernel_launch(void* const* d_in, const int* in_sizes, int n_in,
                              void* d_out, int out_size, void* d_ws, size_t ws_size,
                              hipStream_t stream)
{
    const float* agent_traj = (const float*)d_in[0];
    const float* neighbours = (const float*)d_in[1];
    const float* aW_ih = (const float*)d_in[2];
    const float* aW_hh = (const float*)d_in[3];
    const float* ab_ih = (const float*)d_in[4];
    const float* ab_hh = (const float*)d_in[5];
    const float* nW_ih = (const float*)d_in[6];
    const float* nW_hh = (const float*)d_in[7];
    const float* nb_ih = (const float*)d_in[8];
    const float* nb_hh = (const float*)d_in[9];
    const float* dW_ih = (const float*)d_in[10];
    const float* dW_hh = (const float*)d_in[11];
    const float* db_ih = (const float*)d_in[12];
    const float* db_hh = (const float*)d_in[13];
    const float* pW = (const float*)d_in[14];
    const float* pb = (const float*)d_in[15];
    const float* rW = (const float*)d_in[16];
    const float* rb = (const float*)d_in[17];
    const float* m1W = (const float*)d_in[18];
    const float* m1b = (const float*)d_in[19];
    const float* g1  = (const float*)d_in[20];
    const float* be1 = (const float*)d_in[21];
    const float* m2W = (const float*)d_in[22];
    const float* m2b = (const float*)d_in[23];
    const float* g2  = (const float*)d_in[24];
    const float* be2 = (const float*)d_in[25];
    const float* i1W = (const float*)d_in[26];
    const float* i1b = (const float*)d_in[27];
    const float* ig1 = (const float*)d_in[28];
    const float* ib1 = (const float*)d_in[29];
    const float* i2W = (const float*)d_in[30];
    const float* i2b = (const float*)d_in[31];
    const float* ig2 = (const float*)d_in[32];
    const float* ib2 = (const float*)d_in[33];
    const int*   seg = (const int*)d_in[34];
    float* pred = (float*)d_out;

    const int B = 2048, T = 20, N = 32768;

    char* p = (char*)d_ws;
    auto alloc = [&](size_t bytes) -> char* {
        char* r = p; p += (bytes + 255) & ~(size_t)255; return r;
    };
    float* agent_h = (float*)alloc((size_t)B*64*4);
    float* agent_c = (float*)alloc((size_t)B*64*4);
    char* neigh_region = alloc((size_t)N*64*4);          // t1 (fp32 B*1024)
    unsigned short* x0hi = (unsigned short*)alloc((size_t)N*128*2);
    unsigned short* x0lo = (unsigned short*)alloc((size_t)N*128*2);
    char* y1hi_region  = alloc((size_t)N*512*2);         // y1hi, later d0hi/d0lo/t2
    unsigned short* y1lo = (unsigned short*)alloc((size_t)N*512*2);
    float* poolraw = (float*)alloc((size_t)B*1024*4);    // 8 MB, zero-init
    float* accAll = (float*)alloc((size_t)(1024+2048+2048+128)*4);
    float* acc1 = accAll;            // 2*512
    float* acc2 = accAll + 1024;     // 2*1024
    float* acc3 = accAll + 3072;     // 2*1024
    float* acc4 = accAll + 5120;     // 2*64
    float* sc3 = (float*)alloc(1024*4); float* sh3 = (float*)alloc(1024*4);
    float* Wc = (float*)alloc(256*64*4);
    float* bc = (float*)alloc(256*4);
    unsigned short* W1hi = (unsigned short*)alloc((size_t)512*128*2);
    unsigned short* W1lo = (unsigned short*)alloc((size_t)512*128*2);
    unsigned short* W2hi = (unsigned short*)alloc((size_t)1024*512*2);
    unsigned short* W2lo = (unsigned short*)alloc((size_t)1024*512*2);
    unsigned short* Wi1hi = (unsigned short*)alloc((size_t)1024*1088*2);
    unsigned short* Wi1lo = (unsigned short*)alloc((size_t)1024*1088*2);
    float* b1f = (float*)alloc(512*4);
    float* b2f = (float*)alloc(1024*4);
    float* bi1f = (float*)alloc(1024*4);
    float* i2part = (float*)alloc((size_t)8*B*64*4);     // 4 MB partials

    // aliases (lifetimes disjoint, stream-ordered)
    float* t1 = (float*)neigh_region;            // i1 output (fp32 B*1024)
    unsigned short* y1hi = (unsigned short*)y1hi_region;
    unsigned short* d0hi = (unsigned short*)y1hi_region;          // after MLP2
    unsigned short* d0lo = d0hi + (size_t)B*1088;
    float* t2 = (float*)(y1hi_region + (size_t)2*B*1088*2);

    hipMemsetAsync(accAll, 0, (1024+2048+2048+128)*sizeof(float), stream);
    hipMemsetAsync(poolraw, 0, (size_t)B*1024*4, stream);

    // all BN-independent preps in one dispatch (was 5)
    prep_all<<<2588, 64, 0, stream>>>(m1W, m1b, i1W, i1b, dW_ih, dW_hh, db_ih, db_hh,
                                      W1hi, W1lo, b1f, Wi1hi, Wi1lo, bi1f, Wc, bc);

    // merged agent+neighbour LSTM with fused x0 build
    lstm_mfma<<<B/32 + N/32, 256, 0, stream>>>(
        agent_traj, aW_ih, aW_hh, ab_ih, ab_hh, agent_h, agent_c,
        neighbours, nW_ih, nW_hh, nb_ih, nb_hh,
        seg, rW, rb, x0hi, x0lo, B/32, T);

    // MLP1 (fused colstats -> acc1)
    gemm_split<<<dim3(512/128, N/128), 256, 0, stream>>>(
        x0hi, x0lo, W1hi, W1lo, b1f, nullptr, y1hi, y1lo, acc1,
        nullptr, nullptr, N, 128, 512);

    // W2 prep with BN1 folded inline
    prep_w2<<<2048, 64, 0, stream>>>(m2W, m2b, acc1, g1, be1, 1.0f/N,
                                     W2hi, W2lo, b2f);

    // MLP2 (fused colstats -> acc2, fused LDS-reduced segment-max -> poolraw)
    gemm_split<<<dim3(1024/128, N/128), 256, 0, stream>>>(
        y1hi, y1lo, W2hi, W2lo, b2f, nullptr, nullptr, nullptr, acc2,
        seg, poolraw, N, 512, 1024);

    // d0 with BN2 inline
    build_d0<<<B, 256, 0, stream>>>(poolraw, agent_h, seg, N, acc2, g2, be2,
                                    1.0f/N, d0hi, d0lo);

    // i1 (fused colstats -> acc3)
    gemm_split<<<dim3(1024/128, B/128), 256, 0, stream>>>(
        d0hi, d0lo, Wi1hi, Wi1lo, bi1f, t1, nullptr, nullptr, acc3,
        nullptr, nullptr, B, 1088, 1024);
    bn_finalize<<<4, 256, 0, stream>>>(acc3, ig1, ib1, 1024, 1.0f/B, sc3, sh3);

    // i2: K-split partials + finish (with fused column stats -> acc4)
    gemm_i2_part<<<dim3(B/128, 8), 256, 0, stream>>>(t1, i2W, sc3, sh3, i2part,
                                                     B, 1024, 128);
    i2_finish_stats<<<64, 256, 0, stream>>>(i2part, i2b, B, 8, t2, acc4);

    // decoder with BN4 inline
    decoder_kernel<<<B/2, 256, 0, stream>>>(t2, acc4, ig2, ib2, 1.0f/B,
                                            agent_c, Wc, bc, pW, pb, pred);
}

// Round 9
// 583.169 us; speedup vs baseline: 1.1325x; 1.1325x over previous
//
#include <hip/hip_runtime.h>

#define EPS_BN 1e-5f

typedef __attribute__((ext_vector_type(8))) short short8;
typedef __attribute__((ext_vector_type(4))) float f32x4;

__device__ __forceinline__ float fast_rcp(float x) { return __builtin_amdgcn_rcpf(x); }
__device__ __forceinline__ float sigmoid_f(float x) { return fast_rcp(1.0f + __expf(-x)); }
// robust tanh: no inf/inf NaN at large |x|
__device__ __forceinline__ float tanh_f(float x) { return 1.0f - 2.0f * fast_rcp(__expf(2.0f * x) + 1.0f); }

// round-to-nearest-even fp32 -> bf16 bits
__device__ __forceinline__ unsigned short f2bf(float f) {
    unsigned u = __float_as_uint(f);
    u += 0x7FFFu + ((u >> 16) & 1u);
    return (unsigned short)(u >> 16);
}
__device__ __forceinline__ unsigned pk_bf(float a, float b) {
    return (unsigned)f2bf(a) | ((unsigned)f2bf(b) << 16);
}
// value of the bf16 rounding (hi part); residual = f - bf_hi(f)
__device__ __forceinline__ float bf_hi(float f) {
    return __uint_as_float((unsigned)f2bf(f) << 16);
}

// async global -> LDS, 16 bytes per lane (dest is wave-uniform base + lane*16)
__device__ __forceinline__ void gload16(const unsigned short* g, unsigned short* l) {
    __builtin_amdgcn_global_load_lds(
        (const __attribute__((address_space(1))) unsigned int*)g,
        (__attribute__((address_space(3))) unsigned int*)l,
        16, 0, 0);
}

union AFrag { short e[8]; short8 v; };
union BFrag { uint4 u; short8 v; };

// ---------------------------------------------------------------------------
// Split-precision MFMA LSTM encoder v7 — MERGED dispatch, 32 seqs/block.
// LAUNCH BOUNDS: (256,2) is LOAD-BEARING (R4: (256,4) clamps VGPR -> spill).
// v6: merged-activation epilogue (5 rcp -> 3 rcp per element).
// v7: build_x0 fused into the neighbour epilogue. R7 verified (579.7us e2e).
// ---------------------------------------------------------------------------
__global__ __launch_bounds__(256, 2) void lstm_mfma(
    const float* __restrict__ xA,      // agent_traj [SA, T, 2]
    const float* __restrict__ aW_ih, const float* __restrict__ aW_hh,
    const float* __restrict__ ab_ih, const float* __restrict__ ab_hh,
    float* __restrict__ agent_h, float* __restrict__ agent_c,
    const float* __restrict__ xN,      // neighbours [SN, T, 2]
    const float* __restrict__ nW_ih, const float* __restrict__ nW_hh,
    const float* __restrict__ nb_ih, const float* __restrict__ nb_hh,
    const int* __restrict__ seg, const float* __restrict__ rW,
    const float* __restrict__ rb,
    unsigned short* __restrict__ x0hi, unsigned short* __restrict__ x0lo,
    int nAgentBlk, int T)
{
    __shared__ unsigned h_ex[2][2][32 * 52];   // [buf][hi/lo][32 seqs x 52]

    const bool isA = (blockIdx.x < (unsigned)nAgentBlk);
    const long blk = isA ? blockIdx.x : blockIdx.x - nAgentBlk;
    const float* __restrict__ x     = isA ? xA   : xN;
    const float* __restrict__ W_ih  = isA ? aW_ih : nW_ih;
    const float* __restrict__ W_hh  = isA ? aW_hh : nW_hh;
    const float* __restrict__ b_ih  = isA ? ab_ih : nb_ih;
    const float* __restrict__ b_hh  = isA ? ab_hh : nb_hh;

    const int tid  = threadIdx.x;
    const int w    = tid >> 6;        // cell-group == wave
    const int lane = tid & 63;
    const int s    = lane & 15;       // sequence within the 16 (per B-group)
    const int q    = lane >> 4;       // quad

    short8 ahi[4][3], alo[4][3];
#pragma unroll
    for (int gt = 0; gt < 4; ++gt) {
        const int n = gt * 64 + w * 16 + s;
#pragma unroll
        for (int kc = 0; kc < 2; ++kc) {
            const float* src = &W_hh[n * 64 + kc * 32 + q * 8];
            float4 v0 = *(const float4*)src;
            float4 v1 = *(const float4*)(src + 4);
            float v[8] = {v0.x, v0.y, v0.z, v0.w, v1.x, v1.y, v1.z, v1.w};
            AFrag a, b;
#pragma unroll
            for (int j = 0; j < 8; ++j) {
                a.e[j] = (short)f2bf(v[j]);
                b.e[j] = (short)f2bf(v[j] - bf_hi(v[j]));
            }
            ahi[gt][kc] = a.v;
            alo[gt][kc] = b.v;
        }
        AFrag a2, b2;
#pragma unroll
        for (int j = 0; j < 8; ++j) { a2.e[j] = 0; b2.e[j] = 0; }
        if (q == 0) {   // K rows 64(wi0), 65(wi1), 66(bias)
            const float wi0 = W_ih[n * 2 + 0];
            const float wi1 = W_ih[n * 2 + 1];
            const float bs  = b_ih[n] + b_hh[n];
            a2.e[0] = (short)f2bf(wi0); b2.e[0] = (short)f2bf(wi0 - bf_hi(wi0));
            a2.e[1] = (short)f2bf(wi1); b2.e[1] = (short)f2bf(wi1 - bf_hi(wi1));
            a2.e[2] = (short)f2bf(bs);  b2.e[2] = (short)f2bf(bs  - bf_hi(bs));
        }
        ahi[gt][2] = a2.v;
        alo[gt][2] = b2.v;
    }

    for (int i = tid; i < 2 * 2 * 32 * 52; i += 256) (&h_ex[0][0][0])[i] = 0u;
    __syncthreads();
    if (tid < 32) {   // seq = tid
        h_ex[0][0][tid * 52 + 33] = pk_bf(1.0f, 0.0f);
        h_ex[1][0][tid * 52 + 33] = pk_bf(1.0f, 0.0f);
        float2 xv = *(const float2*)&x[(blk * 32 + tid) * (long)(T * 2)];
        h_ex[0][0][tid * 52 + 32] = pk_bf(xv.x, xv.y);
        h_ex[0][1][tid * 52 + 32] = pk_bf(xv.x - bf_hi(xv.x), xv.y - bf_hi(xv.y));
    }
    __syncthreads();

    float creg[2][4] = {{0.f, 0.f, 0.f, 0.f}, {0.f, 0.f, 0.f, 0.f}};

    for (int t = 0; t < T; ++t) {
        const int rb_ = t & 1, wb = rb_ ^ 1;
        BFrag bhi[2][3], blo[2][3];
#pragma unroll
        for (int g = 0; g < 2; ++g)
#pragma unroll
        for (int kc = 0; kc < 3; ++kc) {
            const int off = (g * 16 + s) * 52 + kc * 16 + (q >> 1) * 8 + (q & 1) * 4;
            bhi[g][kc].u = *(const uint4*)&h_ex[rb_][0][off];
            blo[g][kc].u = *(const uint4*)&h_ex[rb_][1][off];
        }

        f32x4 acc[4][2];
#pragma unroll
        for (int gt = 0; gt < 4; ++gt) { acc[gt][0] = (f32x4)0.f; acc[gt][1] = (f32x4)0.f; }

#pragma unroll
        for (int kc = 0; kc < 3; ++kc) {
#pragma unroll
            for (int g = 0; g < 2; ++g) {
                const short8 bh = bhi[g][kc].v;
                const short8 bl = blo[g][kc].v;
#pragma unroll
                for (int gt = 0; gt < 4; ++gt) {
                    f32x4 a = acc[gt][g];
                    a = __builtin_amdgcn_mfma_f32_16x16x32_bf16(ahi[gt][kc], bh, a, 0, 0, 0);
                    a = __builtin_amdgcn_mfma_f32_16x16x32_bf16(ahi[gt][kc], bl, a, 0, 0, 0);
                    a = __builtin_amdgcn_mfma_f32_16x16x32_bf16(alo[gt][kc], bh, a, 0, 0, 0);
                    acc[gt][g] = a;
                }
            }
        }

#pragma unroll
        for (int g = 0; g < 2; ++g) {
            float hval[4];
#pragma unroll
            for (int r = 0; r < 4; ++r) {
                // merged activations: sigma(zi)*tanh(zg) and sigma(zo)*tanh(c)
                // via single-rcp rational forms (5 rcp -> 3 rcp per element).
                const float ei = __expf(-acc[0][g][r]);          // e^-zi
                const float eg = __expf(2.0f * acc[2][g][r]);    // e^2zg
                const float it = (eg - 1.0f) * fast_rcp((1.0f + ei) * (eg + 1.0f));
                const float sf = fast_rcp(1.0f + __expf(-acc[1][g][r]));
                const float c  = fmaf(sf, creg[g][r], it);
                creg[g][r] = c;
                const float eo = __expf(-acc[3][g][r]);          // e^-zo
                const float ec = __expf(2.0f * c);               // e^2c
                hval[r] = (ec - 1.0f) * fast_rcp((1.0f + eo) * (ec + 1.0f));
            }
            {
                const int w0 = (g * 16 + s) * 52 + w * 8 + q * 2;
                h_ex[wb][0][w0]     = pk_bf(hval[0], hval[1]);
                h_ex[wb][0][w0 + 1] = pk_bf(hval[2], hval[3]);
                h_ex[wb][1][w0]     = pk_bf(hval[0] - bf_hi(hval[0]), hval[1] - bf_hi(hval[1]));
                h_ex[wb][1][w0 + 1] = pk_bf(hval[2] - bf_hi(hval[2]), hval[3] - bf_hi(hval[3]));
            }
            if (t == T - 1) {
                const long seq = blk * 32 + g * 16 + s;
                const int j0 = w * 16 + q * 4;
                if (isA) {
                    *(float4*)&agent_h[seq * 64 + j0] =
                        make_float4(hval[0], hval[1], hval[2], hval[3]);
                    *(float4*)&agent_c[seq * 64 + j0] =
                        make_float4(creg[g][0], creg[g][1], creg[g][2], creg[g][3]);
                } else {
                    // x0 cols 0..63 = neigh_h (identical rounding to old path)
                    *(uint2*)&x0hi[seq * 128 + j0] = make_uint2(
                        pk_bf(hval[0], hval[1]), pk_bf(hval[2], hval[3]));
                    *(uint2*)&x0lo[seq * 128 + j0] = make_uint2(
                        pk_bf(hval[0] - bf_hi(hval[0]), hval[1] - bf_hi(hval[1])),
                        pk_bf(hval[2] - bf_hi(hval[2]), hval[3] - bf_hi(hval[3])));
                }
            }
        }
        if (tid < 32 && t + 1 < T) {
            float2 xv = *(const float2*)&x[(blk * 32 + tid) * (long)(T * 2) + (t + 1) * 2];
            h_ex[wb][0][tid * 52 + 32] = pk_bf(xv.x, xv.y);
            h_ex[wb][1][tid * 52 + 32] = pk_bf(xv.x - bf_hi(xv.x), xv.y - bf_hi(xv.y));
        }
        __syncthreads();
    }

    // x0 cols 64..127: rel_emb = rel @ rW.T + rb  (thread -> 1 seq x 8 cols)
    if (!isA) {
        const int sloc = tid >> 3;
        const long n = blk * 32 + sloc;
        const float2 np = *(const float2*)&x[n * (long)(T * 2) + (T - 1) * 2];
        const int sid = seg[n];
        const float2 ap = *(const float2*)&xA[(long)sid * (T * 2) + (T - 1) * 2];
        const float ra = np.x - ap.x, rbv = np.y - ap.y;
        const int o0 = (tid & 7) * 8;
#pragma unroll
        for (int j = 0; j < 8; ++j) {
            const int o = o0 + j;
            const float v = fmaf(rW[o * 2 + 0], ra, fmaf(rW[o * 2 + 1], rbv, rb[o]));
            x0hi[n * 128 + 64 + o] = f2bf(v);
            x0lo[n * 128 + 64 + o] = f2bf(v - bf_hi(v));
        }
    }
}

// ---------------------------------------------------------------------------
// Weight prep bodies (shared by prep_all / prep_w2).
// ---------------------------------------------------------------------------
__device__ __forceinline__ void wfrag_body(
    const float* __restrict__ W, int K, int blk, int l,
    unsigned short* __restrict__ Whi, unsigned short* __restrict__ Wlo)
{
    const int nKc = K >> 5;
    const int ti = blk / nKc, kc = blk - ti * nKc;
    const int n = ti * 16 + (l & 15);
    const int k0 = kc * 32 + (l >> 4) * 8;
    const long ob = ((long)blk * 64 + l) * 8;
#pragma unroll
    for (int j = 0; j < 8; ++j) {
        float v = W[(long)n * K + k0 + j];
        Whi[ob + j] = f2bf(v);
        Wlo[ob + j] = f2bf(v - bf_hi(v));
    }
}

// ---------------------------------------------------------------------------
// prep_all: all BN-independent weight preps in ONE dispatch (was 5).
// ---------------------------------------------------------------------------
__global__ __launch_bounds__(64) void prep_all(
    const float* __restrict__ m1W, const float* __restrict__ m1b,
    const float* __restrict__ i1W, const float* __restrict__ i1b,
    const float* __restrict__ dW_ih, const float* __restrict__ dW_hh,
    const float* __restrict__ db_ih, const float* __restrict__ db_hh,
    unsigned short* __restrict__ W1hi, unsigned short* __restrict__ W1lo,
    float* __restrict__ b1f,
    unsigned short* __restrict__ Wi1hi, unsigned short* __restrict__ Wi1lo,
    float* __restrict__ bi1f,
    float* __restrict__ Wc, float* __restrict__ bc)
{
    const int b = blockIdx.x, l = threadIdx.x;
    if (b < 128) {
        wfrag_body(m1W, 128, b, l, W1hi, W1lo);
    } else if (b < 2304) {
        wfrag_body(i1W, 1088, b - 128, l, Wi1hi, Wi1lo);
    } else if (b < 2312) {
        const int i = (b - 2304) * 64 + l;    // 512
        b1f[i] = m1b[i];
    } else if (b < 2328) {
        const int i = (b - 2312) * 64 + l;    // 1024
        bi1f[i] = i1b[i];
    } else {
        const int idx = (b - 2328) * 64 + l;  // 16640
        if (idx < 16384) Wc[idx] = dW_ih[idx] + dW_hh[idx];
        else if (idx < 16640) bc[idx - 16384] = db_ih[idx - 16384] + db_hh[idx - 16384];
    }
}

// ---------------------------------------------------------------------------
// prep_w2: W2 frag-split with BN1 scale folded INLINE from acc1 + bias fold.
// ---------------------------------------------------------------------------
__global__ __launch_bounds__(64) void prep_w2(
    const float* __restrict__ W,      // m2W [1024,512]
    const float* __restrict__ b2,     // m2b
    const float* __restrict__ acc1,   // [2*512]
    const float* __restrict__ g1, const float* __restrict__ be1,
    float invN,
    unsigned short* __restrict__ Whi, unsigned short* __restrict__ Wlo,
    float* __restrict__ bout)
{
    const int K = 512, nKc = 16;
    const int blk = blockIdx.x, l = threadIdx.x;
    if (blk < 1024) {
        const int ti = blk / nKc, kc = blk - ti * nKc;
        const int n = ti * 16 + (l & 15);
        const int k0 = kc * 32 + (l >> 4) * 8;
        const long ob = ((long)blk * 64 + l) * 8;
#pragma unroll
        for (int j = 0; j < 8; ++j) {
            const int k = k0 + j;
            const float mean = acc1[k] * invN;
            const float var  = acc1[512 + k] * invN - mean * mean;
            const float sc   = g1[k] * rsqrtf(var + EPS_BN);
            const float v = W[(long)n * K + k] * sc;
            Whi[ob + j] = f2bf(v);
            Wlo[ob + j] = f2bf(v - bf_hi(v));
        }
    } else {
        const int n = blk - 1024;
        float s = 0.f;
        for (int k = l; k < K; k += 64) {
            const float mean = acc1[k] * invN;
            const float var  = acc1[512 + k] * invN - mean * mean;
            const float sc   = g1[k] * rsqrtf(var + EPS_BN);
            const float sh   = be1[k] - mean * sc;
            s += sh * W[(long)n * K + k];
        }
#pragma unroll
        for (int m = 32; m >= 1; m >>= 1) s += __shfl_xor(s, m, 64);
        if (l == 0) bout[n] = b2[n] + s;
    }
}

// ---------------------------------------------------------------------------
// Split-activation MFMA GEMM — R7-VERIFIED version (REVERTED from the R8
// 2-deep counted-vmcnt pipeline, which REGRESSED: 160->177us, VGPR 104->128,
// VALUBusy 19->34% — the sched_barrier(0) pinning + rotating-buffer overhead
// reproduces the guide's m141 lesson. Both schedule levers are now measured
// dead ends on this 2-phase structure: T2 swizzle = null (R7, regime-gate),
// counted-vmcnt graft = regression (R8). ~160us is this structure's plateau
// (MFMA floor 41us); escape requires the full 8-phase 256-sq template.
// DO NOT re-attempt partial pipeline grafts here.
// Structure: DIRECT global_load_lds x16 A-staging, linear [128*32] LDS + XOR
// swizzle slot^=(row>>1)&3 (write side via inverse-permuted global src, read
// side on ds_read_b128). launch_bounds (256,2) LOAD-BEARING. nKc EVEN.
// gridDim.y % 8 == 0. Epilogue: LDS segment-max pool (span<=60), interior-sid
// plain stores + boundary atomicMax; fallback to direct atomics.
// ---------------------------------------------------------------------------
__global__ __launch_bounds__(256, 2) void gemm_split(
    const unsigned short* __restrict__ Ahi,
    const unsigned short* __restrict__ Alo,
    const unsigned short* __restrict__ Whi,
    const unsigned short* __restrict__ Wlo,
    const float* __restrict__ bias,
    float* __restrict__ Yf,
    unsigned short* __restrict__ Yhi,
    unsigned short* __restrict__ Ylo,
    float* __restrict__ accum,
    const int* __restrict__ segp,
    float* __restrict__ poolmax,
    int M, int K, int O)
{
    __shared__ unsigned short As[2][2][128 * 32];   // [buf][hi/lo][row*32] linear
    __shared__ int segl[128];
    const int t = threadIdx.x;
    const int lane = t & 63;
    const int w = t >> 6;
    const int wm = w & 1, wn = w >> 1;

    // XCD swizzle: flat -> (row panel, col panel)
    const int nx = gridDim.x;
    const int flat = blockIdx.y * nx + blockIdx.x;
    const int grp = flat / (8 * nx);
    const int loc = flat - grp * (8 * nx);
    const int m0 = (grp * 8 + (loc & 7)) * 128;
    const int n0 = (loc >> 3) * 128;
    const int nKc = K >> 5;   // even

    f32x4 acc[4][4];
#pragma unroll
    for (int mt = 0; mt < 4; ++mt)
#pragma unroll
    for (int nt = 0; nt < 4; ++nt) acc[mt][nt] = (f32x4)0.f;

    // A staging: wave w owns local rows [w*32, w*32+32) in 2 chunks of 16.
    const int rloc0 = w * 32 + (lane >> 2);
    const int rloc1 = rloc0 + 16;
    const int sd = lane & 3;
    const unsigned short* gsrc[2][2];
    gsrc[0][0] = Ahi + (long)(m0 + rloc0) * K + (sd ^ ((rloc0 >> 1) & 3)) * 8;
    gsrc[0][1] = Ahi + (long)(m0 + rloc1) * K + (sd ^ ((rloc1 >> 1) & 3)) * 8;
    gsrc[1][0] = Alo + (long)(m0 + rloc0) * K + (sd ^ ((rloc0 >> 1) & 3)) * 8;
    gsrc[1][1] = Alo + (long)(m0 + rloc1) * K + (sd ^ ((rloc1 >> 1) & 3)) * 8;

    auto stageA = [&](int buf, int kc) {
#pragma unroll
        for (int pp = 0; pp < 2; ++pp)
#pragma unroll
        for (int cc = 0; cc < 2; ++cc)
            gload16(gsrc[pp][cc] + kc * 32,
                    &As[buf][pp][(w * 32 + cc * 16) * 32]);
    };

    // read-side swizzled slot (shorts offset); mt- and wm-independent.
    const int s2 = ((lane >> 4) ^ ((lane >> 1) & 3)) * 8;
    const int arow = wm * 64 + (lane & 15);
    const long bt0 = (long)((n0 >> 4) + wn * 4);

    auto loadB = [&](BFrag* bh, BFrag* bl, int kc) {
#pragma unroll
        for (int nt = 0; nt < 4; ++nt) {
            const long fb = ((bt0 + nt) * nKc + kc) * 512 + lane * 8;
            bh[nt].u = *(const uint4*)(Whi + fb);
            bl[nt].u = *(const uint4*)(Wlo + fb);
        }
    };
    auto compute = [&](int buf, BFrag* bh, BFrag* bl) {
        BFrag afh[4], afl[4];
#pragma unroll
        for (int mt = 0; mt < 4; ++mt) {
            afh[mt].u = *(const uint4*)&As[buf][0][(arow + mt * 16) * 32 + s2];
            afl[mt].u = *(const uint4*)&As[buf][1][(arow + mt * 16) * 32 + s2];
        }
#pragma unroll
        for (int nt = 0; nt < 4; ++nt)
#pragma unroll
        for (int mt = 0; mt < 4; ++mt) {
            f32x4 a = acc[mt][nt];
            a = __builtin_amdgcn_mfma_f32_16x16x32_bf16(afh[mt].v, bh[nt].v, a, 0, 0, 0);
            a = __builtin_amdgcn_mfma_f32_16x16x32_bf16(afh[mt].v, bl[nt].v, a, 0, 0, 0);
            a = __builtin_amdgcn_mfma_f32_16x16x32_bf16(afl[mt].v, bh[nt].v, a, 0, 0, 0);
            acc[mt][nt] = a;
        }
    };

    BFrag bh0[4], bl0[4], bh1[4], bl1[4];
    stageA(0, 0);
    loadB(bh0, bl0, 0);
    __syncthreads();
    for (int kc = 0; kc < nKc; kc += 2) {
        stageA(1, kc + 1);
        loadB(bh1, bl1, kc + 1);
        compute(0, bh0, bl0);
        __syncthreads();
        if (kc + 2 < nKc) {
            stageA(0, kc + 2);
            loadB(bh0, bl0, kc + 2);
        }
        compute(1, bh1, bl1);
        if (kc + 2 < nKc) __syncthreads();
    }

    int sid0 = 0, span = 0;
    bool useLds = false;
    float* pool = nullptr;
    if (segp) {
        __syncthreads();                 // As is dead after this point
        if (t < 128) segl[t] = segp[m0 + t];
        __syncthreads();
        sid0 = segl[0];
        span = segl[127] - sid0 + 1;     // sorted ids -> contiguous range
        pool = (float*)&As[0][0][0];     // reuse As as [span][132] fp32 pool
        useLds = (span <= 60);           // 60*132*4 = 31.7 KB <= 32.8 KB
        if (useLds) {
            for (int i = t; i < span * 132; i += 256) pool[i] = 0.f;
            __syncthreads();
        }
    }

    const int cn = lane & 15, cq = lane >> 4;
#pragma unroll
    for (int nt = 0; nt < 4; ++nt) {
        const int cl = wn * 64 + nt * 16 + cn;   // column local to n-panel
        const int n = n0 + cl;
        const float bs = bias[n];
        float s = 0.f, ssq = 0.f;
#pragma unroll
        for (int mt = 0; mt < 4; ++mt) {
            const int mb = wm * 64 + mt * 16 + cq * 4;
            float vmax = 0.f; int sid = -1;
#pragma unroll
            for (int r = 0; r < 4; ++r) {
                const float v = fmaxf(acc[mt][nt][r] + bs, 0.f);
                s += v; ssq += v * v;
                if (segp) {
                    const int sr = segl[mb + r];
                    if (r == 0) { vmax = v; sid = sr; }
                    else if (sr == sid) { vmax = fmaxf(vmax, v); }
                    else {
                        if (vmax > 0.f) {
                            if (useLds)
                                atomicMax((int*)&pool[(sid - sid0) * 132 + cl], __float_as_int(vmax));
                            else
                                atomicMax((int*)&poolmax[(long)sid * O + n], __float_as_int(vmax));
                        }
                        sid = sr; vmax = v;
                    }
                } else if (Yf) {
                    Yf[(long)(m0 + mb + r) * O + n] = v;
                } else {
                    const long idx = (long)(m0 + mb + r) * O + n;
                    Yhi[idx] = f2bf(v);
                    Ylo[idx] = f2bf(v - bf_hi(v));
                }
            }
            if (segp && vmax > 0.f) {
                if (useLds)
                    atomicMax((int*)&pool[(sid - sid0) * 132 + cl], __float_as_int(vmax));
                else
                    atomicMax((int*)&poolmax[(long)sid * O + n], __float_as_int(vmax));
            }
        }
        if (accum) {
            s   += __shfl_xor(s, 16, 64);   ssq += __shfl_xor(ssq, 16, 64);
            s   += __shfl_xor(s, 32, 64);   ssq += __shfl_xor(ssq, 32, 64);
            if (cq == 0) {
                atomicAdd(&accum[n], s);
                atomicAdd(&accum[O + n], ssq);
            }
        }
    }

    if (segp && useLds) {
        __syncthreads();
        // interior sids: unique writer -> plain store; boundary sids ->
        // global atomicMax. Absent sids are globally empty (sorted ids).
        for (int e = t; e < span * 128; e += 256) {
            const int sl = e >> 7, c = e & 127;
            const float v = pool[sl * 132 + c];
            const long gi = (long)(sid0 + sl) * O + (n0 + c);
            if (sl == 0 || sl == span - 1) {
                if (v > 0.f) atomicMax((int*)&poolmax[gi], __float_as_int(v));
            } else {
                poolmax[gi] = v;
            }
        }
    }
}

__global__ __launch_bounds__(256) void bn_finalize(
    const float* __restrict__ accum, const float* __restrict__ g,
    const float* __restrict__ be, int O, float invM,
    float* __restrict__ scale, float* __restrict__ shift)
{
    const int o = blockIdx.x * 256 + threadIdx.x;
    if (o < O) {
        const float mean = accum[o] * invM;
        const float var  = accum[O + o] * invM - mean * mean;
        const float sc   = g[o] * rsqrtf(var + EPS_BN);
        scale[o] = sc;
        shift[o] = be[o] - mean * sc;
    }
}

// ---------------------------------------------------------------------------
// d0 = concat( BN2(poolmax) or 0 (empty segment), agent_h ) -> hi/lo.
// BN2 computed INLINE from acc2.
// ---------------------------------------------------------------------------
__global__ __launch_bounds__(256) void build_d0(
    const float* __restrict__ poolraw, const float* __restrict__ agent_h,
    const int* __restrict__ seg, int N,
    const float* __restrict__ acc2, const float* __restrict__ g2,
    const float* __restrict__ be2, float invN,
    unsigned short* __restrict__ d0hi, unsigned short* __restrict__ d0lo)
{
    const int b = blockIdx.x;
    int l = 0, h = N;
    while (l < h) { const int mid = (l + h) >> 1; if (seg[mid] < b) l = mid + 1; else h = mid; }
    const bool nonempty = (l < N) && (seg[l] == b);
    for (int c = threadIdx.x; c < 1088; c += 256) {
        float v;
        if (c < 1024) {
            const float mean = acc2[c] * invN;
            const float var  = acc2[1024 + c] * invN - mean * mean;
            const float sc   = g2[c] * rsqrtf(var + EPS_BN);
            const float sh   = be2[c] - mean * sc;
            v = nonempty ? fmaf(sc, poolraw[(long)b * 1024 + c], sh) : 0.f;
        } else {
            v = agent_h[(long)b * 64 + (c - 1024)];
        }
        d0hi[(long)b * 1088 + c] = f2bf(v);
        d0lo[(long)b * 1088 + c] = f2bf(v - bf_hi(v));
    }
}

// ---------------------------------------------------------------------------
// i2 K-split partial GEMM (fp32, O=64): grid (M/128, KS).
// ---------------------------------------------------------------------------
__global__ __launch_bounds__(256) void gemm_i2_part(
    const float* __restrict__ A,   // [M, K] fp32
    const float* __restrict__ W,   // [64, K]
    const float* __restrict__ ascale, const float* __restrict__ ashift,
    float* __restrict__ part, int M, int K, int kchunk)
{
    __shared__ float As[16][132];
    __shared__ float Bs[16][68];
    const int t = threadIdx.x;
    const int m0 = blockIdx.x * 128;
    const int ks = blockIdx.y;
    const int kbeg = ks * kchunk;
    const int kend = kbeg + kchunk;
    const int tm = (t & 15) * 8;
    const int tn = (t >> 4) * 4;
    const int ar = t >> 1;          // 0..127
    const int ac = (t & 1) * 8;     // 0 or 8
    const int br = t >> 2;          // 0..63
    const int bc = (t & 3) * 4;     // 0,4,8,12

    float acc[8][4];
#pragma unroll
    for (int i = 0; i < 8; ++i)
#pragma unroll
    for (int j = 0; j < 4; ++j) acc[i][j] = 0.f;

    for (int k0 = kbeg; k0 < kend; k0 += 16) {
        float4 a0 = *(const float4*)&A[(long)(m0+ar)*K + k0 + ac];
        float4 a1 = *(const float4*)&A[(long)(m0+ar)*K + k0 + ac + 4];
        float4 s0 = *(const float4*)&ascale[k0 + ac];
        float4 s1 = *(const float4*)&ascale[k0 + ac + 4];
        float4 h0 = *(const float4*)&ashift[k0 + ac];
        float4 h1 = *(const float4*)&ashift[k0 + ac + 4];
        a0.x = fmaf(a0.x, s0.x, h0.x); a0.y = fmaf(a0.y, s0.y, h0.y);
        a0.z = fmaf(a0.z, s0.z, h0.z); a0.w = fmaf(a0.w, s0.w, h0.w);
        a1.x = fmaf(a1.x, s1.x, h1.x); a1.y = fmaf(a1.y, s1.y, h1.y);
        a1.z = fmaf(a1.z, s1.z, h1.z); a1.w = fmaf(a1.w, s1.w, h1.w);
        float4 b0 = *(const float4*)&W[(long)br*K + k0 + bc];
        __syncthreads();
        As[ac+0][ar] = a0.x; As[ac+1][ar] = a0.y; As[ac+2][ar] = a0.z; As[ac+3][ar] = a0.w;
        As[ac+4][ar] = a1.x; As[ac+5][ar] = a1.y; As[ac+6][ar] = a1.z; As[ac+7][ar] = a1.w;
        Bs[bc+0][br] = b0.x; Bs[bc+1][br] = b0.y; Bs[bc+2][br] = b0.z; Bs[bc+3][br] = b0.w;
        __syncthreads();
#pragma unroll
        for (int kk = 0; kk < 16; ++kk) {
            float av[8], bv[4];
            *(float4*)&av[0] = *(const float4*)&As[kk][tm];
            *(float4*)&av[4] = *(const float4*)&As[kk][tm + 4];
            *(float4*)&bv[0] = *(const float4*)&Bs[kk][tn];
#pragma unroll
            for (int i = 0; i < 8; ++i)
#pragma unroll
            for (int j = 0; j < 4; ++j)
                acc[i][j] = fmaf(av[i], bv[j], acc[i][j]);
        }
    }

    float* po = part + (long)ks * M * 64;
#pragma unroll
    for (int i = 0; i < 8; ++i)
        *(float4*)&po[(long)(m0 + tm + i) * 64 + tn] = *(float4*)&acc[i][0];
}

// ---------------------------------------------------------------------------
// t2 = relu(sum_ks part + bias) + fused column stats -> acc4.
// ---------------------------------------------------------------------------
__global__ __launch_bounds__(256) void i2_finish_stats(
    const float* __restrict__ part, const float* __restrict__ bias,
    int M, int KS, float* __restrict__ t2, float* __restrict__ accum)
{
    __shared__ float l1[256], l2[256];
    const int t = threadIdx.x;
    const long base = (long)blockIdx.x * 2048;
    float s = 0.f, ss = 0.f;
#pragma unroll
    for (int k = 0; k < 8; ++k) {
        const long idx = base + k * 256 + t;
        float v = 0.f;
        for (int ks = 0; ks < KS; ++ks) v += part[(long)ks * M * 64 + idx];
        v = fmaxf(v + bias[idx & 63], 0.f);
        t2[idx] = v;
        s += v; ss += v * v;
    }
    l1[t] = s; l2[t] = ss;
    __syncthreads();
    if (t < 64) {
        s  = l1[t] + l1[t + 64] + l1[t + 128] + l1[t + 192];
        ss = l2[t] + l2[t + 64] + l2[t + 128] + l2[t + 192];
        atomicAdd(&accum[t], s);
        atomicAdd(&accum[64 + t], ss);
    }
}

// ---------------------------------------------------------------------------
// Autoregressive decoder: 30 LSTMCell steps (input == h), fused prediction.
// BN4 computed INLINE from acc4.
// ---------------------------------------------------------------------------
__global__ __launch_bounds__(256) void decoder_kernel(
    const float* __restrict__ t2, const float* __restrict__ acc4,
    const float* __restrict__ ig2, const float* __restrict__ ib2, float invB,
    const float* __restrict__ agent_c,
    const float* __restrict__ Wc, const float* __restrict__ bc,
    const float* __restrict__ pW, const float* __restrict__ pb,
    float* __restrict__ pred /*[B,30,2]*/)
{
    __shared__ float h_lds[2][64];
    __shared__ float zg_lds[2][64];
    __shared__ float zo_lds[2][64];
    const int t = threadIdx.x;
    const int lane = t & 63;
    const int wave = t >> 6;
    const int s = wave >> 1;
    const int role = wave & 1;
    const long seq = (long)blockIdx.x * 2 + s;

    const int r0 = role * 128 + lane;
    const int r1 = r0 + 64;
    float w0[64], w1[64];
#pragma unroll
    for (int k = 0; k < 64; k += 4) {
        float4 va = *(const float4*)&Wc[r0 * 64 + k];
        w0[k] = va.x; w0[k+1] = va.y; w0[k+2] = va.z; w0[k+3] = va.w;
        float4 vb = *(const float4*)&Wc[r1 * 64 + k];
        w1[k] = vb.x; w1[k+1] = vb.y; w1[k+2] = vb.z; w1[k+3] = vb.w;
    }
    const float bias0 = bc[r0];
    const float bias1 = bc[r1];
    const float pw0 = pW[lane], pw1 = pW[64 + lane];
    const float pb0 = pb[0], pb1 = pb[1];

    float c = agent_c[seq*64 + lane];
    if (role == 0) {
        const float mean = acc4[lane] * invB;
        const float var  = acc4[64 + lane] * invB - mean * mean;
        const float sc   = ig2[lane] * rsqrtf(var + EPS_BN);
        const float sh   = ib2[lane] - mean * sc;
        h_lds[s][lane] = fmaf(sc, t2[seq*64 + lane], sh);
    }
    __syncthreads();
    float hv = h_lds[s][lane];

    for (int step = 0; step < 30; ++step) {
        float z0 = bias0, z1 = bias1;
#pragma unroll
        for (int k = 0; k < 64; ++k) {
            float hk = __int_as_float(__builtin_amdgcn_readlane(__float_as_int(hv), k));
            z0 = fmaf(hk, w0[k], z0);
            z1 = fmaf(hk, w1[k], z1);
        }
        if (role == 1) { zg_lds[s][lane] = z0; zo_lds[s][lane] = z1; }
        __syncthreads();
        if (role == 0) {
            const float ig = sigmoid_f(z0);
            const float fg = sigmoid_f(z1);
            const float gg = tanh_f(zg_lds[s][lane]);
            const float og = sigmoid_f(zo_lds[s][lane]);
            c = fmaf(fg, c, ig * gg);
            h_lds[s][lane] = og * tanh_f(c);
        }
        __syncthreads();
        hv = h_lds[s][lane];
        if (role == 0) {
            float p0 = hv * pw0;
            float p1 = hv * pw1;
#pragma unroll
            for (int m = 32; m >= 1; m >>= 1) {
                p0 += __shfl_xor(p0, m, 64);
                p1 += __shfl_xor(p1, m, 64);
            }
            if (lane == 0) {
                pred[seq*60 + step*2 + 0] = p0 + pb0;
                pred[seq*60 + step*2 + 1] = p1 + pb1;
            }
        }
    }
}

// ---------------------------------------------------------------------------
extern "C" void kernel_launch(void* const* d_in, const int* in_sizes, int n_in,
                              void* d_out, int out_size, void* d_ws, size_t ws_size,
                              hipStream_t stream)
{
    const float* agent_traj = (const float*)d_in[0];
    const float* neighbours = (const float*)d_in[1];
    const float* aW_ih = (const float*)d_in[2];
    const float* aW_hh = (const float*)d_in[3];
    const float* ab_ih = (const float*)d_in[4];
    const float* ab_hh = (const float*)d_in[5];
    const float* nW_ih = (const float*)d_in[6];
    const float* nW_hh = (const float*)d_in[7];
    const float* nb_ih = (const float*)d_in[8];
    const float* nb_hh = (const float*)d_in[9];
    const float* dW_ih = (const float*)d_in[10];
    const float* dW_hh = (const float*)d_in[11];
    const float* db_ih = (const float*)d_in[12];
    const float* db_hh = (const float*)d_in[13];
    const float* pW = (const float*)d_in[14];
    const float* pb = (const float*)d_in[15];
    const float* rW = (const float*)d_in[16];
    const float* rb = (const float*)d_in[17];
    const float* m1W = (const float*)d_in[18];
    const float* m1b = (const float*)d_in[19];
    const float* g1  = (const float*)d_in[20];
    const float* be1 = (const float*)d_in[21];
    const float* m2W = (const float*)d_in[22];
    const float* m2b = (const float*)d_in[23];
    const float* g2  = (const float*)d_in[24];
    const float* be2 = (const float*)d_in[25];
    const float* i1W = (const float*)d_in[26];
    const float* i1b = (const float*)d_in[27];
    const float* ig1 = (const float*)d_in[28];
    const float* ib1 = (const float*)d_in[29];
    const float* i2W = (const float*)d_in[30];
    const float* i2b = (const float*)d_in[31];
    const float* ig2 = (const float*)d_in[32];
    const float* ib2 = (const float*)d_in[33];
    const int*   seg = (const int*)d_in[34];
    float* pred = (float*)d_out;

    const int B = 2048, T = 20, N = 32768;

    char* p = (char*)d_ws;
    auto alloc = [&](size_t bytes) -> char* {
        char* r = p; p += (bytes + 255) & ~(size_t)255; return r;
    };
    float* agent_h = (float*)alloc((size_t)B*64*4);
    float* agent_c = (float*)alloc((size_t)B*64*4);
    char* neigh_region = alloc((size_t)N*64*4);          // t1 (fp32 B*1024)
    unsigned short* x0hi = (unsigned short*)alloc((size_t)N*128*2);
    unsigned short* x0lo = (unsigned short*)alloc((size_t)N*128*2);
    char* y1hi_region  = alloc((size_t)N*512*2);         // y1hi, later d0hi/d0lo/t2
    unsigned short* y1lo = (unsigned short*)alloc((size_t)N*512*2);
    float* poolraw = (float*)alloc((size_t)B*1024*4);    // 8 MB, zero-init
    float* accAll = (float*)alloc((size_t)(1024+2048+2048+128)*4);
    float* acc1 = accAll;            // 2*512
    float* acc2 = accAll + 1024;     // 2*1024
    float* acc3 = accAll + 3072;     // 2*1024
    float* acc4 = accAll + 5120;     // 2*64
    float* sc3 = (float*)alloc(1024*4); float* sh3 = (float*)alloc(1024*4);
    float* Wc = (float*)alloc(256*64*4);
    float* bc = (float*)alloc(256*4);
    unsigned short* W1hi = (unsigned short*)alloc((size_t)512*128*2);
    unsigned short* W1lo = (unsigned short*)alloc((size_t)512*128*2);
    unsigned short* W2hi = (unsigned short*)alloc((size_t)1024*512*2);
    unsigned short* W2lo = (unsigned short*)alloc((size_t)1024*512*2);
    unsigned short* Wi1hi = (unsigned short*)alloc((size_t)1024*1088*2);
    unsigned short* Wi1lo = (unsigned short*)alloc((size_t)1024*1088*2);
    float* b1f = (float*)alloc(512*4);
    float* b2f = (float*)alloc(1024*4);
    float* bi1f = (float*)alloc(1024*4);
    float* i2part = (float*)alloc((size_t)8*B*64*4);     // 4 MB partials

    // aliases (lifetimes disjoint, stream-ordered)
    float* t1 = (float*)neigh_region;            // i1 output (fp32 B*1024)
    unsigned short* y1hi = (unsigned short*)y1hi_region;
    unsigned short* d0hi = (unsigned short*)y1hi_region;          // after MLP2
    unsigned short* d0lo = d0hi + (size_t)B*1088;
    float* t2 = (float*)(y1hi_region + (size_t)2*B*1088*2);

    hipMemsetAsync(accAll, 0, (1024+2048+2048+128)*sizeof(float), stream);
    hipMemsetAsync(poolraw, 0, (size_t)B*1024*4, stream);

    // all BN-independent preps in one dispatch (was 5)
    prep_all<<<2588, 64, 0, stream>>>(m1W, m1b, i1W, i1b, dW_ih, dW_hh, db_ih, db_hh,
                                      W1hi, W1lo, b1f, Wi1hi, Wi1lo, bi1f, Wc, bc);

    // merged agent+neighbour LSTM with fused x0 build
    lstm_mfma<<<B/32 + N/32, 256, 0, stream>>>(
        agent_traj, aW_ih, aW_hh, ab_ih, ab_hh, agent_h, agent_c,
        neighbours, nW_ih, nW_hh, nb_ih, nb_hh,
        seg, rW, rb, x0hi, x0lo, B/32, T);

    // MLP1 (fused colstats -> acc1)
    gemm_split<<<dim3(512/128, N/128), 256, 0, stream>>>(
        x0hi, x0lo, W1hi, W1lo, b1f, nullptr, y1hi, y1lo, acc1,
        nullptr, nullptr, N, 128, 512);

    // W2 prep with BN1 folded inline
    prep_w2<<<2048, 64, 0, stream>>>(m2W, m2b, acc1, g1, be1, 1.0f/N,
                                     W2hi, W2lo, b2f);

    // MLP2 (fused colstats -> acc2, fused LDS-reduced segment-max -> poolraw)
    gemm_split<<<dim3(1024/128, N/128), 256, 0, stream>>>(
        y1hi, y1lo, W2hi, W2lo, b2f, nullptr, nullptr, nullptr, acc2,
        seg, poolraw, N, 512, 1024);

    // d0 with BN2 inline
    build_d0<<<B, 256, 0, stream>>>(poolraw, agent_h, seg, N, acc2, g2, be2,
                                    1.0f/N, d0hi, d0lo);

    // i1 (fused colstats -> acc3)
    gemm_split<<<dim3(1024/128, B/128), 256, 0, stream>>>(
        d0hi, d0lo, Wi1hi, Wi1lo, bi1f, t1, nullptr, nullptr, acc3,
        nullptr, nullptr, B, 1088, 1024);
    bn_finalize<<<4, 256, 0, stream>>>(acc3, ig1, ib1, 1024, 1.0f/B, sc3, sh3);

    // i2: K-split partials + finish (with fused column stats -> acc4)
    gemm_i2_part<<<dim3(B/128, 8), 256, 0, stream>>>(t1, i2W, sc3, sh3, i2part,
                                                     B, 1024, 128);
    i2_finish_stats<<<64, 256, 0, stream>>>(i2part, i2b, B, 8, t2, acc4);

    // decoder with BN4 inline
    decoder_kernel<<<B/2, 256, 0, stream>>>(t2, acc4, ig2, ib2, 1.0f/B,
                                            agent_c, Wc, bc, pW, pb, pred);
}

// Round 11
// 581.948 us; speedup vs baseline: 1.1349x; 1.0021x over previous
//
#include <hip/hip_runtime.h>

#define EPS_BN 1e-5f

typedef __attribute__((ext_vector_type(8))) short short8;
typedef __attribute__((ext_vector_type(4))) float f32x4;

__device__ __forceinline__ float fast_rcp(float x) { return __builtin_amdgcn_rcpf(x); }
__device__ __forceinline__ float sigmoid_f(float x) { return fast_rcp(1.0f + __expf(-x)); }
// robust tanh: no inf/inf NaN at large |x|
__device__ __forceinline__ float tanh_f(float x) { return 1.0f - 2.0f * fast_rcp(__expf(2.0f * x) + 1.0f); }

// round-to-nearest-even fp32 -> bf16 bits
__device__ __forceinline__ unsigned short f2bf(float f) {
    unsigned u = __float_as_uint(f);
    u += 0x7FFFu + ((u >> 16) & 1u);
    return (unsigned short)(u >> 16);
}
__device__ __forceinline__ unsigned pk_bf(float a, float b) {
    return (unsigned)f2bf(a) | ((unsigned)f2bf(b) << 16);
}
// value of the bf16 rounding (hi part); residual = f - bf_hi(f)
__device__ __forceinline__ float bf_hi(float f) {
    return __uint_as_float((unsigned)f2bf(f) << 16);
}

// async global -> LDS, 16 bytes per lane (dest is wave-uniform base + lane*16)
__device__ __forceinline__ void gload16(const unsigned short* g, unsigned short* l) {
    __builtin_amdgcn_global_load_lds(
        (const __attribute__((address_space(1))) unsigned int*)g,
        (__attribute__((address_space(3))) unsigned int*)l,
        16, 0, 0);
}

union AFrag { short e[8]; short8 v; };
union BFrag { uint4 u; short8 v; };

// ---------------------------------------------------------------------------
// Split-precision MFMA LSTM encoder v8 — MERGED dispatch, 32 seqs/block.
// v8: __launch_bounds__(256) — second arg DROPPED. R9 counters: VGPR=96,
// LDS=26.6KB permit 4 blocks/CU, yet Occupancy reads 17% (~1.4 blk/CU).
// Test: if the (256,2) promise was acting as a residency target on this
// toolchain, removing it lifts occupancy (dur -15-20%); if the derived
// counter is a gfx94x-formula artifact and the kernel is issue-bound at real
// 4-blk residency, dur is flat. REVERT to (256,2) if VGPR >128 appears
// (R4: (256,4) catastrophically clamps to 64 — never use a 2nd arg > 2).
// (R10 bench was lost to GPU-broker timeout; this is an unchanged resubmit.)
// v6: merged-activation epilogue (5 rcp -> 3 rcp; R2/R9 A/B null but
// verified-correct, kept). v7: build_x0 fused into neighbour epilogue.
// ---------------------------------------------------------------------------
__global__ __launch_bounds__(256) void lstm_mfma(
    const float* __restrict__ xA,      // agent_traj [SA, T, 2]
    const float* __restrict__ aW_ih, const float* __restrict__ aW_hh,
    const float* __restrict__ ab_ih, const float* __restrict__ ab_hh,
    float* __restrict__ agent_h, float* __restrict__ agent_c,
    const float* __restrict__ xN,      // neighbours [SN, T, 2]
    const float* __restrict__ nW_ih, const float* __restrict__ nW_hh,
    const float* __restrict__ nb_ih, const float* __restrict__ nb_hh,
    const int* __restrict__ seg, const float* __restrict__ rW,
    const float* __restrict__ rb,
    unsigned short* __restrict__ x0hi, unsigned short* __restrict__ x0lo,
    int nAgentBlk, int T)
{
    __shared__ unsigned h_ex[2][2][32 * 52];   // [buf][hi/lo][32 seqs x 52]

    const bool isA = (blockIdx.x < (unsigned)nAgentBlk);
    const long blk = isA ? blockIdx.x : blockIdx.x - nAgentBlk;
    const float* __restrict__ x     = isA ? xA   : xN;
    const float* __restrict__ W_ih  = isA ? aW_ih : nW_ih;
    const float* __restrict__ W_hh  = isA ? aW_hh : nW_hh;
    const float* __restrict__ b_ih  = isA ? ab_ih : nb_ih;
    const float* __restrict__ b_hh  = isA ? ab_hh : nb_hh;

    const int tid  = threadIdx.x;
    const int w    = tid >> 6;        // cell-group == wave
    const int lane = tid & 63;
    const int s    = lane & 15;       // sequence within the 16 (per B-group)
    const int q    = lane >> 4;       // quad

    short8 ahi[4][3], alo[4][3];
#pragma unroll
    for (int gt = 0; gt < 4; ++gt) {
        const int n = gt * 64 + w * 16 + s;
#pragma unroll
        for (int kc = 0; kc < 2; ++kc) {
            const float* src = &W_hh[n * 64 + kc * 32 + q * 8];
            float4 v0 = *(const float4*)src;
            float4 v1 = *(const float4*)(src + 4);
            float v[8] = {v0.x, v0.y, v0.z, v0.w, v1.x, v1.y, v1.z, v1.w};
            AFrag a, b;
#pragma unroll
            for (int j = 0; j < 8; ++j) {
                a.e[j] = (short)f2bf(v[j]);
                b.e[j] = (short)f2bf(v[j] - bf_hi(v[j]));
            }
            ahi[gt][kc] = a.v;
            alo[gt][kc] = b.v;
        }
        AFrag a2, b2;
#pragma unroll
        for (int j = 0; j < 8; ++j) { a2.e[j] = 0; b2.e[j] = 0; }
        if (q == 0) {   // K rows 64(wi0), 65(wi1), 66(bias)
            const float wi0 = W_ih[n * 2 + 0];
            const float wi1 = W_ih[n * 2 + 1];
            const float bs  = b_ih[n] + b_hh[n];
            a2.e[0] = (short)f2bf(wi0); b2.e[0] = (short)f2bf(wi0 - bf_hi(wi0));
            a2.e[1] = (short)f2bf(wi1); b2.e[1] = (short)f2bf(wi1 - bf_hi(wi1));
            a2.e[2] = (short)f2bf(bs);  b2.e[2] = (short)f2bf(bs  - bf_hi(bs));
        }
        ahi[gt][2] = a2.v;
        alo[gt][2] = b2.v;
    }

    for (int i = tid; i < 2 * 2 * 32 * 52; i += 256) (&h_ex[0][0][0])[i] = 0u;
    __syncthreads();
    if (tid < 32) {   // seq = tid
        h_ex[0][0][tid * 52 + 33] = pk_bf(1.0f, 0.0f);
        h_ex[1][0][tid * 52 + 33] = pk_bf(1.0f, 0.0f);
        float2 xv = *(const float2*)&x[(blk * 32 + tid) * (long)(T * 2)];
        h_ex[0][0][tid * 52 + 32] = pk_bf(xv.x, xv.y);
        h_ex[0][1][tid * 52 + 32] = pk_bf(xv.x - bf_hi(xv.x), xv.y - bf_hi(xv.y));
    }
    __syncthreads();

    float creg[2][4] = {{0.f, 0.f, 0.f, 0.f}, {0.f, 0.f, 0.f, 0.f}};

    for (int t = 0; t < T; ++t) {
        const int rb_ = t & 1, wb = rb_ ^ 1;
        BFrag bhi[2][3], blo[2][3];
#pragma unroll
        for (int g = 0; g < 2; ++g)
#pragma unroll
        for (int kc = 0; kc < 3; ++kc) {
            const int off = (g * 16 + s) * 52 + kc * 16 + (q >> 1) * 8 + (q & 1) * 4;
            bhi[g][kc].u = *(const uint4*)&h_ex[rb_][0][off];
            blo[g][kc].u = *(const uint4*)&h_ex[rb_][1][off];
        }

        f32x4 acc[4][2];
#pragma unroll
        for (int gt = 0; gt < 4; ++gt) { acc[gt][0] = (f32x4)0.f; acc[gt][1] = (f32x4)0.f; }

#pragma unroll
        for (int kc = 0; kc < 3; ++kc) {
#pragma unroll
            for (int g = 0; g < 2; ++g) {
                const short8 bh = bhi[g][kc].v;
                const short8 bl = blo[g][kc].v;
#pragma unroll
                for (int gt = 0; gt < 4; ++gt) {
                    f32x4 a = acc[gt][g];
                    a = __builtin_amdgcn_mfma_f32_16x16x32_bf16(ahi[gt][kc], bh, a, 0, 0, 0);
                    a = __builtin_amdgcn_mfma_f32_16x16x32_bf16(ahi[gt][kc], bl, a, 0, 0, 0);
                    a = __builtin_amdgcn_mfma_f32_16x16x32_bf16(alo[gt][kc], bh, a, 0, 0, 0);
                    acc[gt][g] = a;
                }
            }
        }

#pragma unroll
        for (int g = 0; g < 2; ++g) {
            float hval[4];
#pragma unroll
            for (int r = 0; r < 4; ++r) {
                // merged activations: sigma(zi)*tanh(zg) and sigma(zo)*tanh(c)
                // via single-rcp rational forms (5 rcp -> 3 rcp per element).
                const float ei = __expf(-acc[0][g][r]);          // e^-zi
                const float eg = __expf(2.0f * acc[2][g][r]);    // e^2zg
                const float it = (eg - 1.0f) * fast_rcp((1.0f + ei) * (eg + 1.0f));
                const float sf = fast_rcp(1.0f + __expf(-acc[1][g][r]));
                const float c  = fmaf(sf, creg[g][r], it);
                creg[g][r] = c;
                const float eo = __expf(-acc[3][g][r]);          // e^-zo
                const float ec = __expf(2.0f * c);               // e^2c
                hval[r] = (ec - 1.0f) * fast_rcp((1.0f + eo) * (ec + 1.0f));
            }
            {
                const int w0 = (g * 16 + s) * 52 + w * 8 + q * 2;
                h_ex[wb][0][w0]     = pk_bf(hval[0], hval[1]);
                h_ex[wb][0][w0 + 1] = pk_bf(hval[2], hval[3]);
                h_ex[wb][1][w0]     = pk_bf(hval[0] - bf_hi(hval[0]), hval[1] - bf_hi(hval[1]));
                h_ex[wb][1][w0 + 1] = pk_bf(hval[2] - bf_hi(hval[2]), hval[3] - bf_hi(hval[3]));
            }
            if (t == T - 1) {
                const long seq = blk * 32 + g * 16 + s;
                const int j0 = w * 16 + q * 4;
                if (isA) {
                    *(float4*)&agent_h[seq * 64 + j0] =
                        make_float4(hval[0], hval[1], hval[2], hval[3]);
                    *(float4*)&agent_c[seq * 64 + j0] =
                        make_float4(creg[g][0], creg[g][1], creg[g][2], creg[g][3]);
                } else {
                    // x0 cols 0..63 = neigh_h (identical rounding to old path)
                    *(uint2*)&x0hi[seq * 128 + j0] = make_uint2(
                        pk_bf(hval[0], hval[1]), pk_bf(hval[2], hval[3]));
                    *(uint2*)&x0lo[seq * 128 + j0] = make_uint2(
                        pk_bf(hval[0] - bf_hi(hval[0]), hval[1] - bf_hi(hval[1])),
                        pk_bf(hval[2] - bf_hi(hval[2]), hval[3] - bf_hi(hval[3])));
                }
            }
        }
        if (tid < 32 && t + 1 < T) {
            float2 xv = *(const float2*)&x[(blk * 32 + tid) * (long)(T * 2) + (t + 1) * 2];
            h_ex[wb][0][tid * 52 + 32] = pk_bf(xv.x, xv.y);
            h_ex[wb][1][tid * 52 + 32] = pk_bf(xv.x - bf_hi(xv.x), xv.y - bf_hi(xv.y));
        }
        __syncthreads();
    }

    // x0 cols 64..127: rel_emb = rel @ rW.T + rb  (thread -> 1 seq x 8 cols)
    if (!isA) {
        const int sloc = tid >> 3;
        const long n = blk * 32 + sloc;
        const float2 np = *(const float2*)&x[n * (long)(T * 2) + (T - 1) * 2];
        const int sid = seg[n];
        const float2 ap = *(const float2*)&xA[(long)sid * (T * 2) + (T - 1) * 2];
        const float ra = np.x - ap.x, rbv = np.y - ap.y;
        const int o0 = (tid & 7) * 8;
#pragma unroll
        for (int j = 0; j < 8; ++j) {
            const int o = o0 + j;
            const float v = fmaf(rW[o * 2 + 0], ra, fmaf(rW[o * 2 + 1], rbv, rb[o]));
            x0hi[n * 128 + 64 + o] = f2bf(v);
            x0lo[n * 128 + 64 + o] = f2bf(v - bf_hi(v));
        }
    }
}

// ---------------------------------------------------------------------------
// Weight prep bodies (shared by prep_all / prep_w2).
// ---------------------------------------------------------------------------
__device__ __forceinline__ void wfrag_body(
    const float* __restrict__ W, int K, int blk, int l,
    unsigned short* __restrict__ Whi, unsigned short* __restrict__ Wlo)
{
    const int nKc = K >> 5;
    const int ti = blk / nKc, kc = blk - ti * nKc;
    const int n = ti * 16 + (l & 15);
    const int k0 = kc * 32 + (l >> 4) * 8;
    const long ob = ((long)blk * 64 + l) * 8;
#pragma unroll
    for (int j = 0; j < 8; ++j) {
        float v = W[(long)n * K + k0 + j];
        Whi[ob + j] = f2bf(v);
        Wlo[ob + j] = f2bf(v - bf_hi(v));
    }
}

// ---------------------------------------------------------------------------
// prep_all: all BN-independent weight preps + workspace zeroing in ONE
// dispatch (v8: absorbs the two hipMemsetAsync calls).
// blocks: [0,128) wfrag m1W | [128,2304) wfrag i1W | [2304,2312) b1f copy |
// [2312,2328) bi1f copy | [2328,2588) decoder Wc/bc | [2588,2594) zero accAll
// (5248 floats) | [2594,4642) zero poolraw (2M floats).
// ---------------------------------------------------------------------------
__global__ __launch_bounds__(64) void prep_all(
    const float* __restrict__ m1W, const float* __restrict__ m1b,
    const float* __restrict__ i1W, const float* __restrict__ i1b,
    const float* __restrict__ dW_ih, const float* __restrict__ dW_hh,
    const float* __restrict__ db_ih, const float* __restrict__ db_hh,
    unsigned short* __restrict__ W1hi, unsigned short* __restrict__ W1lo,
    float* __restrict__ b1f,
    unsigned short* __restrict__ Wi1hi, unsigned short* __restrict__ Wi1lo,
    float* __restrict__ bi1f,
    float* __restrict__ Wc, float* __restrict__ bc,
    float* __restrict__ accAll, float* __restrict__ poolraw)
{
    const int b = blockIdx.x, l = threadIdx.x;
    if (b < 128) {
        wfrag_body(m1W, 128, b, l, W1hi, W1lo);
    } else if (b < 2304) {
        wfrag_body(i1W, 1088, b - 128, l, Wi1hi, Wi1lo);
    } else if (b < 2312) {
        const int i = (b - 2304) * 64 + l;    // 512
        b1f[i] = m1b[i];
    } else if (b < 2328) {
        const int i = (b - 2312) * 64 + l;    // 1024
        bi1f[i] = i1b[i];
    } else if (b < 2588) {
        const int idx = (b - 2328) * 64 + l;  // 16640
        if (idx < 16384) Wc[idx] = dW_ih[idx] + dW_hh[idx];
        else if (idx < 16640) bc[idx - 16384] = db_ih[idx - 16384] + db_hh[idx - 16384];
    } else if (b < 2594) {
        const int i0 = (b - 2588) * 1024 + l; // 5248 floats total
#pragma unroll
        for (int j = 0; j < 16; ++j) {
            const int i = i0 + j * 64;
            if (i < 5248) accAll[i] = 0.f;
        }
    } else {
        const long i0 = (long)(b - 2594) * 1024 + l * 4;  // 2M floats total
        const float4 z = make_float4(0.f, 0.f, 0.f, 0.f);
#pragma unroll
        for (int j = 0; j < 4; ++j)
            *(float4*)&poolraw[i0 + j * 256] = z;
    }
}

// ---------------------------------------------------------------------------
// prep_w2: W2 frag-split with BN1 scale folded INLINE from acc1 + bias fold.
// ---------------------------------------------------------------------------
__global__ __launch_bounds__(64) void prep_w2(
    const float* __restrict__ W,      // m2W [1024,512]
    const float* __restrict__ b2,     // m2b
    const float* __restrict__ acc1,   // [2*512]
    const float* __restrict__ g1, const float* __restrict__ be1,
    float invN,
    unsigned short* __restrict__ Whi, unsigned short* __restrict__ Wlo,
    float* __restrict__ bout)
{
    const int K = 512, nKc = 16;
    const int blk = blockIdx.x, l = threadIdx.x;
    if (blk < 1024) {
        const int ti = blk / nKc, kc = blk - ti * nKc;
        const int n = ti * 16 + (l & 15);
        const int k0 = kc * 32 + (l >> 4) * 8;
        const long ob = ((long)blk * 64 + l) * 8;
#pragma unroll
        for (int j = 0; j < 8; ++j) {
            const int k = k0 + j;
            const float mean = acc1[k] * invN;
            const float var  = acc1[512 + k] * invN - mean * mean;
            const float sc   = g1[k] * rsqrtf(var + EPS_BN);
            const float v = W[(long)n * K + k] * sc;
            Whi[ob + j] = f2bf(v);
            Wlo[ob + j] = f2bf(v - bf_hi(v));
        }
    } else {
        const int n = blk - 1024;
        float s = 0.f;
        for (int k = l; k < K; k += 64) {
            const float mean = acc1[k] * invN;
            const float var  = acc1[512 + k] * invN - mean * mean;
            const float sc   = g1[k] * rsqrtf(var + EPS_BN);
            const float sh   = be1[k] - mean * sc;
            s += sh * W[(long)n * K + k];
        }
#pragma unroll
        for (int m = 32; m >= 1; m >>= 1) s += __shfl_xor(s, m, 64);
        if (l == 0) bout[n] = b2[n] + s;
    }
}

// ---------------------------------------------------------------------------
// Split-activation MFMA GEMM — R7-VERIFIED 2-phase version. Measured history:
// T2 swizzle = null at 2-phase (R7, regime-gate), counted-vmcnt graft =
// regression (R8: 160->177us, VGPR 104->128). ~160us (+-15% fleet variance)
// is this structure's plateau (MFMA floor 41us); escape requires the full
// 8-phase 256-sq template. DO NOT re-attempt partial pipeline grafts.
// Structure: DIRECT global_load_lds x16 A-staging, linear [128*32] LDS + XOR
// swizzle slot^=(row>>1)&3 (write side via inverse-permuted global src, read
// side on ds_read_b128). launch_bounds (256,2) LOAD-BEARING. nKc EVEN.
// gridDim.y % 8 == 0. Epilogue: LDS segment-max pool (span<=60), interior-sid
// plain stores + boundary atomicMax; fallback to direct atomics.
// ---------------------------------------------------------------------------
__global__ __launch_bounds__(256, 2) void gemm_split(
    const unsigned short* __restrict__ Ahi,
    const unsigned short* __restrict__ Alo,
    const unsigned short* __restrict__ Whi,
    const unsigned short* __restrict__ Wlo,
    const float* __restrict__ bias,
    float* __restrict__ Yf,
    unsigned short* __restrict__ Yhi,
    unsigned short* __restrict__ Ylo,
    float* __restrict__ accum,
    const int* __restrict__ segp,
    float* __restrict__ poolmax,
    int M, int K, int O)
{
    __shared__ unsigned short As[2][2][128 * 32];   // [buf][hi/lo][row*32] linear
    __shared__ int segl[128];
    const int t = threadIdx.x;
    const int lane = t & 63;
    const int w = t >> 6;
    const int wm = w & 1, wn = w >> 1;

    // XCD swizzle: flat -> (row panel, col panel)
    const int nx = gridDim.x;
    const int flat = blockIdx.y * nx + blockIdx.x;
    const int grp = flat / (8 * nx);
    const int loc = flat - grp * (8 * nx);
    const int m0 = (grp * 8 + (loc & 7)) * 128;
    const int n0 = (loc >> 3) * 128;
    const int nKc = K >> 5;   // even

    f32x4 acc[4][4];
#pragma unroll
    for (int mt = 0; mt < 4; ++mt)
#pragma unroll
    for (int nt = 0; nt < 4; ++nt) acc[mt][nt] = (f32x4)0.f;

    // A staging: wave w owns local rows [w*32, w*32+32) in 2 chunks of 16.
    const int rloc0 = w * 32 + (lane >> 2);
    const int rloc1 = rloc0 + 16;
    const int sd = lane & 3;
    const unsigned short* gsrc[2][2];
    gsrc[0][0] = Ahi + (long)(m0 + rloc0) * K + (sd ^ ((rloc0 >> 1) & 3)) * 8;
    gsrc[0][1] = Ahi + (long)(m0 + rloc1) * K + (sd ^ ((rloc1 >> 1) & 3)) * 8;
    gsrc[1][0] = Alo + (long)(m0 + rloc0) * K + (sd ^ ((rloc0 >> 1) & 3)) * 8;
    gsrc[1][1] = Alo + (long)(m0 + rloc1) * K + (sd ^ ((rloc1 >> 1) & 3)) * 8;

    auto stageA = [&](int buf, int kc) {
#pragma unroll
        for (int pp = 0; pp < 2; ++pp)
#pragma unroll
        for (int cc = 0; cc < 2; ++cc)
            gload16(gsrc[pp][cc] + kc * 32,
                    &As[buf][pp][(w * 32 + cc * 16) * 32]);
    };

    // read-side swizzled slot (shorts offset); mt- and wm-independent.
    const int s2 = ((lane >> 4) ^ ((lane >> 1) & 3)) * 8;
    const int arow = wm * 64 + (lane & 15);
    const long bt0 = (long)((n0 >> 4) + wn * 4);

    auto loadB = [&](BFrag* bh, BFrag* bl, int kc) {
#pragma unroll
        for (int nt = 0; nt < 4; ++nt) {
            const long fb = ((bt0 + nt) * nKc + kc) * 512 + lane * 8;
            bh[nt].u = *(const uint4*)(Whi + fb);
            bl[nt].u = *(const uint4*)(Wlo + fb);
        }
    };
    auto compute = [&](int buf, BFrag* bh, BFrag* bl) {
        BFrag afh[4], afl[4];
#pragma unroll
        for (int mt = 0; mt < 4; ++mt) {
            afh[mt].u = *(const uint4*)&As[buf][0][(arow + mt * 16) * 32 + s2];
            afl[mt].u = *(const uint4*)&As[buf][1][(arow + mt * 16) * 32 + s2];
        }
#pragma unroll
        for (int nt = 0; nt < 4; ++nt)
#pragma unroll
        for (int mt = 0; mt < 4; ++mt) {
            f32x4 a = acc[mt][nt];
            a = __builtin_amdgcn_mfma_f32_16x16x32_bf16(afh[mt].v, bh[nt].v, a, 0, 0, 0);
            a = __builtin_amdgcn_mfma_f32_16x16x32_bf16(afh[mt].v, bl[nt].v, a, 0, 0, 0);
            a = __builtin_amdgcn_mfma_f32_16x16x32_bf16(afl[mt].v, bh[nt].v, a, 0, 0, 0);
            acc[mt][nt] = a;
        }
    };

    BFrag bh0[4], bl0[4], bh1[4], bl1[4];
    stageA(0, 0);
    loadB(bh0, bl0, 0);
    __syncthreads();
    for (int kc = 0; kc < nKc; kc += 2) {
        stageA(1, kc + 1);
        loadB(bh1, bl1, kc + 1);
        compute(0, bh0, bl0);
        __syncthreads();
        if (kc + 2 < nKc) {
            stageA(0, kc + 2);
            loadB(bh0, bl0, kc + 2);
        }
        compute(1, bh1, bl1);
        if (kc + 2 < nKc) __syncthreads();
    }

    int sid0 = 0, span = 0;
    bool useLds = false;
    float* pool = nullptr;
    if (segp) {
        __syncthreads();                 // As is dead after this point
        if (t < 128) segl[t] = segp[m0 + t];
        __syncthreads();
        sid0 = segl[0];
        span = segl[127] - sid0 + 1;     // sorted ids -> contiguous range
        pool = (float*)&As[0][0][0];     // reuse As as [span][132] fp32 pool
        useLds = (span <= 60);           // 60*132*4 = 31.7 KB <= 32.8 KB
        if (useLds) {
            for (int i = t; i < span * 132; i += 256) pool[i] = 0.f;
            __syncthreads();
        }
    }

    const int cn = lane & 15, cq = lane >> 4;
#pragma unroll
    for (int nt = 0; nt < 4; ++nt) {
        const int cl = wn * 64 + nt * 16 + cn;   // column local to n-panel
        const int n = n0 + cl;
        const float bs = bias[n];
        float s = 0.f, ssq = 0.f;
#pragma unroll
        for (int mt = 0; mt < 4; ++mt) {
            const int mb = wm * 64 + mt * 16 + cq * 4;
            float vmax = 0.f; int sid = -1;
#pragma unroll
            for (int r = 0; r < 4; ++r) {
                const float v = fmaxf(acc[mt][nt][r] + bs, 0.f);
                s += v; ssq += v * v;
                if (segp) {
                    const int sr = segl[mb + r];
                    if (r == 0) { vmax = v; sid = sr; }
                    else if (sr == sid) { vmax = fmaxf(vmax, v); }
                    else {
                        if (vmax > 0.f) {
                            if (useLds)
                                atomicMax((int*)&pool[(sid - sid0) * 132 + cl], __float_as_int(vmax));
                            else
                                atomicMax((int*)&poolmax[(long)sid * O + n], __float_as_int(vmax));
                        }
                        sid = sr; vmax = v;
                    }
                } else if (Yf) {
                    Yf[(long)(m0 + mb + r) * O + n] = v;
                } else {
                    const long idx = (long)(m0 + mb + r) * O + n;
                    Yhi[idx] = f2bf(v);
                    Ylo[idx] = f2bf(v - bf_hi(v));
                }
            }
            if (segp && vmax > 0.f) {
                if (useLds)
                    atomicMax((int*)&pool[(sid - sid0) * 132 + cl], __float_as_int(vmax));
                else
                    atomicMax((int*)&poolmax[(long)sid * O + n], __float_as_int(vmax));
            }
        }
        if (accum) {
            s   += __shfl_xor(s, 16, 64);   ssq += __shfl_xor(ssq, 16, 64);
            s   += __shfl_xor(s, 32, 64);   ssq += __shfl_xor(ssq, 32, 64);
            if (cq == 0) {
                atomicAdd(&accum[n], s);
                atomicAdd(&accum[O + n], ssq);
            }
        }
    }

    if (segp && useLds) {
        __syncthreads();
        // interior sids: unique writer -> plain store; boundary sids ->
        // global atomicMax. Absent sids are globally empty (sorted ids).
        for (int e = t; e < span * 128; e += 256) {
            const int sl = e >> 7, c = e & 127;
            const float v = pool[sl * 132 + c];
            const long gi = (long)(sid0 + sl) * O + (n0 + c);
            if (sl == 0 || sl == span - 1) {
                if (v > 0.f) atomicMax((int*)&poolmax[gi], __float_as_int(v));
            } else {
                poolmax[gi] = v;
            }
        }
    }
}

__global__ __launch_bounds__(256) void bn_finalize(
    const float* __restrict__ accum, const float* __restrict__ g,
    const float* __restrict__ be, int O, float invM,
    float* __restrict__ scale, float* __restrict__ shift)
{
    const int o = blockIdx.x * 256 + threadIdx.x;
    if (o < O) {
        const float mean = accum[o] * invM;
        const float var  = accum[O + o] * invM - mean * mean;
        const float sc   = g[o] * rsqrtf(var + EPS_BN);
        scale[o] = sc;
        shift[o] = be[o] - mean * sc;
    }
}

// ---------------------------------------------------------------------------
// d0 = concat( BN2(poolmax) or 0 (empty segment), agent_h ) -> hi/lo.
// BN2 computed INLINE from acc2.
// ---------------------------------------------------------------------------
__global__ __launch_bounds__(256) void build_d0(
    const float* __restrict__ poolraw, const float* __restrict__ agent_h,
    const int* __restrict__ seg, int N,
    const float* __restrict__ acc2, const float* __restrict__ g2,
    const float* __restrict__ be2, float invN,
    unsigned short* __restrict__ d0hi, unsigned short* __restrict__ d0lo)
{
    const int b = blockIdx.x;
    int l = 0, h = N;
    while (l < h) { const int mid = (l + h) >> 1; if (seg[mid] < b) l = mid + 1; else h = mid; }
    const bool nonempty = (l < N) && (seg[l] == b);
    for (int c = threadIdx.x; c < 1088; c += 256) {
        float v;
        if (c < 1024) {
            const float mean = acc2[c] * invN;
            const float var  = acc2[1024 + c] * invN - mean * mean;
            const float sc   = g2[c] * rsqrtf(var + EPS_BN);
            const float sh   = be2[c] - mean * sc;
            v = nonempty ? fmaf(sc, poolraw[(long)b * 1024 + c], sh) : 0.f;
        } else {
            v = agent_h[(long)b * 64 + (c - 1024)];
        }
        d0hi[(long)b * 1088 + c] = f2bf(v);
        d0lo[(long)b * 1088 + c] = f2bf(v - bf_hi(v));
    }
}

// ---------------------------------------------------------------------------
// i2 K-split partial GEMM (fp32, O=64): grid (M/128, KS).
// ---------------------------------------------------------------------------
__global__ __launch_bounds__(256) void gemm_i2_part(
    const float* __restrict__ A,   // [M, K] fp32
    const float* __restrict__ W,   // [64, K]
    const float* __restrict__ ascale, const float* __restrict__ ashift,
    float* __restrict__ part, int M, int K, int kchunk)
{
    __shared__ float As[16][132];
    __shared__ float Bs[16][68];
    const int t = threadIdx.x;
    const int m0 = blockIdx.x * 128;
    const int ks = blockIdx.y;
    const int kbeg = ks * kchunk;
    const int kend = kbeg + kchunk;
    const int tm = (t & 15) * 8;
    const int tn = (t >> 4) * 4;
    const int ar = t >> 1;          // 0..127
    const int ac = (t & 1) * 8;     // 0 or 8
    const int br = t >> 2;          // 0..63
    const int bc = (t & 3) * 4;     // 0,4,8,12

    float acc[8][4];
#pragma unroll
    for (int i = 0; i < 8; ++i)
#pragma unroll
    for (int j = 0; j < 4; ++j) acc[i][j] = 0.f;

    for (int k0 = kbeg; k0 < kend; k0 += 16) {
        float4 a0 = *(const float4*)&A[(long)(m0+ar)*K + k0 + ac];
        float4 a1 = *(const float4*)&A[(long)(m0+ar)*K + k0 + ac + 4];
        float4 s0 = *(const float4*)&ascale[k0 + ac];
        float4 s1 = *(const float4*)&ascale[k0 + ac + 4];
        float4 h0 = *(const float4*)&ashift[k0 + ac];
        float4 h1 = *(const float4*)&ashift[k0 + ac + 4];
        a0.x = fmaf(a0.x, s0.x, h0.x); a0.y = fmaf(a0.y, s0.y, h0.y);
        a0.z = fmaf(a0.z, s0.z, h0.z); a0.w = fmaf(a0.w, s0.w, h0.w);
        a1.x = fmaf(a1.x, s1.x, h1.x); a1.y = fmaf(a1.y, s1.y, h1.y);
        a1.z = fmaf(a1.z, s1.z, h1.z); a1.w = fmaf(a1.w, s1.w, h1.w);
        float4 b0 = *(const float4*)&W[(long)br*K + k0 + bc];
        __syncthreads();
        As[ac+0][ar] = a0.x; As[ac+1][ar] = a0.y; As[ac+2][ar] = a0.z; As[ac+3][ar] = a0.w;
        As[ac+4][ar] = a1.x; As[ac+5][ar] = a1.y; As[ac+6][ar] = a1.z; As[ac+7][ar] = a1.w;
        Bs[bc+0][br] = b0.x; Bs[bc+1][br] = b0.y; Bs[bc+2][br] = b0.z; Bs[bc+3][br] = b0.w;
        __syncthreads();
#pragma unroll
        for (int kk = 0; kk < 16; ++kk) {
            float av[8], bv[4];
            *(float4*)&av[0] = *(const float4*)&As[kk][tm];
            *(float4*)&av[4] = *(const float4*)&As[kk][tm + 4];
            *(float4*)&bv[0] = *(const float4*)&Bs[kk][tn];
#pragma unroll
            for (int i = 0; i < 8; ++i)
#pragma unroll
            for (int j = 0; j < 4; ++j)
                acc[i][j] = fmaf(av[i], bv[j], acc[i][j]);
        }
    }

    float* po = part + (long)ks * M * 64;
#pragma unroll
    for (int i = 0; i < 8; ++i)
        *(float4*)&po[(long)(m0 + tm + i) * 64 + tn] = *(float4*)&acc[i][0];
}

// ---------------------------------------------------------------------------
// t2 = relu(sum_ks part + bias) + fused column stats -> acc4.
// ---------------------------------------------------------------------------
__global__ __launch_bounds__(256) void i2_finish_stats(
    const float* __restrict__ part, const float* __restrict__ bias,
    int M, int KS, float* __restrict__ t2, float* __restrict__ accum)
{
    __shared__ float l1[256], l2[256];
    const int t = threadIdx.x;
    const long base = (long)blockIdx.x * 2048;
    float s = 0.f, ss = 0.f;
#pragma unroll
    for (int k = 0; k < 8; ++k) {
        const long idx = base + k * 256 + t;
        float v = 0.f;
        for (int ks = 0; ks < KS; ++ks) v += part[(long)ks * M * 64 + idx];
        v = fmaxf(v + bias[idx & 63], 0.f);
        t2[idx] = v;
        s += v; ss += v * v;
    }
    l1[t] = s; l2[t] = ss;
    __syncthreads();
    if (t < 64) {
        s  = l1[t] + l1[t + 64] + l1[t + 128] + l1[t + 192];
        ss = l2[t] + l2[t + 64] + l2[t + 128] + l2[t + 192];
        atomicAdd(&accum[t], s);
        atomicAdd(&accum[64 + t], ss);
    }
}

// ---------------------------------------------------------------------------
// Autoregressive decoder: 30 LSTMCell steps (input == h), fused prediction.
// BN4 computed INLINE from acc4.
// ---------------------------------------------------------------------------
__global__ __launch_bounds__(256) void decoder_kernel(
    const float* __restrict__ t2, const float* __restrict__ acc4,
    const float* __restrict__ ig2, const float* __restrict__ ib2, float invB,
    const float* __restrict__ agent_c,
    const float* __restrict__ Wc, const float* __restrict__ bc,
    const float* __restrict__ pW, const float* __restrict__ pb,
    float* __restrict__ pred /*[B,30,2]*/)
{
    __shared__ float h_lds[2][64];
    __shared__ float zg_lds[2][64];
    __shared__ float zo_lds[2][64];
    const int t = threadIdx.x;
    const int lane = t & 63;
    const int wave = t >> 6;
    const int s = wave >> 1;
    const int role = wave & 1;
    const long seq = (long)blockIdx.x * 2 + s;

    const int r0 = role * 128 + lane;
    const int r1 = r0 + 64;
    float w0[64], w1[64];
#pragma unroll
    for (int k = 0; k < 64; k += 4) {
        float4 va = *(const float4*)&Wc[r0 * 64 + k];
        w0[k] = va.x; w0[k+1] = va.y; w0[k+2] = va.z; w0[k+3] = va.w;
        float4 vb = *(const float4*)&Wc[r1 * 64 + k];
        w1[k] = vb.x; w1[k+1] = vb.y; w1[k+2] = vb.z; w1[k+3] = vb.w;
    }
    const float bias0 = bc[r0];
    const float bias1 = bc[r1];
    const float pw0 = pW[lane], pw1 = pW[64 + lane];
    const float pb0 = pb[0], pb1 = pb[1];

    float c = agent_c[seq*64 + lane];
    if (role == 0) {
        const float mean = acc4[lane] * invB;
        const float var  = acc4[64 + lane] * invB - mean * mean;
        const float sc   = ig2[lane] * rsqrtf(var + EPS_BN);
        const float sh   = ib2[lane] - mean * sc;
        h_lds[s][lane] = fmaf(sc, t2[seq*64 + lane], sh);
    }
    __syncthreads();
    float hv = h_lds[s][lane];

    for (int step = 0; step < 30; ++step) {
        float z0 = bias0, z1 = bias1;
#pragma unroll
        for (int k = 0; k < 64; ++k) {
            float hk = __int_as_float(__builtin_amdgcn_readlane(__float_as_int(hv), k));
            z0 = fmaf(hk, w0[k], z0);
            z1 = fmaf(hk, w1[k], z1);
        }
        if (role == 1) { zg_lds[s][lane] = z0; zo_lds[s][lane] = z1; }
        __syncthreads();
        if (role == 0) {
            const float ig = sigmoid_f(z0);
            const float fg = sigmoid_f(z1);
            const float gg = tanh_f(zg_lds[s][lane]);
            const float og = sigmoid_f(zo_lds[s][lane]);
            c = fmaf(fg, c, ig * gg);
            h_lds[s][lane] = og * tanh_f(c);
        }
        __syncthreads();
        hv = h_lds[s][lane];
        if (role == 0) {
            float p0 = hv * pw0;
            float p1 = hv * pw1;
#pragma unroll
            for (int m = 32; m >= 1; m >>= 1) {
                p0 += __shfl_xor(p0, m, 64);
                p1 += __shfl_xor(p1, m, 64);
            }
            if (lane == 0) {
                pred[seq*60 + step*2 + 0] = p0 + pb0;
                pred[seq*60 + step*2 + 1] = p1 + pb1;
            }
        }
    }
}

// ---------------------------------------------------------------------------
extern "C" void kernel_launch(void* const* d_in, const int* in_sizes, int n_in,
                              void* d_out, int out_size, void* d_ws, size_t ws_size,
                              hipStream_t stream)
{
    const float* agent_traj = (const float*)d_in[0];
    const float* neighbours = (const float*)d_in[1];
    const float* aW_ih = (const float*)d_in[2];
    const float* aW_hh = (const float*)d_in[3];
    const float* ab_ih = (const float*)d_in[4];
    const float* ab_hh = (const float*)d_in[5];
    const float* nW_ih = (const float*)d_in[6];
    const float* nW_hh = (const float*)d_in[7];
    const float* nb_ih = (const float*)d_in[8];
    const float* nb_hh = (const float*)d_in[9];
    const float* dW_ih = (const float*)d_in[10];
    const float* dW_hh = (const float*)d_in[11];
    const float* db_ih = (const float*)d_in[12];
    const float* db_hh = (const float*)d_in[13];
    const float* pW = (const float*)d_in[14];
    const float* pb = (const float*)d_in[15];
    const float* rW = (const float*)d_in[16];
    const float* rb = (const float*)d_in[17];
    const float* m1W = (const float*)d_in[18];
    const float* m1b = (const float*)d_in[19];
    const float* g1  = (const float*)d_in[20];
    const float* be1 = (const float*)d_in[21];
    const float* m2W = (const float*)d_in[22];
    const float* m2b = (const float*)d_in[23];
    const float* g2  = (const float*)d_in[24];
    const float* be2 = (const float*)d_in[25];
    const float* i1W = (const float*)d_in[26];
    const float* i1b = (const float*)d_in[27];
    const float* ig1 = (const float*)d_in[28];
    const float* ib1 = (const float*)d_in[29];
    const float* i2W = (const float*)d_in[30];
    const float* i2b = (const float*)d_in[31];
    const float* ig2 = (const float*)d_in[32];
    const float* ib2 = (const float*)d_in[33];
    const int*   seg = (const int*)d_in[34];
    float* pred = (float*)d_out;

    const int B = 2048, T = 20, N = 32768;

    char* p = (char*)d_ws;
    auto alloc = [&](size_t bytes) -> char* {
        char* r = p; p += (bytes + 255) & ~(size_t)255; return r;
    };
    float* agent_h = (float*)alloc((size_t)B*64*4);
    float* agent_c = (float*)alloc((size_t)B*64*4);
    char* neigh_region = alloc((size_t)N*64*4);          // t1 (fp32 B*1024)
    unsigned short* x0hi = (unsigned short*)alloc((size_t)N*128*2);
    unsigned short* x0lo = (unsigned short*)alloc((size_t)N*128*2);
    char* y1hi_region  = alloc((size_t)N*512*2);         // y1hi, later d0hi/d0lo/t2
    unsigned short* y1lo = (unsigned short*)alloc((size_t)N*512*2);
    float* poolraw = (float*)alloc((size_t)B*1024*4);    // 8 MB, zeroed in prep_all
    float* accAll = (float*)alloc((size_t)(1024+2048+2048+128)*4);
    float* acc1 = accAll;            // 2*512
    float* acc2 = accAll + 1024;     // 2*1024
    float* acc3 = accAll + 3072;     // 2*1024
    float* acc4 = accAll + 5120;     // 2*64
    float* sc3 = (float*)alloc(1024*4); float* sh3 = (float*)alloc(1024*4);
    float* Wc = (float*)alloc(256*64*4);
    float* bc = (float*)alloc(256*4);
    unsigned short* W1hi = (unsigned short*)alloc((size_t)512*128*2);
    unsigned short* W1lo = (unsigned short*)alloc((size_t)512*128*2);
    unsigned short* W2hi = (unsigned short*)alloc((size_t)1024*512*2);
    unsigned short* W2lo = (unsigned short*)alloc((size_t)1024*512*2);
    unsigned short* Wi1hi = (unsigned short*)alloc((size_t)1024*1088*2);
    unsigned short* Wi1lo = (unsigned short*)alloc((size_t)1024*1088*2);
    float* b1f = (float*)alloc(512*4);
    float* b2f = (float*)alloc(1024*4);
    float* bi1f = (float*)alloc(1024*4);
    float* i2part = (float*)alloc((size_t)8*B*64*4);     // 4 MB partials

    // aliases (lifetimes disjoint, stream-ordered)
    float* t1 = (float*)neigh_region;            // i1 output (fp32 B*1024)
    unsigned short* y1hi = (unsigned short*)y1hi_region;
    unsigned short* d0hi = (unsigned short*)y1hi_region;          // after MLP2
    unsigned short* d0lo = d0hi + (size_t)B*1088;
    float* t2 = (float*)(y1hi_region + (size_t)2*B*1088*2);

    // all BN-independent preps + workspace zeroing in one dispatch
    // (v8: absorbs the two former hipMemsetAsync calls)
    prep_all<<<4642, 64, 0, stream>>>(m1W, m1b, i1W, i1b, dW_ih, dW_hh, db_ih, db_hh,
                                      W1hi, W1lo, b1f, Wi1hi, Wi1lo, bi1f, Wc, bc,
                                      accAll, poolraw);

    // merged agent+neighbour LSTM with fused x0 build
    lstm_mfma<<<B/32 + N/32, 256, 0, stream>>>(
        agent_traj, aW_ih, aW_hh, ab_ih, ab_hh, agent_h, agent_c,
        neighbours, nW_ih, nW_hh, nb_ih, nb_hh,
        seg, rW, rb, x0hi, x0lo, B/32, T);

    // MLP1 (fused colstats -> acc1)
    gemm_split<<<dim3(512/128, N/128), 256, 0, stream>>>(
        x0hi, x0lo, W1hi, W1lo, b1f, nullptr, y1hi, y1lo, acc1,
        nullptr, nullptr, N, 128, 512);

    // W2 prep with BN1 folded inline
    prep_w2<<<2048, 64, 0, stream>>>(m2W, m2b, acc1, g1, be1, 1.0f/N,
                                     W2hi, W2lo, b2f);

    // MLP2 (fused colstats -> acc2, fused LDS-reduced segment-max -> poolraw)
    gemm_split<<<dim3(1024/128, N/128), 256, 0, stream>>>(
        y1hi, y1lo, W2hi, W2lo, b2f, nullptr, nullptr, nullptr, acc2,
        seg, poolraw, N, 512, 1024);

    // d0 with BN2 inline
    build_d0<<<B, 256, 0, stream>>>(poolraw, agent_h, seg, N, acc2, g2, be2,
                                    1.0f/N, d0hi, d0lo);

    // i1 (fused colstats -> acc3)
    gemm_split<<<dim3(1024/128, B/128), 256, 0, stream>>>(
        d0hi, d0lo, Wi1hi, Wi1lo, bi1f, t1, nullptr, nullptr, acc3,
        nullptr, nullptr, B, 1088, 1024);
    bn_finalize<<<4, 256, 0, stream>>>(acc3, ig1, ib1, 1024, 1.0f/B, sc3, sh3);

    // i2: K-split partials + finish (with fused column stats -> acc4)
    gemm_i2_part<<<dim3(B/128, 8), 256, 0, stream>>>(t1, i2W, sc3, sh3, i2part,
                                                     B, 1024, 128);
    i2_finish_stats<<<64, 256, 0, stream>>>(i2part, i2b, B, 8, t2, acc4);

    // decoder with BN4 inline
    decoder_kernel<<<B/2, 256, 0, stream>>>(t2, acc4, ig2, ib2, 1.0f/B,
                                            agent_c, Wc, bc, pW, pb, pred);
}

// Round 13
// 572.462 us; speedup vs baseline: 1.1537x; 1.0166x over previous
//
#include <hip/hip_runtime.h>

#define EPS_BN 1e-5f

typedef __attribute__((ext_vector_type(8))) short short8;
typedef __attribute__((ext_vector_type(4))) float f32x4;

__device__ __forceinline__ float fast_rcp(float x) { return __builtin_amdgcn_rcpf(x); }
__device__ __forceinline__ float sigmoid_f(float x) { return fast_rcp(1.0f + __expf(-x)); }
// robust tanh: no inf/inf NaN at large |x|
__device__ __forceinline__ float tanh_f(float x) { return 1.0f - 2.0f * fast_rcp(__expf(2.0f * x) + 1.0f); }

// round-to-nearest-even fp32 -> bf16 bits
__device__ __forceinline__ unsigned short f2bf(float f) {
    unsigned u = __float_as_uint(f);
    u += 0x7FFFu + ((u >> 16) & 1u);
    return (unsigned short)(u >> 16);
}
__device__ __forceinline__ unsigned pk_bf(float a, float b) {
    return (unsigned)f2bf(a) | ((unsigned)f2bf(b) << 16);
}
// value of the bf16 rounding (hi part); residual = f - bf_hi(f)
__device__ __forceinline__ float bf_hi(float f) {
    return __uint_as_float((unsigned)f2bf(f) << 16);
}

// async global -> LDS, 16 bytes per lane (dest is wave-uniform base + lane*16)
__device__ __forceinline__ void gload16(const unsigned short* g, unsigned short* l) {
    __builtin_amdgcn_global_load_lds(
        (const __attribute__((address_space(1))) unsigned int*)g,
        (__attribute__((address_space(3))) unsigned int*)l,
        16, 0, 0);
}

union AFrag { short e[8]; short8 v; };
union BFrag { uint4 u; short8 v; };

// ---------------------------------------------------------------------------
// Split-precision MFMA LSTM encoder v8 — MERGED dispatch, 32 seqs/block.
// __launch_bounds__(256): R11 verified null vs (256,2) — occupancy reading
// was a counter artifact; kernel is issue-bound. NEVER use 2nd arg > 2
// (R4: (256,4) clamps VGPR->64, catastrophic spill).
// v6: merged-activation epilogue (null but verified-correct). v7: build_x0
// fused into neighbour epilogue. R11 verified 581.9us e2e.
// ---------------------------------------------------------------------------
__global__ __launch_bounds__(256) void lstm_mfma(
    const float* __restrict__ xA,      // agent_traj [SA, T, 2]
    const float* __restrict__ aW_ih, const float* __restrict__ aW_hh,
    const float* __restrict__ ab_ih, const float* __restrict__ ab_hh,
    float* __restrict__ agent_h, float* __restrict__ agent_c,
    const float* __restrict__ xN,      // neighbours [SN, T, 2]
    const float* __restrict__ nW_ih, const float* __restrict__ nW_hh,
    const float* __restrict__ nb_ih, const float* __restrict__ nb_hh,
    const int* __restrict__ seg, const float* __restrict__ rW,
    const float* __restrict__ rb,
    unsigned short* __restrict__ x0hi, unsigned short* __restrict__ x0lo,
    int nAgentBlk, int T)
{
    __shared__ unsigned h_ex[2][2][32 * 52];   // [buf][hi/lo][32 seqs x 52]

    const bool isA = (blockIdx.x < (unsigned)nAgentBlk);
    const long blk = isA ? blockIdx.x : blockIdx.x - nAgentBlk;
    const float* __restrict__ x     = isA ? xA   : xN;
    const float* __restrict__ W_ih  = isA ? aW_ih : nW_ih;
    const float* __restrict__ W_hh  = isA ? aW_hh : nW_hh;
    const float* __restrict__ b_ih  = isA ? ab_ih : nb_ih;
    const float* __restrict__ b_hh  = isA ? ab_hh : nb_hh;

    const int tid  = threadIdx.x;
    const int w    = tid >> 6;        // cell-group == wave
    const int lane = tid & 63;
    const int s    = lane & 15;       // sequence within the 16 (per B-group)
    const int q    = lane >> 4;       // quad

    short8 ahi[4][3], alo[4][3];
#pragma unroll
    for (int gt = 0; gt < 4; ++gt) {
        const int n = gt * 64 + w * 16 + s;
#pragma unroll
        for (int kc = 0; kc < 2; ++kc) {
            const float* src = &W_hh[n * 64 + kc * 32 + q * 8];
            float4 v0 = *(const float4*)src;
            float4 v1 = *(const float4*)(src + 4);
            float v[8] = {v0.x, v0.y, v0.z, v0.w, v1.x, v1.y, v1.z, v1.w};
            AFrag a, b;
#pragma unroll
            for (int j = 0; j < 8; ++j) {
                a.e[j] = (short)f2bf(v[j]);
                b.e[j] = (short)f2bf(v[j] - bf_hi(v[j]));
            }
            ahi[gt][kc] = a.v;
            alo[gt][kc] = b.v;
        }
        AFrag a2, b2;
#pragma unroll
        for (int j = 0; j < 8; ++j) { a2.e[j] = 0; b2.e[j] = 0; }
        if (q == 0) {   // K rows 64(wi0), 65(wi1), 66(bias)
            const float wi0 = W_ih[n * 2 + 0];
            const float wi1 = W_ih[n * 2 + 1];
            const float bs  = b_ih[n] + b_hh[n];
            a2.e[0] = (short)f2bf(wi0); b2.e[0] = (short)f2bf(wi0 - bf_hi(wi0));
            a2.e[1] = (short)f2bf(wi1); b2.e[1] = (short)f2bf(wi1 - bf_hi(wi1));
            a2.e[2] = (short)f2bf(bs);  b2.e[2] = (short)f2bf(bs  - bf_hi(bs));
        }
        ahi[gt][2] = a2.v;
        alo[gt][2] = b2.v;
    }

    for (int i = tid; i < 2 * 2 * 32 * 52; i += 256) (&h_ex[0][0][0])[i] = 0u;
    __syncthreads();
    if (tid < 32) {   // seq = tid
        h_ex[0][0][tid * 52 + 33] = pk_bf(1.0f, 0.0f);
        h_ex[1][0][tid * 52 + 33] = pk_bf(1.0f, 0.0f);
        float2 xv = *(const float2*)&x[(blk * 32 + tid) * (long)(T * 2)];
        h_ex[0][0][tid * 52 + 32] = pk_bf(xv.x, xv.y);
        h_ex[0][1][tid * 52 + 32] = pk_bf(xv.x - bf_hi(xv.x), xv.y - bf_hi(xv.y));
    }
    __syncthreads();

    float creg[2][4] = {{0.f, 0.f, 0.f, 0.f}, {0.f, 0.f, 0.f, 0.f}};

    for (int t = 0; t < T; ++t) {
        const int rb_ = t & 1, wb = rb_ ^ 1;
        BFrag bhi[2][3], blo[2][3];
#pragma unroll
        for (int g = 0; g < 2; ++g)
#pragma unroll
        for (int kc = 0; kc < 3; ++kc) {
            const int off = (g * 16 + s) * 52 + kc * 16 + (q >> 1) * 8 + (q & 1) * 4;
            bhi[g][kc].u = *(const uint4*)&h_ex[rb_][0][off];
            blo[g][kc].u = *(const uint4*)&h_ex[rb_][1][off];
        }

        f32x4 acc[4][2];
#pragma unroll
        for (int gt = 0; gt < 4; ++gt) { acc[gt][0] = (f32x4)0.f; acc[gt][1] = (f32x4)0.f; }

#pragma unroll
        for (int kc = 0; kc < 3; ++kc) {
#pragma unroll
            for (int g = 0; g < 2; ++g) {
                const short8 bh = bhi[g][kc].v;
                const short8 bl = blo[g][kc].v;
#pragma unroll
                for (int gt = 0; gt < 4; ++gt) {
                    f32x4 a = acc[gt][g];
                    a = __builtin_amdgcn_mfma_f32_16x16x32_bf16(ahi[gt][kc], bh, a, 0, 0, 0);
                    a = __builtin_amdgcn_mfma_f32_16x16x32_bf16(ahi[gt][kc], bl, a, 0, 0, 0);
                    a = __builtin_amdgcn_mfma_f32_16x16x32_bf16(alo[gt][kc], bh, a, 0, 0, 0);
                    acc[gt][g] = a;
                }
            }
        }

#pragma unroll
        for (int g = 0; g < 2; ++g) {
            float hval[4];
#pragma unroll
            for (int r = 0; r < 4; ++r) {
                // merged activations: sigma(zi)*tanh(zg) and sigma(zo)*tanh(c)
                // via single-rcp rational forms (5 rcp -> 3 rcp per element).
                const float ei = __expf(-acc[0][g][r]);          // e^-zi
                const float eg = __expf(2.0f * acc[2][g][r]);    // e^2zg
                const float it = (eg - 1.0f) * fast_rcp((1.0f + ei) * (eg + 1.0f));
                const float sf = fast_rcp(1.0f + __expf(-acc[1][g][r]));
                const float c  = fmaf(sf, creg[g][r], it);
                creg[g][r] = c;
                const float eo = __expf(-acc[3][g][r]);          // e^-zo
                const float ec = __expf(2.0f * c);               // e^2c
                hval[r] = (ec - 1.0f) * fast_rcp((1.0f + eo) * (ec + 1.0f));
            }
            {
                const int w0 = (g * 16 + s) * 52 + w * 8 + q * 2;
                h_ex[wb][0][w0]     = pk_bf(hval[0], hval[1]);
                h_ex[wb][0][w0 + 1] = pk_bf(hval[2], hval[3]);
                h_ex[wb][1][w0]     = pk_bf(hval[0] - bf_hi(hval[0]), hval[1] - bf_hi(hval[1]));
                h_ex[wb][1][w0 + 1] = pk_bf(hval[2] - bf_hi(hval[2]), hval[3] - bf_hi(hval[3]));
            }
            if (t == T - 1) {
                const long seq = blk * 32 + g * 16 + s;
                const int j0 = w * 16 + q * 4;
                if (isA) {
                    *(float4*)&agent_h[seq * 64 + j0] =
                        make_float4(hval[0], hval[1], hval[2], hval[3]);
                    *(float4*)&agent_c[seq * 64 + j0] =
                        make_float4(creg[g][0], creg[g][1], creg[g][2], creg[g][3]);
                } else {
                    // x0 cols 0..63 = neigh_h (identical rounding to old path)
                    *(uint2*)&x0hi[seq * 128 + j0] = make_uint2(
                        pk_bf(hval[0], hval[1]), pk_bf(hval[2], hval[3]));
                    *(uint2*)&x0lo[seq * 128 + j0] = make_uint2(
                        pk_bf(hval[0] - bf_hi(hval[0]), hval[1] - bf_hi(hval[1])),
                        pk_bf(hval[2] - bf_hi(hval[2]), hval[3] - bf_hi(hval[3])));
                }
            }
        }
        if (tid < 32 && t + 1 < T) {
            float2 xv = *(const float2*)&x[(blk * 32 + tid) * (long)(T * 2) + (t + 1) * 2];
            h_ex[wb][0][tid * 52 + 32] = pk_bf(xv.x, xv.y);
            h_ex[wb][1][tid * 52 + 32] = pk_bf(xv.x - bf_hi(xv.x), xv.y - bf_hi(xv.y));
        }
        __syncthreads();
    }

    // x0 cols 64..127: rel_emb = rel @ rW.T + rb  (thread -> 1 seq x 8 cols)
    if (!isA) {
        const int sloc = tid >> 3;
        const long n = blk * 32 + sloc;
        const float2 np = *(const float2*)&x[n * (long)(T * 2) + (T - 1) * 2];
        const int sid = seg[n];
        const float2 ap = *(const float2*)&xA[(long)sid * (T * 2) + (T - 1) * 2];
        const float ra = np.x - ap.x, rbv = np.y - ap.y;
        const int o0 = (tid & 7) * 8;
#pragma unroll
        for (int j = 0; j < 8; ++j) {
            const int o = o0 + j;
            const float v = fmaf(rW[o * 2 + 0], ra, fmaf(rW[o * 2 + 1], rbv, rb[o]));
            x0hi[n * 128 + 64 + o] = f2bf(v);
            x0lo[n * 128 + 64 + o] = f2bf(v - bf_hi(v));
        }
    }
}

// ---------------------------------------------------------------------------
// Weight prep bodies (shared by prep_all / prep_w2).
// ---------------------------------------------------------------------------
__device__ __forceinline__ void wfrag_body(
    const float* __restrict__ W, int K, int blk, int l,
    unsigned short* __restrict__ Whi, unsigned short* __restrict__ Wlo)
{
    const int nKc = K >> 5;
    const int ti = blk / nKc, kc = blk - ti * nKc;
    const int n = ti * 16 + (l & 15);
    const int k0 = kc * 32 + (l >> 4) * 8;
    const long ob = ((long)blk * 64 + l) * 8;
#pragma unroll
    for (int j = 0; j < 8; ++j) {
        float v = W[(long)n * K + k0 + j];
        Whi[ob + j] = f2bf(v);
        Wlo[ob + j] = f2bf(v - bf_hi(v));
    }
}

// ---------------------------------------------------------------------------
// prep_all: all BN-independent weight preps + workspace zeroing in ONE
// dispatch (absorbs the two former hipMemsetAsync calls).
// blocks: [0,128) wfrag m1W | [128,2304) wfrag i1W | [2304,2312) b1f copy |
// [2312,2328) bi1f copy | [2328,2588) decoder Wc/bc | [2588,2594) zero accAll
// (5248 floats) | [2594,4642) zero poolraw (2M floats).
// ---------------------------------------------------------------------------
__global__ __launch_bounds__(64) void prep_all(
    const float* __restrict__ m1W, const float* __restrict__ m1b,
    const float* __restrict__ i1W, const float* __restrict__ i1b,
    const float* __restrict__ dW_ih, const float* __restrict__ dW_hh,
    const float* __restrict__ db_ih, const float* __restrict__ db_hh,
    unsigned short* __restrict__ W1hi, unsigned short* __restrict__ W1lo,
    float* __restrict__ b1f,
    unsigned short* __restrict__ Wi1hi, unsigned short* __restrict__ Wi1lo,
    float* __restrict__ bi1f,
    float* __restrict__ Wc, float* __restrict__ bc,
    float* __restrict__ accAll, float* __restrict__ poolraw)
{
    const int b = blockIdx.x, l = threadIdx.x;
    if (b < 128) {
        wfrag_body(m1W, 128, b, l, W1hi, W1lo);
    } else if (b < 2304) {
        wfrag_body(i1W, 1088, b - 128, l, Wi1hi, Wi1lo);
    } else if (b < 2312) {
        const int i = (b - 2304) * 64 + l;    // 512
        b1f[i] = m1b[i];
    } else if (b < 2328) {
        const int i = (b - 2312) * 64 + l;    // 1024
        bi1f[i] = i1b[i];
    } else if (b < 2588) {
        const int idx = (b - 2328) * 64 + l;  // 16640
        if (idx < 16384) Wc[idx] = dW_ih[idx] + dW_hh[idx];
        else if (idx < 16640) bc[idx - 16384] = db_ih[idx - 16384] + db_hh[idx - 16384];
    } else if (b < 2594) {
        const int i0 = (b - 2588) * 1024 + l; // 5248 floats total
#pragma unroll
        for (int j = 0; j < 16; ++j) {
            const int i = i0 + j * 64;
            if (i < 5248) accAll[i] = 0.f;
        }
    } else {
        const long i0 = (long)(b - 2594) * 1024 + l * 4;  // 2M floats total
        const float4 z = make_float4(0.f, 0.f, 0.f, 0.f);
#pragma unroll
        for (int j = 0; j < 4; ++j)
            *(float4*)&poolraw[i0 + j * 256] = z;
    }
}

// ---------------------------------------------------------------------------
// prep_w2: W2 frag-split with BN1 scale folded INLINE from acc1 + bias fold.
// ---------------------------------------------------------------------------
__global__ __launch_bounds__(64) void prep_w2(
    const float* __restrict__ W,      // m2W [1024,512]
    const float* __restrict__ b2,     // m2b
    const float* __restrict__ acc1,   // [2*512]
    const float* __restrict__ g1, const float* __restrict__ be1,
    float invN,
    unsigned short* __restrict__ Whi, unsigned short* __restrict__ Wlo,
    float* __restrict__ bout)
{
    const int K = 512, nKc = 16;
    const int blk = blockIdx.x, l = threadIdx.x;
    if (blk < 1024) {
        const int ti = blk / nKc, kc = blk - ti * nKc;
        const int n = ti * 16 + (l & 15);
        const int k0 = kc * 32 + (l >> 4) * 8;
        const long ob = ((long)blk * 64 + l) * 8;
#pragma unroll
        for (int j = 0; j < 8; ++j) {
            const int k = k0 + j;
            const float mean = acc1[k] * invN;
            const float var  = acc1[512 + k] * invN - mean * mean;
            const float sc   = g1[k] * rsqrtf(var + EPS_BN);
            const float v = W[(long)n * K + k] * sc;
            Whi[ob + j] = f2bf(v);
            Wlo[ob + j] = f2bf(v - bf_hi(v));
        }
    } else {
        const int n = blk - 1024;
        float s = 0.f;
        for (int k = l; k < K; k += 64) {
            const float mean = acc1[k] * invN;
            const float var  = acc1[512 + k] * invN - mean * mean;
            const float sc   = g1[k] * rsqrtf(var + EPS_BN);
            const float sh   = be1[k] - mean * sc;
            s += sh * W[(long)n * K + k];
        }
#pragma unroll
        for (int m = 32; m >= 1; m >>= 1) s += __shfl_xor(s, m, 64);
        if (l == 0) bout[n] = b2[n] + s;
    }
}

// ---------------------------------------------------------------------------
// Split-activation MFMA GEMM v9: BK=64 — each LDS buffer holds 2 kc (128x64
// per plane), ONE __syncthreads per 2 kc (was two). Theory: the 2-phase
// stall is the stage->drain at each barrier (~400cy cover deficit at BK=32:
// 240cy MFMA vs ~600-900cy load latency). BK=64 gives the stage a ~480cy
// compute phase of cover and halves the barrier count. TILE-GEOMETRY change
// (plain __syncthreads kept) — NOT an R8-style vmcnt/sched_barrier graft
// (measured dead ends). m132's BK-widening regression was occupancy-driven
// (3->2 blk/CU); here occupancy is already pinned at 2 blk/CU by (256,2)
// and 2x64KB=128<=160KB LDS.
// Row stride is now 128B (would-be full-bank alias) -> 8-slot XOR swizzle:
// physical slot p of row r holds logical slot p^(r&7); write side applies
// the inverse permutation on the per-lane GLOBAL source (gload_lds dest
// stays linear, rule #21), read side XORs the same key (row&7 == lane&7 for
// all mt/wm — key is layout-invariant). Residual 2-lane bank aliasing is the
// free case (m136). launch_bounds (256,2) LOAD-BEARING. nKc EVEN.
// gridDim.y % 8 == 0. Epilogue: LDS segment-max pool (span<=120 with 64KB
// As), interior-sid plain stores + boundary atomicMax; fallback to atomics.
// (R12 bench was lost to GPU-broker timeout; this is an unchanged resubmit.)
// ---------------------------------------------------------------------------
__global__ __launch_bounds__(256, 2) void gemm_split(
    const unsigned short* __restrict__ Ahi,
    const unsigned short* __restrict__ Alo,
    const unsigned short* __restrict__ Whi,
    const unsigned short* __restrict__ Wlo,
    const float* __restrict__ bias,
    float* __restrict__ Yf,
    unsigned short* __restrict__ Yhi,
    unsigned short* __restrict__ Ylo,
    float* __restrict__ accum,
    const int* __restrict__ segp,
    float* __restrict__ poolmax,
    int M, int K, int O)
{
    __shared__ unsigned short As[2][2][128 * 64];   // [buf][hi/lo], BK=64
    __shared__ int segl[128];
    const int t = threadIdx.x;
    const int lane = t & 63;
    const int w = t >> 6;
    const int wm = w & 1, wn = w >> 1;

    // XCD swizzle: flat -> (row panel, col panel)
    const int nx = gridDim.x;
    const int flat = blockIdx.y * nx + blockIdx.x;
    const int grp = flat / (8 * nx);
    const int loc = flat - grp * (8 * nx);
    const int m0 = (grp * 8 + (loc & 7)) * 128;
    const int n0 = (loc >> 3) * 128;
    const int nKc = K >> 5;   // even

    f32x4 acc[4][4];
#pragma unroll
    for (int mt = 0; mt < 4; ++mt)
#pragma unroll
    for (int nt = 0; nt < 4; ++nt) acc[mt][nt] = (f32x4)0.f;

    // A staging, BK=64: wave w owns rows [w*32, w*32+32); 4 chunks of 8 rows
    // per plane per stage (8 gload16 total per stage, same count as BK=32).
    // lane l -> row = chunk*8 + (l>>3)  (row&7 == l>>3 for all chunks),
    // physical slot p = l&7. Source logical slot s = p ^ (row&7); logical s
    // maps to global col (s>>2)*32 + (s&3)*8 within the contiguous kc pair.
    const int rl = w * 32 + (lane >> 3);
    const int sl = (lane & 7) ^ (lane >> 3);
    const long gcol = (long)((sl >> 2) * 32 + (sl & 3) * 8);
    const unsigned short* gA[2];
    gA[0] = Ahi + (long)(m0 + rl) * K + gcol;
    gA[1] = Alo + (long)(m0 + rl) * K + gcol;

    auto stageA = [&](int buf, int kc2) {
#pragma unroll
        for (int pp = 0; pp < 2; ++pp)
#pragma unroll
        for (int cc = 0; cc < 4; ++cc)
            gload16(gA[pp] + (long)cc * 8 * K + kc2 * 32,
                    &As[buf][pp][(w * 32 + cc * 8) * 64]);
    };

    // read-side physical slot for kc-half h: ((lane>>4) + h*4) ^ (lane&7).
    // (arow+mt*16)&7 == lane&7 for all mt/wm -> key is mt/wm-invariant.
    const int s2a = (((lane >> 4) + 0) ^ (lane & 7)) * 8;
    const int s2b = (((lane >> 4) + 4) ^ (lane & 7)) * 8;
    const int arow = wm * 64 + (lane & 15);
    const long bt0 = (long)((n0 >> 4) + wn * 4);

    auto loadB = [&](BFrag* bh, BFrag* bl, int kc) {
#pragma unroll
        for (int nt = 0; nt < 4; ++nt) {
            const long fb = ((bt0 + nt) * nKc + kc) * 512 + lane * 8;
            bh[nt].u = *(const uint4*)(Whi + fb);
            bl[nt].u = *(const uint4*)(Wlo + fb);
        }
    };
    auto compute = [&](int buf, int s2, BFrag* bh, BFrag* bl) {
        BFrag afh[4], afl[4];
#pragma unroll
        for (int mt = 0; mt < 4; ++mt) {
            afh[mt].u = *(const uint4*)&As[buf][0][(arow + mt * 16) * 64 + s2];
            afl[mt].u = *(const uint4*)&As[buf][1][(arow + mt * 16) * 64 + s2];
        }
#pragma unroll
        for (int nt = 0; nt < 4; ++nt)
#pragma unroll
        for (int mt = 0; mt < 4; ++mt) {
            f32x4 a = acc[mt][nt];
            a = __builtin_amdgcn_mfma_f32_16x16x32_bf16(afh[mt].v, bh[nt].v, a, 0, 0, 0);
            a = __builtin_amdgcn_mfma_f32_16x16x32_bf16(afh[mt].v, bl[nt].v, a, 0, 0, 0);
            a = __builtin_amdgcn_mfma_f32_16x16x32_bf16(afl[mt].v, bh[nt].v, a, 0, 0, 0);
            acc[mt][nt] = a;
        }
    };

    BFrag bh0[4], bl0[4], bh1[4], bl1[4];
    stageA(0, 0);             // kc 0,1 -> buf0
    loadB(bh0, bl0, 0);
    __syncthreads();
    int buf = 0;
    for (int kc2 = 0; kc2 < nKc; kc2 += 2) {
        if (kc2 + 2 < nKc) stageA(buf ^ 1, kc2 + 2);
        loadB(bh1, bl1, kc2 + 1);
        compute(buf, s2a, bh0, bl0);          // kc2 (half 0)
        if (kc2 + 2 < nKc) loadB(bh0, bl0, kc2 + 2);
        compute(buf, s2b, bh1, bl1);          // kc2+1 (half 1)
        if (kc2 + 2 < nKc) __syncthreads();   // drains stage(buf^1), releases buf
        buf ^= 1;
    }

    int sid0 = 0, span = 0;
    bool useLds = false;
    float* pool = nullptr;
    if (segp) {
        __syncthreads();                 // As is dead after this point
        if (t < 128) segl[t] = segp[m0 + t];
        __syncthreads();
        sid0 = segl[0];
        span = segl[127] - sid0 + 1;     // sorted ids -> contiguous range
        pool = (float*)&As[0][0][0];     // reuse As as [span][132] fp32 pool
        useLds = (span <= 120);          // 120*132*4 = 63.4 KB <= 64 KB
        if (useLds) {
            for (int i = t; i < span * 132; i += 256) pool[i] = 0.f;
            __syncthreads();
        }
    }

    const int cn = lane & 15, cq = lane >> 4;
#pragma unroll
    for (int nt = 0; nt < 4; ++nt) {
        const int cl = wn * 64 + nt * 16 + cn;   // column local to n-panel
        const int n = n0 + cl;
        const float bs = bias[n];
        float s = 0.f, ssq = 0.f;
#pragma unroll
        for (int mt = 0; mt < 4; ++mt) {
            const int mb = wm * 64 + mt * 16 + cq * 4;
            float vmax = 0.f; int sid = -1;
#pragma unroll
            for (int r = 0; r < 4; ++r) {
                const float v = fmaxf(acc[mt][nt][r] + bs, 0.f);
                s += v; ssq += v * v;
                if (segp) {
                    const int sr = segl[mb + r];
                    if (r == 0) { vmax = v; sid = sr; }
                    else if (sr == sid) { vmax = fmaxf(vmax, v); }
                    else {
                        if (vmax > 0.f) {
                            if (useLds)
                                atomicMax((int*)&pool[(sid - sid0) * 132 + cl], __float_as_int(vmax));
                            else
                                atomicMax((int*)&poolmax[(long)sid * O + n], __float_as_int(vmax));
                        }
                        sid = sr; vmax = v;
                    }
                } else if (Yf) {
                    Yf[(long)(m0 + mb + r) * O + n] = v;
                } else {
                    const long idx = (long)(m0 + mb + r) * O + n;
                    Yhi[idx] = f2bf(v);
                    Ylo[idx] = f2bf(v - bf_hi(v));
                }
            }
            if (segp && vmax > 0.f) {
                if (useLds)
                    atomicMax((int*)&pool[(sid - sid0) * 132 + cl], __float_as_int(vmax));
                else
                    atomicMax((int*)&poolmax[(long)sid * O + n], __float_as_int(vmax));
            }
        }
        if (accum) {
            s   += __shfl_xor(s, 16, 64);   ssq += __shfl_xor(ssq, 16, 64);
            s   += __shfl_xor(s, 32, 64);   ssq += __shfl_xor(ssq, 32, 64);
            if (cq == 0) {
                atomicAdd(&accum[n], s);
                atomicAdd(&accum[O + n], ssq);
            }
        }
    }

    if (segp && useLds) {
        __syncthreads();
        // interior sids: unique writer -> plain store; boundary sids ->
        // global atomicMax. Absent sids are globally empty (sorted ids).
        for (int e = t; e < span * 128; e += 256) {
            const int sl_ = e >> 7, c = e & 127;
            const float v = pool[sl_ * 132 + c];
            const long gi = (long)(sid0 + sl_) * O + (n0 + c);
            if (sl_ == 0 || sl_ == span - 1) {
                if (v > 0.f) atomicMax((int*)&poolmax[gi], __float_as_int(v));
            } else {
                poolmax[gi] = v;
            }
        }
    }
}

__global__ __launch_bounds__(256) void bn_finalize(
    const float* __restrict__ accum, const float* __restrict__ g,
    const float* __restrict__ be, int O, float invM,
    float* __restrict__ scale, float* __restrict__ shift)
{
    const int o = blockIdx.x * 256 + threadIdx.x;
    if (o < O) {
        const float mean = accum[o] * invM;
        const float var  = accum[O + o] * invM - mean * mean;
        const float sc   = g[o] * rsqrtf(var + EPS_BN);
        scale[o] = sc;
        shift[o] = be[o] - mean * sc;
    }
}

// ---------------------------------------------------------------------------
// d0 = concat( BN2(poolmax) or 0 (empty segment), agent_h ) -> hi/lo.
// BN2 computed INLINE from acc2.
// ---------------------------------------------------------------------------
__global__ __launch_bounds__(256) void build_d0(
    const float* __restrict__ poolraw, const float* __restrict__ agent_h,
    const int* __restrict__ seg, int N,
    const float* __restrict__ acc2, const float* __restrict__ g2,
    const float* __restrict__ be2, float invN,
    unsigned short* __restrict__ d0hi, unsigned short* __restrict__ d0lo)
{
    const int b = blockIdx.x;
    int l = 0, h = N;
    while (l < h) { const int mid = (l + h) >> 1; if (seg[mid] < b) l = mid + 1; else h = mid; }
    const bool nonempty = (l < N) && (seg[l] == b);
    for (int c = threadIdx.x; c < 1088; c += 256) {
        float v;
        if (c < 1024) {
            const float mean = acc2[c] * invN;
            const float var  = acc2[1024 + c] * invN - mean * mean;
            const float sc   = g2[c] * rsqrtf(var + EPS_BN);
            const float sh   = be2[c] - mean * sc;
            v = nonempty ? fmaf(sc, poolraw[(long)b * 1024 + c], sh) : 0.f;
        } else {
            v = agent_h[(long)b * 64 + (c - 1024)];
        }
        d0hi[(long)b * 1088 + c] = f2bf(v);
        d0lo[(long)b * 1088 + c] = f2bf(v - bf_hi(v));
    }
}

// ---------------------------------------------------------------------------
// i2 K-split partial GEMM (fp32, O=64): grid (M/128, KS).
// ---------------------------------------------------------------------------
__global__ __launch_bounds__(256) void gemm_i2_part(
    const float* __restrict__ A,   // [M, K] fp32
    const float* __restrict__ W,   // [64, K]
    const float* __restrict__ ascale, const float* __restrict__ ashift,
    float* __restrict__ part, int M, int K, int kchunk)
{
    __shared__ float As[16][132];
    __shared__ float Bs[16][68];
    const int t = threadIdx.x;
    const int m0 = blockIdx.x * 128;
    const int ks = blockIdx.y;
    const int kbeg = ks * kchunk;
    const int kend = kbeg + kchunk;
    const int tm = (t & 15) * 8;
    const int tn = (t >> 4) * 4;
    const int ar = t >> 1;          // 0..127
    const int ac = (t & 1) * 8;     // 0 or 8
    const int br = t >> 2;          // 0..63
    const int bc = (t & 3) * 4;     // 0,4,8,12

    float acc[8][4];
#pragma unroll
    for (int i = 0; i < 8; ++i)
#pragma unroll
    for (int j = 0; j < 4; ++j) acc[i][j] = 0.f;

    for (int k0 = kbeg; k0 < kend; k0 += 16) {
        float4 a0 = *(const float4*)&A[(long)(m0+ar)*K + k0 + ac];
        float4 a1 = *(const float4*)&A[(long)(m0+ar)*K + k0 + ac + 4];
        float4 s0 = *(const float4*)&ascale[k0 + ac];
        float4 s1 = *(const float4*)&ascale[k0 + ac + 4];
        float4 h0 = *(const float4*)&ashift[k0 + ac];
        float4 h1 = *(const float4*)&ashift[k0 + ac + 4];
        a0.x = fmaf(a0.x, s0.x, h0.x); a0.y = fmaf(a0.y, s0.y, h0.y);
        a0.z = fmaf(a0.z, s0.z, h0.z); a0.w = fmaf(a0.w, s0.w, h0.w);
        a1.x = fmaf(a1.x, s1.x, h1.x); a1.y = fmaf(a1.y, s1.y, h1.y);
        a1.z = fmaf(a1.z, s1.z, h1.z); a1.w = fmaf(a1.w, s1.w, h1.w);
        float4 b0 = *(const float4*)&W[(long)br*K + k0 + bc];
        __syncthreads();
        As[ac+0][ar] = a0.x; As[ac+1][ar] = a0.y; As[ac+2][ar] = a0.z; As[ac+3][ar] = a0.w;
        As[ac+4][ar] = a1.x; As[ac+5][ar] = a1.y; As[ac+6][ar] = a1.z; As[ac+7][ar] = a1.w;
        Bs[bc+0][br] = b0.x; Bs[bc+1][br] = b0.y; Bs[bc+2][br] = b0.z; Bs[bc+3][br] = b0.w;
        __syncthreads();
#pragma unroll
        for (int kk = 0; kk < 16; ++kk) {
            float av[8], bv[4];
            *(float4*)&av[0] = *(const float4*)&As[kk][tm];
            *(float4*)&av[4] = *(const float4*)&As[kk][tm + 4];
            *(float4*)&bv[0] = *(const float4*)&Bs[kk][tn];
#pragma unroll
            for (int i = 0; i < 8; ++i)
#pragma unroll
            for (int j = 0; j < 4; ++j)
                acc[i][j] = fmaf(av[i], bv[j], acc[i][j]);
        }
    }

    float* po = part + (long)ks * M * 64;
#pragma unroll
    for (int i = 0; i < 8; ++i)
        *(float4*)&po[(long)(m0 + tm + i) * 64 + tn] = *(float4*)&acc[i][0];
}

// ---------------------------------------------------------------------------
// t2 = relu(sum_ks part + bias) + fused column stats -> acc4.
// ---------------------------------------------------------------------------
__global__ __launch_bounds__(256) void i2_finish_stats(
    const float* __restrict__ part, const float* __restrict__ bias,
    int M, int KS, float* __restrict__ t2, float* __restrict__ accum)
{
    __shared__ float l1[256], l2[256];
    const int t = threadIdx.x;
    const long base = (long)blockIdx.x * 2048;
    float s = 0.f, ss = 0.f;
#pragma unroll
    for (int k = 0; k < 8; ++k) {
        const long idx = base + k * 256 + t;
        float v = 0.f;
        for (int ks = 0; ks < KS; ++ks) v += part[(long)ks * M * 64 + idx];
        v = fmaxf(v + bias[idx & 63], 0.f);
        t2[idx] = v;
        s += v; ss += v * v;
    }
    l1[t] = s; l2[t] = ss;
    __syncthreads();
    if (t < 64) {
        s  = l1[t] + l1[t + 64] + l1[t + 128] + l1[t + 192];
        ss = l2[t] + l2[t + 64] + l2[t + 128] + l2[t + 192];
        atomicAdd(&accum[t], s);
        atomicAdd(&accum[64 + t], ss);
    }
}

// ---------------------------------------------------------------------------
// Autoregressive decoder: 30 LSTMCell steps (input == h), fused prediction.
// BN4 computed INLINE from acc4.
// ---------------------------------------------------------------------------
__global__ __launch_bounds__(256) void decoder_kernel(
    const float* __restrict__ t2, const float* __restrict__ acc4,
    const float* __restrict__ ig2, const float* __restrict__ ib2, float invB,
    const float* __restrict__ agent_c,
    const float* __restrict__ Wc, const float* __restrict__ bc,
    const float* __restrict__ pW, const float* __restrict__ pb,
    float* __restrict__ pred /*[B,30,2]*/)
{
    __shared__ float h_lds[2][64];
    __shared__ float zg_lds[2][64];
    __shared__ float zo_lds[2][64];
    const int t = threadIdx.x;
    const int lane = t & 63;
    const int wave = t >> 6;
    const int s = wave >> 1;
    const int role = wave & 1;
    const long seq = (long)blockIdx.x * 2 + s;

    const int r0 = role * 128 + lane;
    const int r1 = r0 + 64;
    float w0[64], w1[64];
#pragma unroll
    for (int k = 0; k < 64; k += 4) {
        float4 va = *(const float4*)&Wc[r0 * 64 + k];
        w0[k] = va.x; w0[k+1] = va.y; w0[k+2] = va.z; w0[k+3] = va.w;
        float4 vb = *(const float4*)&Wc[r1 * 64 + k];
        w1[k] = vb.x; w1[k+1] = vb.y; w1[k+2] = vb.z; w1[k+3] = vb.w;
    }
    const float bias0 = bc[r0];
    const float bias1 = bc[r1];
    const float pw0 = pW[lane], pw1 = pW[64 + lane];
    const float pb0 = pb[0], pb1 = pb[1];

    float c = agent_c[seq*64 + lane];
    if (role == 0) {
        const float mean = acc4[lane] * invB;
        const float var  = acc4[64 + lane] * invB - mean * mean;
        const float sc   = ig2[lane] * rsqrtf(var + EPS_BN);
        const float sh   = ib2[lane] - mean * sc;
        h_lds[s][lane] = fmaf(sc, t2[seq*64 + lane], sh);
    }
    __syncthreads();
    float hv = h_lds[s][lane];

    for (int step = 0; step < 30; ++step) {
        float z0 = bias0, z1 = bias1;
#pragma unroll
        for (int k = 0; k < 64; ++k) {
            float hk = __int_as_float(__builtin_amdgcn_readlane(__float_as_int(hv), k));
            z0 = fmaf(hk, w0[k], z0);
            z1 = fmaf(hk, w1[k], z1);
        }
        if (role == 1) { zg_lds[s][lane] = z0; zo_lds[s][lane] = z1; }
        __syncthreads();
        if (role == 0) {
            const float ig = sigmoid_f(z0);
            const float fg = sigmoid_f(z1);
            const float gg = tanh_f(zg_lds[s][lane]);
            const float og = sigmoid_f(zo_lds[s][lane]);
            c = fmaf(fg, c, ig * gg);
            h_lds[s][lane] = og * tanh_f(c);
        }
        __syncthreads();
        hv = h_lds[s][lane];
        if (role == 0) {
            float p0 = hv * pw0;
            float p1 = hv * pw1;
#pragma unroll
            for (int m = 32; m >= 1; m >>= 1) {
                p0 += __shfl_xor(p0, m, 64);
                p1 += __shfl_xor(p1, m, 64);
            }
            if (lane == 0) {
                pred[seq*60 + step*2 + 0] = p0 + pb0;
                pred[seq*60 + step*2 + 1] = p1 + pb1;
            }
        }
    }
}

// ---------------------------------------------------------------------------
extern "C" void kernel_launch(void* const* d_in, const int* in_sizes, int n_in,
                              void* d_out, int out_size, void* d_ws, size_t ws_size,
                              hipStream_t stream)
{
    const float* agent_traj = (const float*)d_in[0];
    const float* neighbours = (const float*)d_in[1];
    const float* aW_ih = (const float*)d_in[2];
    const float* aW_hh = (const float*)d_in[3];
    const float* ab_ih = (const float*)d_in[4];
    const float* ab_hh = (const float*)d_in[5];
    const float* nW_ih = (const float*)d_in[6];
    const float* nW_hh = (const float*)d_in[7];
    const float* nb_ih = (const float*)d_in[8];
    const float* nb_hh = (const float*)d_in[9];
    const float* dW_ih = (const float*)d_in[10];
    const float* dW_hh = (const float*)d_in[11];
    const float* db_ih = (const float*)d_in[12];
    const float* db_hh = (const float*)d_in[13];
    const float* pW = (const float*)d_in[14];
    const float* pb = (const float*)d_in[15];
    const float* rW = (const float*)d_in[16];
    const float* rb = (const float*)d_in[17];
    const float* m1W = (const float*)d_in[18];
    const float* m1b = (const float*)d_in[19];
    const float* g1  = (const float*)d_in[20];
    const float* be1 = (const float*)d_in[21];
    const float* m2W = (const float*)d_in[22];
    const float* m2b = (const float*)d_in[23];
    const float* g2  = (const float*)d_in[24];
    const float* be2 = (const float*)d_in[25];
    const float* i1W = (const float*)d_in[26];
    const float* i1b = (const float*)d_in[27];
    const float* ig1 = (const float*)d_in[28];
    const float* ib1 = (const float*)d_in[29];
    const float* i2W = (const float*)d_in[30];
    const float* i2b = (const float*)d_in[31];
    const float* ig2 = (const float*)d_in[32];
    const float* ib2 = (const float*)d_in[33];
    const int*   seg = (const int*)d_in[34];
    float* pred = (float*)d_out;

    const int B = 2048, T = 20, N = 32768;

    char* p = (char*)d_ws;
    auto alloc = [&](size_t bytes) -> char* {
        char* r = p; p += (bytes + 255) & ~(size_t)255; return r;
    };
    float* agent_h = (float*)alloc((size_t)B*64*4);
    float* agent_c = (float*)alloc((size_t)B*64*4);
    char* neigh_region = alloc((size_t)N*64*4);          // t1 (fp32 B*1024)
    unsigned short* x0hi = (unsigned short*)alloc((size_t)N*128*2);
    unsigned short* x0lo = (unsigned short*)alloc((size_t)N*128*2);
    char* y1hi_region  = alloc((size_t)N*512*2);         // y1hi, later d0hi/d0lo/t2
    unsigned short* y1lo = (unsigned short*)alloc((size_t)N*512*2);
    float* poolraw = (float*)alloc((size_t)B*1024*4);    // 8 MB, zeroed in prep_all
    float* accAll = (float*)alloc((size_t)(1024+2048+2048+128)*4);
    float* acc1 = accAll;            // 2*512
    float* acc2 = accAll + 1024;     // 2*1024
    float* acc3 = accAll + 3072;     // 2*1024
    float* acc4 = accAll + 5120;     // 2*64
    float* sc3 = (float*)alloc(1024*4); float* sh3 = (float*)alloc(1024*4);
    float* Wc = (float*)alloc(256*64*4);
    float* bc = (float*)alloc(256*4);
    unsigned short* W1hi = (unsigned short*)alloc((size_t)512*128*2);
    unsigned short* W1lo = (unsigned short*)alloc((size_t)512*128*2);
    unsigned short* W2hi = (unsigned short*)alloc((size_t)1024*512*2);
    unsigned short* W2lo = (unsigned short*)alloc((size_t)1024*512*2);
    unsigned short* Wi1hi = (unsigned short*)alloc((size_t)1024*1088*2);
    unsigned short* Wi1lo = (unsigned short*)alloc((size_t)1024*1088*2);
    float* b1f = (float*)alloc(512*4);
    float* b2f = (float*)alloc(1024*4);
    float* bi1f = (float*)alloc(1024*4);
    float* i2part = (float*)alloc((size_t)8*B*64*4);     // 4 MB partials

    // aliases (lifetimes disjoint, stream-ordered)
    float* t1 = (float*)neigh_region;            // i1 output (fp32 B*1024)
    unsigned short* y1hi = (unsigned short*)y1hi_region;
    unsigned short* d0hi = (unsigned short*)y1hi_region;          // after MLP2
    unsigned short* d0lo = d0hi + (size_t)B*1088;
    float* t2 = (float*)(y1hi_region + (size_t)2*B*1088*2);

    // all BN-independent preps + workspace zeroing in one dispatch
    prep_all<<<4642, 64, 0, stream>>>(m1W, m1b, i1W, i1b, dW_ih, dW_hh, db_ih, db_hh,
                                      W1hi, W1lo, b1f, Wi1hi, Wi1lo, bi1f, Wc, bc,
                                      accAll, poolraw);

    // merged agent+neighbour LSTM with fused x0 build
    lstm_mfma<<<B/32 + N/32, 256, 0, stream>>>(
        agent_traj, aW_ih, aW_hh, ab_ih, ab_hh, agent_h, agent_c,
        neighbours, nW_ih, nW_hh, nb_ih, nb_hh,
        seg, rW, rb, x0hi, x0lo, B/32, T);

    // MLP1 (fused colstats -> acc1)
    gemm_split<<<dim3(512/128, N/128), 256, 0, stream>>>(
        x0hi, x0lo, W1hi, W1lo, b1f, nullptr, y1hi, y1lo, acc1,
        nullptr, nullptr, N, 128, 512);

    // W2 prep with BN1 folded inline
    prep_w2<<<2048, 64, 0, stream>>>(m2W, m2b, acc1, g1, be1, 1.0f/N,
                                     W2hi, W2lo, b2f);

    // MLP2 (fused colstats -> acc2, fused LDS-reduced segment-max -> poolraw)
    gemm_split<<<dim3(1024/128, N/128), 256, 0, stream>>>(
        y1hi, y1lo, W2hi, W2lo, b2f, nullptr, nullptr, nullptr, acc2,
        seg, poolraw, N, 512, 1024);

    // d0 with BN2 inline
    build_d0<<<B, 256, 0, stream>>>(poolraw, agent_h, seg, N, acc2, g2, be2,
                                    1.0f/N, d0hi, d0lo);

    // i1 (fused colstats -> acc3)
    gemm_split<<<dim3(1024/128, B/128), 256, 0, stream>>>(
        d0hi, d0lo, Wi1hi, Wi1lo, bi1f, t1, nullptr, nullptr, acc3,
        nullptr, nullptr, B, 1088, 1024);
    bn_finalize<<<4, 256, 0, stream>>>(acc3, ig1, ib1, 1024, 1.0f/B, sc3, sh3);

    // i2: K-split partials + finish (with fused column stats -> acc4)
    gemm_i2_part<<<dim3(B/128, 8), 256, 0, stream>>>(t1, i2W, sc3, sh3, i2part,
                                                     B, 1024, 128);
    i2_finish_stats<<<64, 256, 0, stream>>>(i2part, i2b, B, 8, t2, acc4);

    // decoder with BN4 inline
    decoder_kernel<<<B/2, 256, 0, stream>>>(t2, acc4, ig2, ib2, 1.0f/B,
                                            agent_c, Wc, bc, pW, pb, pred);
}

// Round 14
// 561.059 us; speedup vs baseline: 1.1771x; 1.0203x over previous
//
#include <hip/hip_runtime.h>

#define EPS_BN 1e-5f

typedef __attribute__((ext_vector_type(8))) short short8;
typedef __attribute__((ext_vector_type(4))) float f32x4;

__device__ __forceinline__ float fast_rcp(float x) { return __builtin_amdgcn_rcpf(x); }
__device__ __forceinline__ float sigmoid_f(float x) { return fast_rcp(1.0f + __expf(-x)); }
// robust tanh: no inf/inf NaN at large |x|
__device__ __forceinline__ float tanh_f(float x) { return 1.0f - 2.0f * fast_rcp(__expf(2.0f * x) + 1.0f); }

// round-to-nearest-even fp32 -> bf16 bits
__device__ __forceinline__ unsigned short f2bf(float f) {
    unsigned u = __float_as_uint(f);
    u += 0x7FFFu + ((u >> 16) & 1u);
    return (unsigned short)(u >> 16);
}
__device__ __forceinline__ unsigned pk_bf(float a, float b) {
    return (unsigned)f2bf(a) | ((unsigned)f2bf(b) << 16);
}
// value of the bf16 rounding (hi part); residual = f - bf_hi(f)
__device__ __forceinline__ float bf_hi(float f) {
    return __uint_as_float((unsigned)f2bf(f) << 16);
}

// async global -> LDS, 16 bytes per lane (dest is wave-uniform base + lane*16)
__device__ __forceinline__ void gload16(const unsigned short* g, unsigned short* l) {
    __builtin_amdgcn_global_load_lds(
        (const __attribute__((address_space(1))) unsigned int*)g,
        (__attribute__((address_space(3))) unsigned int*)l,
        16, 0, 0);
}

union AFrag { short e[8]; short8 v; };
union BFrag { uint4 u; short8 v; };

// ---------------------------------------------------------------------------
// Split-precision MFMA LSTM encoder — MERGED dispatch, 32 seqs/block.
// LAUNCH BOUNDS (256,2) RESTORED (this round): R13 measured that dropping
// the bound let VGPR grow 96->112 and dur 136.4->143us; R9's (256,2) config
// is the verified-best. NEVER use 2nd arg > 2 (R4: (256,4) clamps VGPR->64,
// catastrophic spill).
// v6: merged-activation epilogue (5 rcp -> 3 rcp). v7: build_x0 fused into
// neighbour epilogue.
// ---------------------------------------------------------------------------
__global__ __launch_bounds__(256, 2) void lstm_mfma(
    const float* __restrict__ xA,      // agent_traj [SA, T, 2]
    const float* __restrict__ aW_ih, const float* __restrict__ aW_hh,
    const float* __restrict__ ab_ih, const float* __restrict__ ab_hh,
    float* __restrict__ agent_h, float* __restrict__ agent_c,
    const float* __restrict__ xN,      // neighbours [SN, T, 2]
    const float* __restrict__ nW_ih, const float* __restrict__ nW_hh,
    const float* __restrict__ nb_ih, const float* __restrict__ nb_hh,
    const int* __restrict__ seg, const float* __restrict__ rW,
    const float* __restrict__ rb,
    unsigned short* __restrict__ x0hi, unsigned short* __restrict__ x0lo,
    int nAgentBlk, int T)
{
    __shared__ unsigned h_ex[2][2][32 * 52];   // [buf][hi/lo][32 seqs x 52]

    const bool isA = (blockIdx.x < (unsigned)nAgentBlk);
    const long blk = isA ? blockIdx.x : blockIdx.x - nAgentBlk;
    const float* __restrict__ x     = isA ? xA   : xN;
    const float* __restrict__ W_ih  = isA ? aW_ih : nW_ih;
    const float* __restrict__ W_hh  = isA ? aW_hh : nW_hh;
    const float* __restrict__ b_ih  = isA ? ab_ih : nb_ih;
    const float* __restrict__ b_hh  = isA ? ab_hh : nb_hh;

    const int tid  = threadIdx.x;
    const int w    = tid >> 6;        // cell-group == wave
    const int lane = tid & 63;
    const int s    = lane & 15;       // sequence within the 16 (per B-group)
    const int q    = lane >> 4;       // quad

    short8 ahi[4][3], alo[4][3];
#pragma unroll
    for (int gt = 0; gt < 4; ++gt) {
        const int n = gt * 64 + w * 16 + s;
#pragma unroll
        for (int kc = 0; kc < 2; ++kc) {
            const float* src = &W_hh[n * 64 + kc * 32 + q * 8];
            float4 v0 = *(const float4*)src;
            float4 v1 = *(const float4*)(src + 4);
            float v[8] = {v0.x, v0.y, v0.z, v0.w, v1.x, v1.y, v1.z, v1.w};
            AFrag a, b;
#pragma unroll
            for (int j = 0; j < 8; ++j) {
                a.e[j] = (short)f2bf(v[j]);
                b.e[j] = (short)f2bf(v[j] - bf_hi(v[j]));
            }
            ahi[gt][kc] = a.v;
            alo[gt][kc] = b.v;
        }
        AFrag a2, b2;
#pragma unroll
        for (int j = 0; j < 8; ++j) { a2.e[j] = 0; b2.e[j] = 0; }
        if (q == 0) {   // K rows 64(wi0), 65(wi1), 66(bias)
            const float wi0 = W_ih[n * 2 + 0];
            const float wi1 = W_ih[n * 2 + 1];
            const float bs  = b_ih[n] + b_hh[n];
            a2.e[0] = (short)f2bf(wi0); b2.e[0] = (short)f2bf(wi0 - bf_hi(wi0));
            a2.e[1] = (short)f2bf(wi1); b2.e[1] = (short)f2bf(wi1 - bf_hi(wi1));
            a2.e[2] = (short)f2bf(bs);  b2.e[2] = (short)f2bf(bs  - bf_hi(bs));
        }
        ahi[gt][2] = a2.v;
        alo[gt][2] = b2.v;
    }

    for (int i = tid; i < 2 * 2 * 32 * 52; i += 256) (&h_ex[0][0][0])[i] = 0u;
    __syncthreads();
    if (tid < 32) {   // seq = tid
        h_ex[0][0][tid * 52 + 33] = pk_bf(1.0f, 0.0f);
        h_ex[1][0][tid * 52 + 33] = pk_bf(1.0f, 0.0f);
        float2 xv = *(const float2*)&x[(blk * 32 + tid) * (long)(T * 2)];
        h_ex[0][0][tid * 52 + 32] = pk_bf(xv.x, xv.y);
        h_ex[0][1][tid * 52 + 32] = pk_bf(xv.x - bf_hi(xv.x), xv.y - bf_hi(xv.y));
    }
    __syncthreads();

    float creg[2][4] = {{0.f, 0.f, 0.f, 0.f}, {0.f, 0.f, 0.f, 0.f}};

    for (int t = 0; t < T; ++t) {
        const int rb_ = t & 1, wb = rb_ ^ 1;
        BFrag bhi[2][3], blo[2][3];
#pragma unroll
        for (int g = 0; g < 2; ++g)
#pragma unroll
        for (int kc = 0; kc < 3; ++kc) {
            const int off = (g * 16 + s) * 52 + kc * 16 + (q >> 1) * 8 + (q & 1) * 4;
            bhi[g][kc].u = *(const uint4*)&h_ex[rb_][0][off];
            blo[g][kc].u = *(const uint4*)&h_ex[rb_][1][off];
        }

        f32x4 acc[4][2];
#pragma unroll
        for (int gt = 0; gt < 4; ++gt) { acc[gt][0] = (f32x4)0.f; acc[gt][1] = (f32x4)0.f; }

#pragma unroll
        for (int kc = 0; kc < 3; ++kc) {
#pragma unroll
            for (int g = 0; g < 2; ++g) {
                const short8 bh = bhi[g][kc].v;
                const short8 bl = blo[g][kc].v;
#pragma unroll
                for (int gt = 0; gt < 4; ++gt) {
                    f32x4 a = acc[gt][g];
                    a = __builtin_amdgcn_mfma_f32_16x16x32_bf16(ahi[gt][kc], bh, a, 0, 0, 0);
                    a = __builtin_amdgcn_mfma_f32_16x16x32_bf16(ahi[gt][kc], bl, a, 0, 0, 0);
                    a = __builtin_amdgcn_mfma_f32_16x16x32_bf16(alo[gt][kc], bh, a, 0, 0, 0);
                    acc[gt][g] = a;
                }
            }
        }

#pragma unroll
        for (int g = 0; g < 2; ++g) {
            float hval[4];
#pragma unroll
            for (int r = 0; r < 4; ++r) {
                // merged activations: sigma(zi)*tanh(zg) and sigma(zo)*tanh(c)
                // via single-rcp rational forms (5 rcp -> 3 rcp per element).
                const float ei = __expf(-acc[0][g][r]);          // e^-zi
                const float eg = __expf(2.0f * acc[2][g][r]);    // e^2zg
                const float it = (eg - 1.0f) * fast_rcp((1.0f + ei) * (eg + 1.0f));
                const float sf = fast_rcp(1.0f + __expf(-acc[1][g][r]));
                const float c  = fmaf(sf, creg[g][r], it);
                creg[g][r] = c;
                const float eo = __expf(-acc[3][g][r]);          // e^-zo
                const float ec = __expf(2.0f * c);               // e^2c
                hval[r] = (ec - 1.0f) * fast_rcp((1.0f + eo) * (ec + 1.0f));
            }
            {
                const int w0 = (g * 16 + s) * 52 + w * 8 + q * 2;
                h_ex[wb][0][w0]     = pk_bf(hval[0], hval[1]);
                h_ex[wb][0][w0 + 1] = pk_bf(hval[2], hval[3]);
                h_ex[wb][1][w0]     = pk_bf(hval[0] - bf_hi(hval[0]), hval[1] - bf_hi(hval[1]));
                h_ex[wb][1][w0 + 1] = pk_bf(hval[2] - bf_hi(hval[2]), hval[3] - bf_hi(hval[3]));
            }
            if (t == T - 1) {
                const long seq = blk * 32 + g * 16 + s;
                const int j0 = w * 16 + q * 4;
                if (isA) {
                    *(float4*)&agent_h[seq * 64 + j0] =
                        make_float4(hval[0], hval[1], hval[2], hval[3]);
                    *(float4*)&agent_c[seq * 64 + j0] =
                        make_float4(creg[g][0], creg[g][1], creg[g][2], creg[g][3]);
                } else {
                    // x0 cols 0..63 = neigh_h (identical rounding to old path)
                    *(uint2*)&x0hi[seq * 128 + j0] = make_uint2(
                        pk_bf(hval[0], hval[1]), pk_bf(hval[2], hval[3]));
                    *(uint2*)&x0lo[seq * 128 + j0] = make_uint2(
                        pk_bf(hval[0] - bf_hi(hval[0]), hval[1] - bf_hi(hval[1])),
                        pk_bf(hval[2] - bf_hi(hval[2]), hval[3] - bf_hi(hval[3])));
                }
            }
        }
        if (tid < 32 && t + 1 < T) {
            float2 xv = *(const float2*)&x[(blk * 32 + tid) * (long)(T * 2) + (t + 1) * 2];
            h_ex[wb][0][tid * 52 + 32] = pk_bf(xv.x, xv.y);
            h_ex[wb][1][tid * 52 + 32] = pk_bf(xv.x - bf_hi(xv.x), xv.y - bf_hi(xv.y));
        }
        __syncthreads();
    }

    // x0 cols 64..127: rel_emb = rel @ rW.T + rb  (thread -> 1 seq x 8 cols)
    if (!isA) {
        const int sloc = tid >> 3;
        const long n = blk * 32 + sloc;
        const float2 np = *(const float2*)&x[n * (long)(T * 2) + (T - 1) * 2];
        const int sid = seg[n];
        const float2 ap = *(const float2*)&xA[(long)sid * (T * 2) + (T - 1) * 2];
        const float ra = np.x - ap.x, rbv = np.y - ap.y;
        const int o0 = (tid & 7) * 8;
#pragma unroll
        for (int j = 0; j < 8; ++j) {
            const int o = o0 + j;
            const float v = fmaf(rW[o * 2 + 0], ra, fmaf(rW[o * 2 + 1], rbv, rb[o]));
            x0hi[n * 128 + 64 + o] = f2bf(v);
            x0lo[n * 128 + 64 + o] = f2bf(v - bf_hi(v));
        }
    }
}

// ---------------------------------------------------------------------------
// Weight prep bodies (shared by prep_all / prep_w2).
// ---------------------------------------------------------------------------
__device__ __forceinline__ void wfrag_body(
    const float* __restrict__ W, int K, int blk, int l,
    unsigned short* __restrict__ Whi, unsigned short* __restrict__ Wlo)
{
    const int nKc = K >> 5;
    const int ti = blk / nKc, kc = blk - ti * nKc;
    const int n = ti * 16 + (l & 15);
    const int k0 = kc * 32 + (l >> 4) * 8;
    const long ob = ((long)blk * 64 + l) * 8;
#pragma unroll
    for (int j = 0; j < 8; ++j) {
        float v = W[(long)n * K + k0 + j];
        Whi[ob + j] = f2bf(v);
        Wlo[ob + j] = f2bf(v - bf_hi(v));
    }
}

// ---------------------------------------------------------------------------
// prep_all: all BN-independent weight preps + workspace zeroing in ONE
// dispatch (absorbs the two former hipMemsetAsync calls).
// blocks: [0,128) wfrag m1W | [128,2304) wfrag i1W | [2304,2312) b1f copy |
// [2312,2328) bi1f copy | [2328,2588) decoder Wc/bc | [2588,2594) zero accAll
// (5248 floats) | [2594,4642) zero poolraw (2M floats).
// ---------------------------------------------------------------------------
__global__ __launch_bounds__(64) void prep_all(
    const float* __restrict__ m1W, const float* __restrict__ m1b,
    const float* __restrict__ i1W, const float* __restrict__ i1b,
    const float* __restrict__ dW_ih, const float* __restrict__ dW_hh,
    const float* __restrict__ db_ih, const float* __restrict__ db_hh,
    unsigned short* __restrict__ W1hi, unsigned short* __restrict__ W1lo,
    float* __restrict__ b1f,
    unsigned short* __restrict__ Wi1hi, unsigned short* __restrict__ Wi1lo,
    float* __restrict__ bi1f,
    float* __restrict__ Wc, float* __restrict__ bc,
    float* __restrict__ accAll, float* __restrict__ poolraw)
{
    const int b = blockIdx.x, l = threadIdx.x;
    if (b < 128) {
        wfrag_body(m1W, 128, b, l, W1hi, W1lo);
    } else if (b < 2304) {
        wfrag_body(i1W, 1088, b - 128, l, Wi1hi, Wi1lo);
    } else if (b < 2312) {
        const int i = (b - 2304) * 64 + l;    // 512
        b1f[i] = m1b[i];
    } else if (b < 2328) {
        const int i = (b - 2312) * 64 + l;    // 1024
        bi1f[i] = i1b[i];
    } else if (b < 2588) {
        const int idx = (b - 2328) * 64 + l;  // 16640
        if (idx < 16384) Wc[idx] = dW_ih[idx] + dW_hh[idx];
        else if (idx < 16640) bc[idx - 16384] = db_ih[idx - 16384] + db_hh[idx - 16384];
    } else if (b < 2594) {
        const int i0 = (b - 2588) * 1024 + l; // 5248 floats total
#pragma unroll
        for (int j = 0; j < 16; ++j) {
            const int i = i0 + j * 64;
            if (i < 5248) accAll[i] = 0.f;
        }
    } else {
        const long i0 = (long)(b - 2594) * 1024 + l * 4;  // 2M floats total
        const float4 z = make_float4(0.f, 0.f, 0.f, 0.f);
#pragma unroll
        for (int j = 0; j < 4; ++j)
            *(float4*)&poolraw[i0 + j * 256] = z;
    }
}

// ---------------------------------------------------------------------------
// prep_w2: W2 frag-split with BN1 scale folded INLINE from acc1 + bias fold.
// ---------------------------------------------------------------------------
__global__ __launch_bounds__(64) void prep_w2(
    const float* __restrict__ W,      // m2W [1024,512]
    const float* __restrict__ b2,     // m2b
    const float* __restrict__ acc1,   // [2*512]
    const float* __restrict__ g1, const float* __restrict__ be1,
    float invN,
    unsigned short* __restrict__ Whi, unsigned short* __restrict__ Wlo,
    float* __restrict__ bout)
{
    const int K = 512, nKc = 16;
    const int blk = blockIdx.x, l = threadIdx.x;
    if (blk < 1024) {
        const int ti = blk / nKc, kc = blk - ti * nKc;
        const int n = ti * 16 + (l & 15);
        const int k0 = kc * 32 + (l >> 4) * 8;
        const long ob = ((long)blk * 64 + l) * 8;
#pragma unroll
        for (int j = 0; j < 8; ++j) {
            const int k = k0 + j;
            const float mean = acc1[k] * invN;
            const float var  = acc1[512 + k] * invN - mean * mean;
            const float sc   = g1[k] * rsqrtf(var + EPS_BN);
            const float v = W[(long)n * K + k] * sc;
            Whi[ob + j] = f2bf(v);
            Wlo[ob + j] = f2bf(v - bf_hi(v));
        }
    } else {
        const int n = blk - 1024;
        float s = 0.f;
        for (int k = l; k < K; k += 64) {
            const float mean = acc1[k] * invN;
            const float var  = acc1[512 + k] * invN - mean * mean;
            const float sc   = g1[k] * rsqrtf(var + EPS_BN);
            const float sh   = be1[k] - mean * sc;
            s += sh * W[(long)n * K + k];
        }
#pragma unroll
        for (int m = 32; m >= 1; m >>= 1) s += __shfl_xor(s, m, 64);
        if (l == 0) bout[n] = b2[n] + s;
    }
}

// ---------------------------------------------------------------------------
// Split-activation MFMA GEMM v9 — BK=64, R13 VERIFIED WIN (e2e 581.9->572.5,
// gemm left top-5): each LDS buffer holds 2 kc (128x64 per plane), ONE
// __syncthreads per 2 kc. 8-slot XOR swizzle: physical slot p of row r holds
// logical p^(r&7); write side = inverse-permuted per-lane GLOBAL source
// (gload_lds dest linear, rule #21), read side XORs same key (row&7==lane&7,
// mt/wm-invariant). launch_bounds (256,2) LOAD-BEARING. nKc EVEN.
// gridDim.y % 8 == 0. Epilogue: LDS segment-max pool (span<=120), interior
// plain stores + boundary atomicMax; fallback to direct atomics.
// Schedule-graft history: T2-alone null (R7), vmcnt graft regression (R8).
// ---------------------------------------------------------------------------
__global__ __launch_bounds__(256, 2) void gemm_split(
    const unsigned short* __restrict__ Ahi,
    const unsigned short* __restrict__ Alo,
    const unsigned short* __restrict__ Whi,
    const unsigned short* __restrict__ Wlo,
    const float* __restrict__ bias,
    float* __restrict__ Yf,
    unsigned short* __restrict__ Yhi,
    unsigned short* __restrict__ Ylo,
    float* __restrict__ accum,
    const int* __restrict__ segp,
    float* __restrict__ poolmax,
    int M, int K, int O)
{
    __shared__ unsigned short As[2][2][128 * 64];   // [buf][hi/lo], BK=64
    __shared__ int segl[128];
    const int t = threadIdx.x;
    const int lane = t & 63;
    const int w = t >> 6;
    const int wm = w & 1, wn = w >> 1;

    // XCD swizzle: flat -> (row panel, col panel)
    const int nx = gridDim.x;
    const int flat = blockIdx.y * nx + blockIdx.x;
    const int grp = flat / (8 * nx);
    const int loc = flat - grp * (8 * nx);
    const int m0 = (grp * 8 + (loc & 7)) * 128;
    const int n0 = (loc >> 3) * 128;
    const int nKc = K >> 5;   // even

    f32x4 acc[4][4];
#pragma unroll
    for (int mt = 0; mt < 4; ++mt)
#pragma unroll
    for (int nt = 0; nt < 4; ++nt) acc[mt][nt] = (f32x4)0.f;

    // A staging, BK=64: wave w owns rows [w*32, w*32+32); 4 chunks of 8 rows
    // per plane per stage. lane l -> row = chunk*8 + (l>>3), physical slot
    // p = l&7. Source logical slot s = p ^ (row&7); logical s maps to global
    // col (s>>2)*32 + (s&3)*8 within the contiguous kc pair.
    const int rl = w * 32 + (lane >> 3);
    const int sl = (lane & 7) ^ (lane >> 3);
    const long gcol = (long)((sl >> 2) * 32 + (sl & 3) * 8);
    const unsigned short* gA[2];
    gA[0] = Ahi + (long)(m0 + rl) * K + gcol;
    gA[1] = Alo + (long)(m0 + rl) * K + gcol;

    auto stageA = [&](int buf, int kc2) {
#pragma unroll
        for (int pp = 0; pp < 2; ++pp)
#pragma unroll
        for (int cc = 0; cc < 4; ++cc)
            gload16(gA[pp] + (long)cc * 8 * K + kc2 * 32,
                    &As[buf][pp][(w * 32 + cc * 8) * 64]);
    };

    // read-side physical slot for kc-half h: ((lane>>4) + h*4) ^ (lane&7).
    const int s2a = (((lane >> 4) + 0) ^ (lane & 7)) * 8;
    const int s2b = (((lane >> 4) + 4) ^ (lane & 7)) * 8;
    const int arow = wm * 64 + (lane & 15);
    const long bt0 = (long)((n0 >> 4) + wn * 4);

    auto loadB = [&](BFrag* bh, BFrag* bl, int kc) {
#pragma unroll
        for (int nt = 0; nt < 4; ++nt) {
            const long fb = ((bt0 + nt) * nKc + kc) * 512 + lane * 8;
            bh[nt].u = *(const uint4*)(Whi + fb);
            bl[nt].u = *(const uint4*)(Wlo + fb);
        }
    };
    auto compute = [&](int buf, int s2, BFrag* bh, BFrag* bl) {
        BFrag afh[4], afl[4];
#pragma unroll
        for (int mt = 0; mt < 4; ++mt) {
            afh[mt].u = *(const uint4*)&As[buf][0][(arow + mt * 16) * 64 + s2];
            afl[mt].u = *(const uint4*)&As[buf][1][(arow + mt * 16) * 64 + s2];
        }
#pragma unroll
        for (int nt = 0; nt < 4; ++nt)
#pragma unroll
        for (int mt = 0; mt < 4; ++mt) {
            f32x4 a = acc[mt][nt];
            a = __builtin_amdgcn_mfma_f32_16x16x32_bf16(afh[mt].v, bh[nt].v, a, 0, 0, 0);
            a = __builtin_amdgcn_mfma_f32_16x16x32_bf16(afh[mt].v, bl[nt].v, a, 0, 0, 0);
            a = __builtin_amdgcn_mfma_f32_16x16x32_bf16(afl[mt].v, bh[nt].v, a, 0, 0, 0);
            acc[mt][nt] = a;
        }
    };

    BFrag bh0[4], bl0[4], bh1[4], bl1[4];
    stageA(0, 0);             // kc 0,1 -> buf0
    loadB(bh0, bl0, 0);
    __syncthreads();
    int buf = 0;
    for (int kc2 = 0; kc2 < nKc; kc2 += 2) {
        if (kc2 + 2 < nKc) stageA(buf ^ 1, kc2 + 2);
        loadB(bh1, bl1, kc2 + 1);
        compute(buf, s2a, bh0, bl0);          // kc2 (half 0)
        if (kc2 + 2 < nKc) loadB(bh0, bl0, kc2 + 2);
        compute(buf, s2b, bh1, bl1);          // kc2+1 (half 1)
        if (kc2 + 2 < nKc) __syncthreads();   // drains stage(buf^1), releases buf
        buf ^= 1;
    }

    int sid0 = 0, span = 0;
    bool useLds = false;
    float* pool = nullptr;
    if (segp) {
        __syncthreads();                 // As is dead after this point
        if (t < 128) segl[t] = segp[m0 + t];
        __syncthreads();
        sid0 = segl[0];
        span = segl[127] - sid0 + 1;     // sorted ids -> contiguous range
        pool = (float*)&As[0][0][0];     // reuse As as [span][132] fp32 pool
        useLds = (span <= 120);          // 120*132*4 = 63.4 KB <= 64 KB
        if (useLds) {
            for (int i = t; i < span * 132; i += 256) pool[i] = 0.f;
            __syncthreads();
        }
    }

    const int cn = lane & 15, cq = lane >> 4;
#pragma unroll
    for (int nt = 0; nt < 4; ++nt) {
        const int cl = wn * 64 + nt * 16 + cn;   // column local to n-panel
        const int n = n0 + cl;
        const float bs = bias[n];
        float s = 0.f, ssq = 0.f;
#pragma unroll
        for (int mt = 0; mt < 4; ++mt) {
            const int mb = wm * 64 + mt * 16 + cq * 4;
            float vmax = 0.f; int sid = -1;
#pragma unroll
            for (int r = 0; r < 4; ++r) {
                const float v = fmaxf(acc[mt][nt][r] + bs, 0.f);
                s += v; ssq += v * v;
                if (segp) {
                    const int sr = segl[mb + r];
                    if (r == 0) { vmax = v; sid = sr; }
                    else if (sr == sid) { vmax = fmaxf(vmax, v); }
                    else {
                        if (vmax > 0.f) {
                            if (useLds)
                                atomicMax((int*)&pool[(sid - sid0) * 132 + cl], __float_as_int(vmax));
                            else
                                atomicMax((int*)&poolmax[(long)sid * O + n], __float_as_int(vmax));
                        }
                        sid = sr; vmax = v;
                    }
                } else if (Yf) {
                    Yf[(long)(m0 + mb + r) * O + n] = v;
                } else {
                    const long idx = (long)(m0 + mb + r) * O + n;
                    Yhi[idx] = f2bf(v);
                    Ylo[idx] = f2bf(v - bf_hi(v));
                }
            }
            if (segp && vmax > 0.f) {
                if (useLds)
                    atomicMax((int*)&pool[(sid - sid0) * 132 + cl], __float_as_int(vmax));
                else
                    atomicMax((int*)&poolmax[(long)sid * O + n], __float_as_int(vmax));
            }
        }
        if (accum) {
            s   += __shfl_xor(s, 16, 64);   ssq += __shfl_xor(ssq, 16, 64);
            s   += __shfl_xor(s, 32, 64);   ssq += __shfl_xor(ssq, 32, 64);
            if (cq == 0) {
                atomicAdd(&accum[n], s);
                atomicAdd(&accum[O + n], ssq);
            }
        }
    }

    if (segp && useLds) {
        __syncthreads();
        // interior sids: unique writer -> plain store; boundary sids ->
        // global atomicMax. Absent sids are globally empty (sorted ids).
        for (int e = t; e < span * 128; e += 256) {
            const int sl_ = e >> 7, c = e & 127;
            const float v = pool[sl_ * 132 + c];
            const long gi = (long)(sid0 + sl_) * O + (n0 + c);
            if (sl_ == 0 || sl_ == span - 1) {
                if (v > 0.f) atomicMax((int*)&poolmax[gi], __float_as_int(v));
            } else {
                poolmax[gi] = v;
            }
        }
    }
}

__global__ __launch_bounds__(256) void bn_finalize(
    const float* __restrict__ accum, const float* __restrict__ g,
    const float* __restrict__ be, int O, float invM,
    float* __restrict__ scale, float* __restrict__ shift)
{
    const int o = blockIdx.x * 256 + threadIdx.x;
    if (o < O) {
        const float mean = accum[o] * invM;
        const float var  = accum[O + o] * invM - mean * mean;
        const float sc   = g[o] * rsqrtf(var + EPS_BN);
        scale[o] = sc;
        shift[o] = be[o] - mean * sc;
    }
}

// ---------------------------------------------------------------------------
// d0 = concat( BN2(poolmax) or 0 (empty segment), agent_h ) -> hi/lo.
// BN2 computed INLINE from acc2.
// ---------------------------------------------------------------------------
__global__ __launch_bounds__(256) void build_d0(
    const float* __restrict__ poolraw, const float* __restrict__ agent_h,
    const int* __restrict__ seg, int N,
    const float* __restrict__ acc2, const float* __restrict__ g2,
    const float* __restrict__ be2, float invN,
    unsigned short* __restrict__ d0hi, unsigned short* __restrict__ d0lo)
{
    const int b = blockIdx.x;
    int l = 0, h = N;
    while (l < h) { const int mid = (l + h) >> 1; if (seg[mid] < b) l = mid + 1; else h = mid; }
    const bool nonempty = (l < N) && (seg[l] == b);
    for (int c = threadIdx.x; c < 1088; c += 256) {
        float v;
        if (c < 1024) {
            const float mean = acc2[c] * invN;
            const float var  = acc2[1024 + c] * invN - mean * mean;
            const float sc   = g2[c] * rsqrtf(var + EPS_BN);
            const float sh   = be2[c] - mean * sc;
            v = nonempty ? fmaf(sc, poolraw[(long)b * 1024 + c], sh) : 0.f;
        } else {
            v = agent_h[(long)b * 64 + (c - 1024)];
        }
        d0hi[(long)b * 1088 + c] = f2bf(v);
        d0lo[(long)b * 1088 + c] = f2bf(v - bf_hi(v));
    }
}

// ---------------------------------------------------------------------------
// i2 K-split partial GEMM (fp32, O=64): grid (M/128, KS).
// ---------------------------------------------------------------------------
__global__ __launch_bounds__(256) void gemm_i2_part(
    const float* __restrict__ A,   // [M, K] fp32
    const float* __restrict__ W,   // [64, K]
    const float* __restrict__ ascale, const float* __restrict__ ashift,
    float* __restrict__ part, int M, int K, int kchunk)
{
    __shared__ float As[16][132];
    __shared__ float Bs[16][68];
    const int t = threadIdx.x;
    const int m0 = blockIdx.x * 128;
    const int ks = blockIdx.y;
    const int kbeg = ks * kchunk;
    const int kend = kbeg + kchunk;
    const int tm = (t & 15) * 8;
    const int tn = (t >> 4) * 4;
    const int ar = t >> 1;          // 0..127
    const int ac = (t & 1) * 8;     // 0 or 8
    const int br = t >> 2;          // 0..63
    const int bc = (t & 3) * 4;     // 0,4,8,12

    float acc[8][4];
#pragma unroll
    for (int i = 0; i < 8; ++i)
#pragma unroll
    for (int j = 0; j < 4; ++j) acc[i][j] = 0.f;

    for (int k0 = kbeg; k0 < kend; k0 += 16) {
        float4 a0 = *(const float4*)&A[(long)(m0+ar)*K + k0 + ac];
        float4 a1 = *(const float4*)&A[(long)(m0+ar)*K + k0 + ac + 4];
        float4 s0 = *(const float4*)&ascale[k0 + ac];
        float4 s1 = *(const float4*)&ascale[k0 + ac + 4];
        float4 h0 = *(const float4*)&ashift[k0 + ac];
        float4 h1 = *(const float4*)&ashift[k0 + ac + 4];
        a0.x = fmaf(a0.x, s0.x, h0.x); a0.y = fmaf(a0.y, s0.y, h0.y);
        a0.z = fmaf(a0.z, s0.z, h0.z); a0.w = fmaf(a0.w, s0.w, h0.w);
        a1.x = fmaf(a1.x, s1.x, h1.x); a1.y = fmaf(a1.y, s1.y, h1.y);
        a1.z = fmaf(a1.z, s1.z, h1.z); a1.w = fmaf(a1.w, s1.w, h1.w);
        float4 b0 = *(const float4*)&W[(long)br*K + k0 + bc];
        __syncthreads();
        As[ac+0][ar] = a0.x; As[ac+1][ar] = a0.y; As[ac+2][ar] = a0.z; As[ac+3][ar] = a0.w;
        As[ac+4][ar] = a1.x; As[ac+5][ar] = a1.y; As[ac+6][ar] = a1.z; As[ac+7][ar] = a1.w;
        Bs[bc+0][br] = b0.x; Bs[bc+1][br] = b0.y; Bs[bc+2][br] = b0.z; Bs[bc+3][br] = b0.w;
        __syncthreads();
#pragma unroll
        for (int kk = 0; kk < 16; ++kk) {
            float av[8], bv[4];
            *(float4*)&av[0] = *(const float4*)&As[kk][tm];
            *(float4*)&av[4] = *(const float4*)&As[kk][tm + 4];
            *(float4*)&bv[0] = *(const float4*)&Bs[kk][tn];
#pragma unroll
            for (int i = 0; i < 8; ++i)
#pragma unroll
            for (int j = 0; j < 4; ++j)
                acc[i][j] = fmaf(av[i], bv[j], acc[i][j]);
        }
    }

    float* po = part + (long)ks * M * 64;
#pragma unroll
    for (int i = 0; i < 8; ++i)
        *(float4*)&po[(long)(m0 + tm + i) * 64 + tn] = *(float4*)&acc[i][0];
}

// ---------------------------------------------------------------------------
// t2 = relu(sum_ks part + bias) + fused column stats -> acc4.
// ---------------------------------------------------------------------------
__global__ __launch_bounds__(256) void i2_finish_stats(
    const float* __restrict__ part, const float* __restrict__ bias,
    int M, int KS, float* __restrict__ t2, float* __restrict__ accum)
{
    __shared__ float l1[256], l2[256];
    const int t = threadIdx.x;
    const long base = (long)blockIdx.x * 2048;
    float s = 0.f, ss = 0.f;
#pragma unroll
    for (int k = 0; k < 8; ++k) {
        const long idx = base + k * 256 + t;
        float v = 0.f;
        for (int ks = 0; ks < KS; ++ks) v += part[(long)ks * M * 64 + idx];
        v = fmaxf(v + bias[idx & 63], 0.f);
        t2[idx] = v;
        s += v; ss += v * v;
    }
    l1[t] = s; l2[t] = ss;
    __syncthreads();
    if (t < 64) {
        s  = l1[t] + l1[t + 64] + l1[t + 128] + l1[t + 192];
        ss = l2[t] + l2[t + 64] + l2[t + 128] + l2[t + 192];
        atomicAdd(&accum[t], s);
        atomicAdd(&accum[64 + t], ss);
    }
}

// ---------------------------------------------------------------------------
// Autoregressive decoder: 30 LSTMCell steps (input == h), fused prediction.
// BN4 computed INLINE from acc4.
// ---------------------------------------------------------------------------
__global__ __launch_bounds__(256) void decoder_kernel(
    const float* __restrict__ t2, const float* __restrict__ acc4,
    const float* __restrict__ ig2, const float* __restrict__ ib2, float invB,
    const float* __restrict__ agent_c,
    const float* __restrict__ Wc, const float* __restrict__ bc,
    const float* __restrict__ pW, const float* __restrict__ pb,
    float* __restrict__ pred /*[B,30,2]*/)
{
    __shared__ float h_lds[2][64];
    __shared__ float zg_lds[2][64];
    __shared__ float zo_lds[2][64];
    const int t = threadIdx.x;
    const int lane = t & 63;
    const int wave = t >> 6;
    const int s = wave >> 1;
    const int role = wave & 1;
    const long seq = (long)blockIdx.x * 2 + s;

    const int r0 = role * 128 + lane;
    const int r1 = r0 + 64;
    float w0[64], w1[64];
#pragma unroll
    for (int k = 0; k < 64; k += 4) {
        float4 va = *(const float4*)&Wc[r0 * 64 + k];
        w0[k] = va.x; w0[k+1] = va.y; w0[k+2] = va.z; w0[k+3] = va.w;
        float4 vb = *(const float4*)&Wc[r1 * 64 + k];
        w1[k] = vb.x; w1[k+1] = vb.y; w1[k+2] = vb.z; w1[k+3] = vb.w;
    }
    const float bias0 = bc[r0];
    const float bias1 = bc[r1];
    const float pw0 = pW[lane], pw1 = pW[64 + lane];
    const float pb0 = pb[0], pb1 = pb[1];

    float c = agent_c[seq*64 + lane];
    if (role == 0) {
        const float mean = acc4[lane] * invB;
        const float var  = acc4[64 + lane] * invB - mean * mean;
        const float sc   = ig2[lane] * rsqrtf(var + EPS_BN);
        const float sh   = ib2[lane] - mean * sc;
        h_lds[s][lane] = fmaf(sc, t2[seq*64 + lane], sh);
    }
    __syncthreads();
    float hv = h_lds[s][lane];

    for (int step = 0; step < 30; ++step) {
        float z0 = bias0, z1 = bias1;
#pragma unroll
        for (int k = 0; k < 64; ++k) {
            float hk = __int_as_float(__builtin_amdgcn_readlane(__float_as_int(hv), k));
            z0 = fmaf(hk, w0[k], z0);
            z1 = fmaf(hk, w1[k], z1);
        }
        if (role == 1) { zg_lds[s][lane] = z0; zo_lds[s][lane] = z1; }
        __syncthreads();
        if (role == 0) {
            const float ig = sigmoid_f(z0);
            const float fg = sigmoid_f(z1);
            const float gg = tanh_f(zg_lds[s][lane]);
            const float og = sigmoid_f(zo_lds[s][lane]);
            c = fmaf(fg, c, ig * gg);
            h_lds[s][lane] = og * tanh_f(c);
        }
        __syncthreads();
        hv = h_lds[s][lane];
        if (role == 0) {
            float p0 = hv * pw0;
            float p1 = hv * pw1;
#pragma unroll
            for (int m = 32; m >= 1; m >>= 1) {
                p0 += __shfl_xor(p0, m, 64);
                p1 += __shfl_xor(p1, m, 64);
            }
            if (lane == 0) {
                pred[seq*60 + step*2 + 0] = p0 + pb0;
                pred[seq*60 + step*2 + 1] = p1 + pb1;
            }
        }
    }
}

// ---------------------------------------------------------------------------
extern "C" void kernel_launch(void* const* d_in, const int* in_sizes, int n_in,
                              void* d_out, int out_size, void* d_ws, size_t ws_size,
                              hipStream_t stream)
{
    const float* agent_traj = (const float*)d_in[0];
    const float* neighbours = (const float*)d_in[1];
    const float* aW_ih = (const float*)d_in[2];
    const float* aW_hh = (const float*)d_in[3];
    const float* ab_ih = (const float*)d_in[4];
    const float* ab_hh = (const float*)d_in[5];
    const float* nW_ih = (const float*)d_in[6];
    const float* nW_hh = (const float*)d_in[7];
    const float* nb_ih = (const float*)d_in[8];
    const float* nb_hh = (const float*)d_in[9];
    const float* dW_ih = (const float*)d_in[10];
    const float* dW_hh = (const float*)d_in[11];
    const float* db_ih = (const float*)d_in[12];
    const float* db_hh = (const float*)d_in[13];
    const float* pW = (const float*)d_in[14];
    const float* pb = (const float*)d_in[15];
    const float* rW = (const float*)d_in[16];
    const float* rb = (const float*)d_in[17];
    const float* m1W = (const float*)d_in[18];
    const float* m1b = (const float*)d_in[19];
    const float* g1  = (const float*)d_in[20];
    const float* be1 = (const float*)d_in[21];
    const float* m2W = (const float*)d_in[22];
    const float* m2b = (const float*)d_in[23];
    const float* g2  = (const float*)d_in[24];
    const float* be2 = (const float*)d_in[25];
    const float* i1W = (const float*)d_in[26];
    const float* i1b = (const float*)d_in[27];
    const float* ig1 = (const float*)d_in[28];
    const float* ib1 = (const float*)d_in[29];
    const float* i2W = (const float*)d_in[30];
    const float* i2b = (const float*)d_in[31];
    const float* ig2 = (const float*)d_in[32];
    const float* ib2 = (const float*)d_in[33];
    const int*   seg = (const int*)d_in[34];
    float* pred = (float*)d_out;

    const int B = 2048, T = 20, N = 32768;

    char* p = (char*)d_ws;
    auto alloc = [&](size_t bytes) -> char* {
        char* r = p; p += (bytes + 255) & ~(size_t)255; return r;
    };
    float* agent_h = (float*)alloc((size_t)B*64*4);
    float* agent_c = (float*)alloc((size_t)B*64*4);
    char* neigh_region = alloc((size_t)N*64*4);          // t1 (fp32 B*1024)
    unsigned short* x0hi = (unsigned short*)alloc((size_t)N*128*2);
    unsigned short* x0lo = (unsigned short*)alloc((size_t)N*128*2);
    char* y1hi_region  = alloc((size_t)N*512*2);         // y1hi, later d0hi/d0lo/t2
    unsigned short* y1lo = (unsigned short*)alloc((size_t)N*512*2);
    float* poolraw = (float*)alloc((size_t)B*1024*4);    // 8 MB, zeroed in prep_all
    float* accAll = (float*)alloc((size_t)(1024+2048+2048+128)*4);
    float* acc1 = accAll;            // 2*512
    float* acc2 = accAll + 1024;     // 2*1024
    float* acc3 = accAll + 3072;     // 2*1024
    float* acc4 = accAll + 5120;     // 2*64
    float* sc3 = (float*)alloc(1024*4); float* sh3 = (float*)alloc(1024*4);
    float* Wc = (float*)alloc(256*64*4);
    float* bc = (float*)alloc(256*4);
    unsigned short* W1hi = (unsigned short*)alloc((size_t)512*128*2);
    unsigned short* W1lo = (unsigned short*)alloc((size_t)512*128*2);
    unsigned short* W2hi = (unsigned short*)alloc((size_t)1024*512*2);
    unsigned short* W2lo = (unsigned short*)alloc((size_t)1024*512*2);
    unsigned short* Wi1hi = (unsigned short*)alloc((size_t)1024*1088*2);
    unsigned short* Wi1lo = (unsigned short*)alloc((size_t)1024*1088*2);
    float* b1f = (float*)alloc(512*4);
    float* b2f = (float*)alloc(1024*4);
    float* bi1f = (float*)alloc(1024*4);
    float* i2part = (float*)alloc((size_t)8*B*64*4);     // 4 MB partials

    // aliases (lifetimes disjoint, stream-ordered)
    float* t1 = (float*)neigh_region;            // i1 output (fp32 B*1024)
    unsigned short* y1hi = (unsigned short*)y1hi_region;
    unsigned short* d0hi = (unsigned short*)y1hi_region;          // after MLP2
    unsigned short* d0lo = d0hi + (size_t)B*1088;
    float* t2 = (float*)(y1hi_region + (size_t)2*B*1088*2);

    // all BN-independent preps + workspace zeroing in one dispatch
    prep_all<<<4642, 64, 0, stream>>>(m1W, m1b, i1W, i1b, dW_ih, dW_hh, db_ih, db_hh,
                                      W1hi, W1lo, b1f, Wi1hi, Wi1lo, bi1f, Wc, bc,
                                      accAll, poolraw);

    // merged agent+neighbour LSTM with fused x0 build
    lstm_mfma<<<B/32 + N/32, 256, 0, stream>>>(
        agent_traj, aW_ih, aW_hh, ab_ih, ab_hh, agent_h, agent_c,
        neighbours, nW_ih, nW_hh, nb_ih, nb_hh,
        seg, rW, rb, x0hi, x0lo, B/32, T);

    // MLP1 (fused colstats -> acc1)
    gemm_split<<<dim3(512/128, N/128), 256, 0, stream>>>(
        x0hi, x0lo, W1hi, W1lo, b1f, nullptr, y1hi, y1lo, acc1,
        nullptr, nullptr, N, 128, 512);

    // W2 prep with BN1 folded inline
    prep_w2<<<2048, 64, 0, stream>>>(m2W, m2b, acc1, g1, be1, 1.0f/N,
                                     W2hi, W2lo, b2f);

    // MLP2 (fused colstats -> acc2, fused LDS-reduced segment-max -> poolraw)
    gemm_split<<<dim3(1024/128, N/128), 256, 0, stream>>>(
        y1hi, y1lo, W2hi, W2lo, b2f, nullptr, nullptr, nullptr, acc2,
        seg, poolraw, N, 512, 1024);

    // d0 with BN2 inline
    build_d0<<<B, 256, 0, stream>>>(poolraw, agent_h, seg, N, acc2, g2, be2,
                                    1.0f/N, d0hi, d0lo);

    // i1 (fused colstats -> acc3)
    gemm_split<<<dim3(1024/128, B/128), 256, 0, stream>>>(
        d0hi, d0lo, Wi1hi, Wi1lo, bi1f, t1, nullptr, nullptr, acc3,
        nullptr, nullptr, B, 1088, 1024);
    bn_finalize<<<4, 256, 0, stream>>>(acc3, ig1, ib1, 1024, 1.0f/B, sc3, sh3);

    // i2: K-split partials + finish (with fused column stats -> acc4)
    gemm_i2_part<<<dim3(B/128, 8), 256, 0, stream>>>(t1, i2W, sc3, sh3, i2part,
                                                     B, 1024, 128);
    i2_finish_stats<<<64, 256, 0, stream>>>(i2part, i2b, B, 8, t2, acc4);

    // decoder with BN4 inline
    decoder_kernel<<<B/2, 256, 0, stream>>>(t2, acc4, ig2, ib2, 1.0f/B,
                                            agent_c, Wc, bc, pW, pb, pred);
}